// Round 1
// baseline (1117.873 us; speedup 1.0000x reference)
//
#include <hip/hip_runtime.h>
#include <math.h>

#define RESQ 7
#define BF   16
#define CH   256
#define HF   36
#define WF   36
#define NROI 512
#define BC   128
#define NB   3
#define NT   512

// LDS layout (floats)
#define OFF_XS   0        // xs  [256][49] = 12544
#define OFF_T1P  12544    // t1p [128][81] = 10368 (zero-padded 9x9)
#define OFF_T2   22912    // t2  [128][49] = 6272
#define OFF_WY   29184    // wy  [7][36]
#define OFF_WX   29436    // wx  [7][36]
#define LDS_FLOATS 29688
// deconv buffer dbuf [256][49]=12544 reuses T1P+T2 region (16640 floats)

__device__ __forceinline__ float Fk(float t) {
    t = fminf(1.f, fmaxf(-1.f, t));
    float a = t + 1.f, b = 1.f - t;
    return (t < 0.f) ? 0.5f * a * a : 1.f - 0.5f * b * b;
}

extern "C" __global__ __launch_bounds__(NT, 2)
void masknet_fused(const float* __restrict__ feat,
                   const float* __restrict__ bbox,
                   const float* __restrict__ w1, const float* __restrict__ s1, const float* __restrict__ b1,
                   const float* __restrict__ w2, const float* __restrict__ s2, const float* __restrict__ b2,
                   const float* __restrict__ w3, const float* __restrict__ s3, const float* __restrict__ b3,
                   const float* __restrict__ wt, const float* __restrict__ bt,
                   const float* __restrict__ wm, const float* __restrict__ bm,
                   float* __restrict__ out)
{
    __shared__ float lds[LDS_FLOATS];
    float* xs   = lds + OFF_XS;
    float* t1p  = lds + OFF_T1P;
    float* t2   = lds + OFF_T2;
    float* wyb  = lds + OFF_WY;
    float* wxb  = lds + OFF_WX;
    float* dbuf = lds + OFF_T1P;   // reuse for deconv quadrant

    const int tid = threadIdx.x;
    const int r   = blockIdx.x;
    const int bfr = r >> 5;        // frame = roi / 32

    // ---- ROI params (uniform per block) ----
    const float S  = 1.f / 16.f;
    const float bx = bbox[r*4+0], by = bbox[r*4+1];
    const float bw_ = bbox[r*4+2], bh_ = bbox[r*4+3];
    const float x1 = bx * S, y1 = by * S;
    const float x2 = (bx + bw_) * S, y2 = (by + bh_) * S;
    const float bwx = (x2 - x1) * (1.f / RESQ);
    const float bwy = (y2 - y1) * (1.f / RESQ);
    const float area = bwx * bwy;
    const float inv_area = (area > 0.f) ? 1.f / fmaxf(area, 1e-12f) : 0.f;

    // ---- Phase A: bilinear-integral weight tables + zero t1p border ----
    if (tid < 252) {
        int p = tid / 36, i = tid - p * 36;
        float st = y1 + bwy * p, en = st + bwy;
        wyb[tid] = Fk(en - (float)i) - Fk(st - (float)i);
    } else if (tid >= 256 && tid < 508) {
        int t = tid - 256;
        int q = t / 36, i = t - q * 36;
        float st = x1 + bwx * q, en = st + bwx;
        wxb[t] = Fk(en - (float)i) - Fk(st - (float)i);
    }
    for (int o = tid; o < BC * 81; o += NT) t1p[o] = 0.f;
    __syncthreads();

    // ---- Phase B: PrRoI pool -> xs[256][49] ----
    {
        const float* fb = feat + (size_t)bfr * CH * HF * WF;
        for (int o = tid; o < CH * 49; o += NT) {
            int c = o / 49, s = o - c * 49;
            int p = s / 7, q = s - p * 7;
            float sy = y1 + bwy * p, ey = sy + bwy;
            float sx = x1 + bwx * q, ex = sx + bwx;
            int ylo = max(0, (int)floorf(sy)), yhi = min(HF - 1, (int)ceilf(ey));
            int xlo = max(0, (int)floorf(sx)), xhi = min(WF - 1, (int)ceilf(ex));
            const float* fc = fb + c * (HF * WF);
            float acc = 0.f;
            for (int y = ylo; y <= yhi; ++y) {
                float wyv = wyb[p * 36 + y];
                const float* frow = fc + y * WF;
                for (int x = xlo; x <= xhi; ++x)
                    acc = fmaf(wyv * wxb[q * 36 + x], frow[x], acc);
            }
            xs[o] = acc * inv_area;
        }
    }
    __syncthreads();

    // ---- thread tiling: 4 out-channels x up-to-4 spatial per thread ----
    const int cg = tid >> 4;     // 0..31  -> cbase = cg*4 (covers 128)
    const int sg = tid & 15;     // 0..15  -> s in {sg, sg+16, sg+32, sg+48}
    int  sk[4], pk[4], qk[4];
    bool vk[4];
    #pragma unroll
    for (int k = 0; k < 4; ++k) {
        int s = sg + 16 * k;
        vk[k] = (s < 49);
        s = vk[k] ? s : 48;
        sk[k] = s; pk[k] = s / 7; qk[k] = s - (s / 7) * 7;
    }

    // ---- Phase C: 3 bottleneck blocks ----
    for (int ib = 0; ib < NB; ++ib) {
        const float* w1b = w1 + (size_t)ib * BC * CH;
        const float* w2b = w2 + (size_t)ib * BC * BC * 9;
        const float* w3b = w3 + (size_t)ib * CH * BC;

        // conv1 1x1: xs[256] -> t1p[128] (interior of 9x9), scale+bias+relu
        {
            const int cbase = cg * 4;
            float acc[4][4] = {};
            for (int ci = 0; ci < CH; ++ci) {
                float xv[4], wv[4];
                #pragma unroll
                for (int k = 0; k < 4; ++k) xv[k] = xs[ci * 49 + sk[k]];
                #pragma unroll
                for (int j = 0; j < 4; ++j) wv[j] = w1b[(cbase + j) * CH + ci];
                #pragma unroll
                for (int j = 0; j < 4; ++j)
                    #pragma unroll
                    for (int k = 0; k < 4; ++k)
                        acc[j][k] = fmaf(wv[j], xv[k], acc[j][k]);
            }
            #pragma unroll
            for (int j = 0; j < 4; ++j) {
                int c = cbase + j;
                float sc = s1[ib * BC + c], bi = b1[ib * BC + c];
                #pragma unroll
                for (int k = 0; k < 4; ++k) if (vk[k])
                    t1p[c * 81 + (pk[k] + 1) * 9 + (qk[k] + 1)] =
                        fmaxf(fmaf(acc[j][k], sc, bi), 0.f);
            }
        }
        __syncthreads();

        // conv2 3x3 (zero-padded): t1p[128] -> t2[128], scale+bias+relu
        {
            const int cbase = cg * 4;
            float acc[4][4] = {};
            for (int ci = 0; ci < BC; ++ci) {
                const float* tp = t1p + ci * 81;
                #pragma unroll
                for (int dy = 0; dy < 3; ++dy)
                #pragma unroll
                for (int dx = 0; dx < 3; ++dx) {
                    const int tap = dy * 3 + dx;
                    float wv[4], xv[4];
                    #pragma unroll
                    for (int j = 0; j < 4; ++j)
                        wv[j] = w2b[((cbase + j) * BC + ci) * 9 + tap];
                    #pragma unroll
                    for (int k = 0; k < 4; ++k)
                        xv[k] = tp[(pk[k] + dy) * 9 + (qk[k] + dx)];
                    #pragma unroll
                    for (int j = 0; j < 4; ++j)
                        #pragma unroll
                        for (int k = 0; k < 4; ++k)
                            acc[j][k] = fmaf(wv[j], xv[k], acc[j][k]);
                }
            }
            #pragma unroll
            for (int j = 0; j < 4; ++j) {
                int c = cbase + j;
                float sc = s2[ib * BC + c], bi = b2[ib * BC + c];
                #pragma unroll
                for (int k = 0; k < 4; ++k) if (vk[k])
                    t2[c * 49 + sk[k]] = fmaxf(fmaf(acc[j][k], sc, bi), 0.f);
            }
        }
        __syncthreads();

        // conv3 1x1: t2[128] -> xs[256], scale+bias + residual + relu
        for (int h = 0; h < 2; ++h) {
            const int cbase = cg * 4 + h * 128;
            float acc[4][4] = {};
            for (int ci = 0; ci < BC; ++ci) {
                float xv[4], wv[4];
                #pragma unroll
                for (int k = 0; k < 4; ++k) xv[k] = t2[ci * 49 + sk[k]];
                #pragma unroll
                for (int j = 0; j < 4; ++j) wv[j] = w3b[(cbase + j) * BC + ci];
                #pragma unroll
                for (int j = 0; j < 4; ++j)
                    #pragma unroll
                    for (int k = 0; k < 4; ++k)
                        acc[j][k] = fmaf(wv[j], xv[k], acc[j][k]);
            }
            #pragma unroll
            for (int j = 0; j < 4; ++j) {
                int c = cbase + j;
                float sc = s3[ib * CH + c], bi = b3[ib * CH + c];
                #pragma unroll
                for (int k = 0; k < 4; ++k) if (vk[k]) {
                    float v = fmaf(acc[j][k], sc, bi) + xs[c * 49 + sk[k]];
                    xs[c * 49 + sk[k]] = fmaxf(v, 0.f);
                }
            }
        }
        __syncthreads();
    }

    // ---- Phase D: deconv 2x2 s2 as 4 quadrant 1x1 convs + bias + relu,
    //      then 1x1 conv (wm) + bm + sigmoid ----
    for (int quad = 0; quad < 4; ++quad) {
        for (int h = 0; h < 2; ++h) {
            const int cbase = cg * 4 + h * 128;
            float acc[4][4] = {};
            for (int ci = 0; ci < CH; ++ci) {
                float xv[4], wv[4];
                #pragma unroll
                for (int k = 0; k < 4; ++k) xv[k] = xs[ci * 49 + sk[k]];
                #pragma unroll
                for (int j = 0; j < 4; ++j)
                    wv[j] = wt[(size_t)ci * 1024 + (cbase + j) * 4 + quad];
                #pragma unroll
                for (int j = 0; j < 4; ++j)
                    #pragma unroll
                    for (int k = 0; k < 4; ++k)
                        acc[j][k] = fmaf(wv[j], xv[k], acc[j][k]);
            }
            #pragma unroll
            for (int j = 0; j < 4; ++j) {
                int c = cbase + j;
                float bi = bt[c];
                #pragma unroll
                for (int k = 0; k < 4; ++k) if (vk[k])
                    dbuf[c * 49 + sk[k]] = fmaxf(acc[j][k] + bi, 0.f);
            }
        }
        __syncthreads();

        if (tid < 49) {
            float lg = bm[0];
            #pragma unroll 4
            for (int co = 0; co < CH; ++co)
                lg = fmaf(wm[co], dbuf[co * 49 + tid], lg);
            const int p = tid / 7, q = tid - p * 7;
            const int dy = quad >> 1, dx = quad & 1;
            out[(size_t)r * 196 + (2 * p + dy) * 14 + (2 * q + dx)] =
                1.f / (1.f + expf(-lg));
        }
        __syncthreads();
    }
}

extern "C" void kernel_launch(void* const* d_in, const int* in_sizes, int n_in,
                              void* d_out, int out_size, void* d_ws, size_t ws_size,
                              hipStream_t stream) {
    const float* feat = (const float*)d_in[0];
    const float* bbox = (const float*)d_in[1];
    const float* w1   = (const float*)d_in[2];
    const float* s1   = (const float*)d_in[3];
    const float* b1   = (const float*)d_in[4];
    const float* w2   = (const float*)d_in[5];
    const float* s2   = (const float*)d_in[6];
    const float* b2   = (const float*)d_in[7];
    const float* w3   = (const float*)d_in[8];
    const float* s3   = (const float*)d_in[9];
    const float* b3   = (const float*)d_in[10];
    const float* wt   = (const float*)d_in[11];
    const float* bt   = (const float*)d_in[12];
    const float* wm   = (const float*)d_in[13];
    const float* bm   = (const float*)d_in[14];
    float* out = (float*)d_out;

    hipLaunchKernelGGL(masknet_fused, dim3(NROI), dim3(NT), 0, stream,
                       feat, bbox, w1, s1, b1, w2, s2, b2, w3, s3, b3,
                       wt, bt, wm, bm, out);
}

// Round 3
// 448.838 us; speedup vs baseline: 2.4906x; 2.4906x over previous
//
#include <hip/hip_runtime.h>
#include <math.h>

#define RESQ 7
#define CH   256
#define HF   36
#define WF   36
#define NROI 512
#define BC   128
#define NB   3
#define NT   512

typedef __bf16 bh8 __attribute__((ext_vector_type(8)));
typedef float  f4_ __attribute__((ext_vector_type(4)));

// ---- d_ws weight layout (bytes) ----
#define W1OFF 0            // [3][128][256] bf16  -> 196608 B
#define W2OFF 196608       // [3][9][128][128] bf16 (tap-major) -> 884736 B
#define W3OFF 1081344      // [3][256][128] bf16 -> 196608 B
#define WTOFF 1277952      // [4][256 co][256 ci] bf16 -> 524288 B
#define WS_BYTES 1802240
#define PRE_ELEMS 901120   // 98304 + 442368 + 98304 + 262144

// ---- LDS layout (bytes) ----
#define XS_OFF 0           // xs_t  [64 sp][256 ch] bf16 = 32768
#define T1_OFF 32768       // t1t   [102 rows][128 ch] bf16 = 26112 (9x9 pad + zero rows 81..101)
#define T2_OFF 58880       // t2t   [64 sp][128 ch] bf16 = 16384
#define WY_OFF 75264       // 252 f32
#define WX_OFF 76272       // 252 f32
#define RED_OFF 77280      // [64][8] f32 = 2048
#define LDS_BYTES 79328
#define DB_OFF T1_OFF      // dbuf [64 sp][256 ch] bf16 = 32768 (overlays t1t+t2t)

#define SWZ(row) (((row) & 7) << 4)

__device__ __forceinline__ float Fk(float t) {
    t = fminf(1.f, fmaxf(-1.f, t));
    float a = t + 1.f, b = 1.f - t;
    return (t < 0.f) ? 0.5f * a * a : 1.f - 0.5f * b * b;
}

__device__ __forceinline__ unsigned int pk2(float a, float b) {
    union { __bf16 h[2]; unsigned int u; } z;
    z.h[0] = (__bf16)a; z.h[1] = (__bf16)b;
    return z.u;
}
__device__ __forceinline__ unsigned short bf16bits(float a) {
    union { __bf16 h; unsigned short s; } z;
    z.h = (__bf16)a;
    return z.s;
}
__device__ __forceinline__ float b2f(unsigned short s) {
    union { unsigned short s2; __bf16 h; } z; z.s2 = s;
    return (float)z.h;
}

__device__ __forceinline__ bh8 ld_bh8(const unsigned char* p) {
    return *(const bh8*)p;
}
__device__ __forceinline__ bh8 cvt8(const float* p) {
    float4 a = *(const float4*)p;
    float4 b = *(const float4*)(p + 4);
    bh8 r;
    r[0]=(__bf16)a.x; r[1]=(__bf16)a.y; r[2]=(__bf16)a.z; r[3]=(__bf16)a.w;
    r[4]=(__bf16)b.x; r[5]=(__bf16)b.y; r[6]=(__bf16)b.z; r[7]=(__bf16)b.w;
    return r;
}
__device__ __forceinline__ bh8 gather8(const float* p, int stride) {
    bh8 r;
    #pragma unroll
    for (int j = 0; j < 8; ++j) r[j] = (__bf16)p[j * stride];
    return r;
}

// ---------------- weight prepass: f32 -> bf16 (+ transposes) ----------------
extern "C" __global__ void prepass(const float* __restrict__ w1,
                                   const float* __restrict__ w2,
                                   const float* __restrict__ w3,
                                   const float* __restrict__ wt,
                                   unsigned char* __restrict__ ws) {
    for (int i = blockIdx.x * blockDim.x + threadIdx.x; i < PRE_ELEMS;
         i += gridDim.x * blockDim.x) {
        if (i < 98304) {
            ((__bf16*)(ws + W1OFF))[i] = (__bf16)w1[i];
        } else if (i < 98304 + 442368) {
            int d = i - 98304;
            int ib = d / 147456, r = d - ib * 147456;
            int tap = r / 16384, r2 = r - tap * 16384;
            int m = r2 >> 7, ci = r2 & 127;
            ((__bf16*)(ws + W2OFF))[d] = (__bf16)w2[((ib * BC + m) * BC + ci) * 9 + tap];
        } else if (i < 98304 + 442368 + 98304) {
            int d = i - (98304 + 442368);
            ((__bf16*)(ws + W3OFF))[d] = (__bf16)w3[d];
        } else {
            int d = i - (98304 + 442368 + 98304);
            int quad = d >> 16, r = d & 65535;
            int co = r >> 8, ci = r & 255;
            ((__bf16*)(ws + WTOFF))[d] = (__bf16)wt[ci * 1024 + co * 4 + quad];
        }
    }
}

// ---------------- fused main kernel ----------------
template<int USE_WS>
__global__ __launch_bounds__(NT, 4)
void masknet_mfma(const float* __restrict__ feat,
                  const float* __restrict__ bbox,
                  const float* __restrict__ w1, const float* __restrict__ s1, const float* __restrict__ b1,
                  const float* __restrict__ w2, const float* __restrict__ s2, const float* __restrict__ b2,
                  const float* __restrict__ w3, const float* __restrict__ s3, const float* __restrict__ b3,
                  const float* __restrict__ wt, const float* __restrict__ bt,
                  const float* __restrict__ wm, const float* __restrict__ bm,
                  const unsigned char* __restrict__ ws,
                  float* __restrict__ out)
{
    __shared__ __align__(16) unsigned char smem[LDS_BYTES];
    float* wyb = (float*)(smem + WY_OFF);
    float* wxb = (float*)(smem + WX_OFF);
    float* red = (float*)(smem + RED_OFF);

    const int tid  = threadIdx.x;
    const int r    = blockIdx.x;
    const int bfr  = r >> 5;
    const int lane = tid & 63;
    const int lr   = lane & 15;
    const int kg   = lane >> 4;
    const int w_   = tid >> 6;

    // ---- ROI params ----
    const float S = 1.f / 16.f;
    const float bx = bbox[r*4+0], by = bbox[r*4+1];
    const float bw_ = bbox[r*4+2], bh_ = bbox[r*4+3];
    const float x1 = bx * S, y1 = by * S;
    const float bwx = (bw_ * S) * (1.f / RESQ);
    const float bwy = (bh_ * S) * (1.f / RESQ);
    const float area = bwx * bwy;
    const float inv_area = (area > 0.f) ? 1.f / fmaxf(area, 1e-12f) : 0.f;

    // ---- Phase A: integral tables + zero-init LDS ----
    if (tid < 252) {
        int p = tid / 36, i = tid - p * 36;
        float st = y1 + bwy * p, en = st + bwy;
        wyb[tid] = Fk(en - (float)i) - Fk(st - (float)i);
    } else if (tid >= 256 && tid < 508) {
        int t = tid - 256;
        int q = t / 36, i = t - q * 36;
        float st = x1 + bwx * q, en = st + bwx;
        wxb[t] = Fk(en - (float)i) - Fk(st - (float)i);
    }
    {   // zero xs_t, t1t, t2t (75264 bytes = 4704 uint4)
        uint4* z = (uint4*)smem;
        for (int o = tid; o < 4704; o += NT) z[o] = make_uint4(0,0,0,0);
    }
    __syncthreads();

    // ---- Phase B: PrRoI pool -> xs_t[s][c] bf16 (swizzled) ----
    {
        const float* fb = feat + (size_t)bfr * CH * HF * WF;
        for (int o = tid; o < CH * 49; o += NT) {
            int c = o / 49, s = o - c * 49;
            int p = s / 7, q = s - p * 7;
            float sy = y1 + bwy * p, ey = sy + bwy;
            float sx = x1 + bwx * q, ex = sx + bwx;
            int ylo = max(0, (int)floorf(sy)), yhi = min(HF - 1, (int)ceilf(ey));
            int xlo = max(0, (int)floorf(sx)), xhi = min(WF - 1, (int)ceilf(ex));
            float wxv[5];
            #pragma unroll
            for (int ii = 0; ii < 5; ++ii) {
                int x = xlo + ii;
                wxv[ii] = (x <= xhi) ? wxb[q * 36 + x] : 0.f;
            }
            const float* fc = fb + c * (HF * WF);
            float acc = 0.f;
            for (int y = ylo; y <= yhi; ++y) {
                float wyv = wyb[p * 36 + y];
                const float* frow = fc + y * WF;
                #pragma unroll
                for (int ii = 0; ii < 5; ++ii) {
                    int x = xlo + ii;
                    if (x <= xhi) acc = fmaf(wyv * wxv[ii], frow[x], acc);
                }
            }
            *(unsigned short*)(smem + XS_OFF + s * 512 + ((2 * c) ^ SWZ(s))) =
                bf16bits(acc * inv_area);
        }
    }
    __syncthreads();

    // wave grids
    const int mw12 = w_ >> 2;            // conv1/2: 2 m-groups (64 ch each)
    const int nw12 = w_ & 3;             //          4 n-waves (16 cols)
    const int n12  = nw12 * 16 + lr;
    const int sw12 = SWZ(n12);
    const int r0   = (n12 < 49) ? (n12 / 7) * 9 + (n12 % 7) : 81;

    const int mw3 = w_ & 3;              // conv3/deconv: 4 m-groups (64 ch)
    const int nw3 = w_ >> 2;             //               2 n-waves (32 cols)

    // ---- Phase C: bottleneck blocks ----
    for (int ib = 0; ib < NB; ++ib) {
        // ===== conv1: xs_t(256) -> t1t(128 interior), K=256 =====
        {
            f4_ acc[4] = {};
            #pragma unroll
            for (int ks = 0; ks < 8; ++ks) {
                const int kb = ks * 32 + kg * 8;
                bh8 b = ld_bh8(smem + XS_OFF + n12 * 512 + ((2 * kb) ^ sw12));
                #pragma unroll
                for (int i = 0; i < 4; ++i) {
                    const int m = mw12 * 64 + i * 16 + lr;
                    bh8 a;
                    if (USE_WS) a = ld_bh8(ws + W1OFF + ((size_t)(ib * BC + m) * CH + kb) * 2);
                    else        a = cvt8(w1 + (size_t)(ib * BC + m) * CH + kb);
                    acc[i] = __builtin_amdgcn_mfma_f32_16x16x32_bf16(a, b, acc[i], 0, 0, 0);
                }
            }
            if (n12 < 49) {
                const int row = (n12 / 7 + 1) * 9 + (n12 % 7 + 1);
                #pragma unroll
                for (int i = 0; i < 4; ++i) {
                    const int c0 = mw12 * 64 + i * 16 + kg * 4;
                    const float4 sv = *(const float4*)(s1 + ib * BC + c0);
                    const float4 bv = *(const float4*)(b1 + ib * BC + c0);
                    float v0 = fmaxf(fmaf(acc[i][0], sv.x, bv.x), 0.f);
                    float v1 = fmaxf(fmaf(acc[i][1], sv.y, bv.y), 0.f);
                    float v2 = fmaxf(fmaf(acc[i][2], sv.z, bv.z), 0.f);
                    float v3 = fmaxf(fmaf(acc[i][3], sv.w, bv.w), 0.f);
                    *(uint2*)(smem + T1_OFF + row * 256 + ((2 * c0) ^ SWZ(row))) =
                        make_uint2(pk2(v0, v1), pk2(v2, v3));
                }
            }
        }
        __syncthreads();

        // ===== conv2: 3x3 as 9 tap-GEMMs, t1t(128) -> t2t(128), K=128/tap =====
        {
            f4_ acc[4] = {};
            #pragma unroll
            for (int tap = 0; tap < 9; ++tap) {
                const int row = r0 + (tap / 3) * 9 + (tap % 3);
                const unsigned char* bbase = smem + T1_OFF + row * 256;
                const int rs = SWZ(row);
                #pragma unroll
                for (int ks = 0; ks < 4; ++ks) {
                    const int kb = ks * 32 + kg * 8;
                    bh8 b = ld_bh8(bbase + ((2 * kb) ^ rs));
                    #pragma unroll
                    for (int i = 0; i < 4; ++i) {
                        const int m = mw12 * 64 + i * 16 + lr;
                        bh8 a;
                        if (USE_WS) a = ld_bh8(ws + W2OFF + ((size_t)((ib * 9 + tap) * BC + m) * BC + kb) * 2);
                        else        a = gather8(w2 + ((size_t)(ib * BC + m) * BC + kb) * 9 + tap, 9);
                        acc[i] = __builtin_amdgcn_mfma_f32_16x16x32_bf16(a, b, acc[i], 0, 0, 0);
                    }
                }
            }
            if (n12 < 49) {
                #pragma unroll
                for (int i = 0; i < 4; ++i) {
                    const int c0 = mw12 * 64 + i * 16 + kg * 4;
                    const float4 sv = *(const float4*)(s2 + ib * BC + c0);
                    const float4 bv = *(const float4*)(b2 + ib * BC + c0);
                    float v0 = fmaxf(fmaf(acc[i][0], sv.x, bv.x), 0.f);
                    float v1 = fmaxf(fmaf(acc[i][1], sv.y, bv.y), 0.f);
                    float v2 = fmaxf(fmaf(acc[i][2], sv.z, bv.z), 0.f);
                    float v3 = fmaxf(fmaf(acc[i][3], sv.w, bv.w), 0.f);
                    *(uint2*)(smem + T2_OFF + n12 * 256 + ((2 * c0) ^ sw12)) =
                        make_uint2(pk2(v0, v1), pk2(v2, v3));
                }
            }
        }
        __syncthreads();

        // ===== conv3: t2t(128) -> xs_t(256) + residual + relu, K=128 =====
        {
            f4_ acc[4][2] = {};
            #pragma unroll
            for (int ks = 0; ks < 4; ++ks) {
                const int kb = ks * 32 + kg * 8;
                bh8 b[2];
                #pragma unroll
                for (int j = 0; j < 2; ++j) {
                    const int n = nw3 * 32 + j * 16 + lr;
                    b[j] = ld_bh8(smem + T2_OFF + n * 256 + ((2 * kb) ^ SWZ(n)));
                }
                #pragma unroll
                for (int i = 0; i < 4; ++i) {
                    const int m = mw3 * 64 + i * 16 + lr;
                    bh8 a;
                    if (USE_WS) a = ld_bh8(ws + W3OFF + ((size_t)(ib * CH + m) * BC + kb) * 2);
                    else        a = cvt8(w3 + (size_t)(ib * CH + m) * BC + kb);
                    #pragma unroll
                    for (int j = 0; j < 2; ++j)
                        acc[i][j] = __builtin_amdgcn_mfma_f32_16x16x32_bf16(a, b[j], acc[i][j], 0, 0, 0);
                }
            }
            #pragma unroll
            for (int j = 0; j < 2; ++j) {
                const int n = nw3 * 32 + j * 16 + lr;
                if (n < 49) {
                    #pragma unroll
                    for (int i = 0; i < 4; ++i) {
                        const int c0 = mw3 * 64 + i * 16 + kg * 4;
                        const float4 sv = *(const float4*)(s3 + ib * CH + c0);
                        const float4 bv = *(const float4*)(b3 + ib * CH + c0);
                        unsigned char* p = smem + XS_OFF + n * 512 + ((2 * c0) ^ SWZ(n));
                        union { uint2 u; unsigned short h[4]; } old;
                        old.u = *(uint2*)p;
                        float v0 = fmaxf(fmaf(acc[i][j][0], sv.x, bv.x) + b2f(old.h[0]), 0.f);
                        float v1 = fmaxf(fmaf(acc[i][j][1], sv.y, bv.y) + b2f(old.h[1]), 0.f);
                        float v2 = fmaxf(fmaf(acc[i][j][2], sv.z, bv.z) + b2f(old.h[2]), 0.f);
                        float v3 = fmaxf(fmaf(acc[i][j][3], sv.w, bv.w) + b2f(old.h[3]), 0.f);
                        *(uint2*)p = make_uint2(pk2(v0, v1), pk2(v2, v3));
                    }
                }
            }
        }
        __syncthreads();
    }

    // ---- Phase D: deconv quadrants + mask head ----
    for (int quad = 0; quad < 4; ++quad) {
        {
            f4_ acc[4][2] = {};
            #pragma unroll
            for (int ks = 0; ks < 8; ++ks) {
                const int kb = ks * 32 + kg * 8;
                bh8 b[2];
                #pragma unroll
                for (int j = 0; j < 2; ++j) {
                    const int n = nw3 * 32 + j * 16 + lr;
                    b[j] = ld_bh8(smem + XS_OFF + n * 512 + ((2 * kb) ^ SWZ(n)));
                }
                #pragma unroll
                for (int i = 0; i < 4; ++i) {
                    const int m = mw3 * 64 + i * 16 + lr;
                    bh8 a;
                    if (USE_WS) a = ld_bh8(ws + WTOFF + ((size_t)(quad * CH + m) * CH + kb) * 2);
                    else        a = gather8(wt + (size_t)kb * 1024 + m * 4 + quad, 1024);
                    #pragma unroll
                    for (int j = 0; j < 2; ++j)
                        acc[i][j] = __builtin_amdgcn_mfma_f32_16x16x32_bf16(a, b[j], acc[i][j], 0, 0, 0);
                }
            }
            #pragma unroll
            for (int j = 0; j < 2; ++j) {
                const int n = nw3 * 32 + j * 16 + lr;
                if (n < 49) {
                    #pragma unroll
                    for (int i = 0; i < 4; ++i) {
                        const int c0 = mw3 * 64 + i * 16 + kg * 4;
                        const float4 bv = *(const float4*)(bt + c0);
                        float v0 = fmaxf(acc[i][j][0] + bv.x, 0.f);
                        float v1 = fmaxf(acc[i][j][1] + bv.y, 0.f);
                        float v2 = fmaxf(acc[i][j][2] + bv.z, 0.f);
                        float v3 = fmaxf(acc[i][j][3] + bv.w, 0.f);
                        *(uint2*)(smem + DB_OFF + n * 512 + ((2 * c0) ^ SWZ(n))) =
                            make_uint2(pk2(v0, v1), pk2(v2, v3));
                    }
                }
            }
        }
        __syncthreads();

        // mask head: logit[s] = bm + sum_c wm[c]*dbuf[s][c]
        {
            const int s = tid & 63, ch_ = tid >> 6;
            if (s < 49) {
                float part = 0.f;
                #pragma unroll
                for (int ii = 0; ii < 4; ++ii) {
                    const int c0 = ch_ * 32 + ii * 8;
                    bh8 v = ld_bh8(smem + DB_OFF + s * 512 + ((2 * c0) ^ SWZ(s)));
                    const float4 wa = *(const float4*)(wm + c0);
                    const float4 wb = *(const float4*)(wm + c0 + 4);
                    part = fmaf(wa.x, (float)v[0], part);
                    part = fmaf(wa.y, (float)v[1], part);
                    part = fmaf(wa.z, (float)v[2], part);
                    part = fmaf(wa.w, (float)v[3], part);
                    part = fmaf(wb.x, (float)v[4], part);
                    part = fmaf(wb.y, (float)v[5], part);
                    part = fmaf(wb.z, (float)v[6], part);
                    part = fmaf(wb.w, (float)v[7], part);
                }
                red[s * 8 + ch_] = part;
            }
        }
        __syncthreads();
        if (tid < 49) {
            float lg = bm[0];
            #pragma unroll
            for (int ch_ = 0; ch_ < 8; ++ch_) lg += red[tid * 8 + ch_];
            const int p = tid / 7, q = tid - p * 7;
            const int dy = quad >> 1, dx = quad & 1;
            out[(size_t)r * 196 + (2 * p + dy) * 14 + (2 * q + dx)] =
                1.f / (1.f + expf(-lg));
        }
        __syncthreads();
    }
}

extern "C" void kernel_launch(void* const* d_in, const int* in_sizes, int n_in,
                              void* d_out, int out_size, void* d_ws, size_t ws_size,
                              hipStream_t stream) {
    const float* feat = (const float*)d_in[0];
    const float* bbox = (const float*)d_in[1];
    const float* w1   = (const float*)d_in[2];
    const float* s1   = (const float*)d_in[3];
    const float* b1   = (const float*)d_in[4];
    const float* w2   = (const float*)d_in[5];
    const float* s2   = (const float*)d_in[6];
    const float* b2   = (const float*)d_in[7];
    const float* w3   = (const float*)d_in[8];
    const float* s3   = (const float*)d_in[9];
    const float* b3   = (const float*)d_in[10];
    const float* wt   = (const float*)d_in[11];
    const float* bt   = (const float*)d_in[12];
    const float* wm   = (const float*)d_in[13];
    const float* bm   = (const float*)d_in[14];
    float* out = (float*)d_out;

    if (ws_size >= (size_t)WS_BYTES) {
        unsigned char* ws = (unsigned char*)d_ws;
        hipLaunchKernelGGL(prepass, dim3(1024), dim3(256), 0, stream, w1, w2, w3, wt, ws);
        hipLaunchKernelGGL((masknet_mfma<1>), dim3(NROI), dim3(NT), 0, stream,
                           feat, bbox, w1, s1, b1, w2, s2, b2, w3, s3, b3,
                           wt, bt, wm, bm, ws, out);
    } else {
        hipLaunchKernelGGL((masknet_mfma<0>), dim3(NROI), dim3(NT), 0, stream,
                           feat, bbox, w1, s1, b1, w2, s2, b2, w3, s3, b3,
                           wt, bt, wm, bm, (const unsigned char*)nullptr, out);
    }
}

// Round 4
// 317.726 us; speedup vs baseline: 3.5184x; 1.4127x over previous
//
#include <hip/hip_runtime.h>
#include <math.h>

#define RESQ 7
#define CH   256
#define HF   36
#define WF   36
#define NROI 512
#define BC   128
#define NB   3
#define NT   512

typedef __bf16 bh8 __attribute__((ext_vector_type(8)));
typedef float  f4_ __attribute__((ext_vector_type(4)));

// ---- d_ws weight layout (bytes) ----
#define W1OFF 0            // [3][128][256] bf16  -> 196608 B
#define W2OFF 196608       // [3][9][128][128] bf16 (tap-major) -> 884736 B
#define W3OFF 1081344      // [3][256][128] bf16 -> 196608 B
#define WTOFF 1277952      // [4][256 co][256 ci] bf16 -> 524288 B
#define WS_BYTES 1802240
#define PRE_ELEMS 901120   // 98304 + 442368 + 98304 + 262144

// ---- LDS layout (bytes) ----
#define XS_OFF 0           // xs_t  [64 sp][256 ch] bf16 = 32768
#define T1_OFF 32768       // t1t   [102 rows][128 ch] bf16 = 26112 (9x9 pad + zero rows 81..101)
#define T2_OFF 58880       // t2t   [64 sp][128 ch] bf16 = 16384
#define WY_OFF 75264       // 252 f32
#define WX_OFF 76272       // 252 f32
#define RED_OFF 77280      // [64][8] f32 = 2048
#define LDS_BYTES 79328
#define DB_OFF T1_OFF      // dbuf [64 sp][256 ch] bf16 = 32768 (overlays t1t + head of t2t)

#define SWZ(row) (((row) & 7) << 4)

__device__ __forceinline__ float Fk(float t) {
    t = fminf(1.f, fmaxf(-1.f, t));
    float a = t + 1.f, b = 1.f - t;
    return (t < 0.f) ? 0.5f * a * a : 1.f - 0.5f * b * b;
}

__device__ __forceinline__ unsigned int pk2(float a, float b) {
    union { __bf16 h[2]; unsigned int u; } z;
    z.h[0] = (__bf16)a; z.h[1] = (__bf16)b;
    return z.u;
}
__device__ __forceinline__ unsigned short bf16bits(float a) {
    union { __bf16 h; unsigned short s; } z;
    z.h = (__bf16)a;
    return z.s;
}
__device__ __forceinline__ float b2f(unsigned short s) {
    union { unsigned short s2; __bf16 h; } z; z.s2 = s;
    return (float)z.h;
}

__device__ __forceinline__ bh8 ld_bh8(const unsigned char* p) {
    return *(const bh8*)p;
}
__device__ __forceinline__ bh8 cvt8(const float* p) {
    float4 a = *(const float4*)p;
    float4 b = *(const float4*)(p + 4);
    bh8 r;
    r[0]=(__bf16)a.x; r[1]=(__bf16)a.y; r[2]=(__bf16)a.z; r[3]=(__bf16)a.w;
    r[4]=(__bf16)b.x; r[5]=(__bf16)b.y; r[6]=(__bf16)b.z; r[7]=(__bf16)b.w;
    return r;
}
__device__ __forceinline__ bh8 gather8(const float* p, int stride) {
    bh8 r;
    #pragma unroll
    for (int j = 0; j < 8; ++j) r[j] = (__bf16)p[j * stride];
    return r;
}

// ---------------- weight prepass: f32 -> bf16 (+ transposes) ----------------
extern "C" __global__ void prepass(const float* __restrict__ w1,
                                   const float* __restrict__ w2,
                                   const float* __restrict__ w3,
                                   const float* __restrict__ wt,
                                   unsigned char* __restrict__ ws) {
    for (int i = blockIdx.x * blockDim.x + threadIdx.x; i < PRE_ELEMS;
         i += gridDim.x * blockDim.x) {
        if (i < 98304) {
            ((__bf16*)(ws + W1OFF))[i] = (__bf16)w1[i];
        } else if (i < 98304 + 442368) {
            int d = i - 98304;
            int ib = d / 147456, r = d - ib * 147456;
            int tap = r / 16384, r2 = r - tap * 16384;
            int m = r2 >> 7, ci = r2 & 127;
            ((__bf16*)(ws + W2OFF))[d] = (__bf16)w2[((ib * BC + m) * BC + ci) * 9 + tap];
        } else if (i < 98304 + 442368 + 98304) {
            int d = i - (98304 + 442368);
            ((__bf16*)(ws + W3OFF))[d] = (__bf16)w3[d];
        } else {
            int d = i - (98304 + 442368 + 98304);
            int quad = d >> 16, r = d & 65535;
            int co = r >> 8, ci = r & 255;
            ((__bf16*)(ws + WTOFF))[d] = (__bf16)wt[ci * 1024 + co * 4 + quad];
        }
    }
}

// ---------------- fused main kernel ----------------
template<int USE_WS>
__global__ __launch_bounds__(NT, 2)
void masknet_mfma(const float* __restrict__ feat,
                  const float* __restrict__ bbox,
                  const float* __restrict__ w1, const float* __restrict__ s1, const float* __restrict__ b1,
                  const float* __restrict__ w2, const float* __restrict__ s2, const float* __restrict__ b2,
                  const float* __restrict__ w3, const float* __restrict__ s3, const float* __restrict__ b3,
                  const float* __restrict__ wt, const float* __restrict__ bt,
                  const float* __restrict__ wm, const float* __restrict__ bm,
                  const unsigned char* __restrict__ ws,
                  float* __restrict__ out)
{
    __shared__ __align__(16) unsigned char smem[LDS_BYTES];
    float* wyb = (float*)(smem + WY_OFF);
    float* wxb = (float*)(smem + WX_OFF);
    float* red = (float*)(smem + RED_OFF);

    const int tid  = threadIdx.x;
    const int r    = blockIdx.x;
    const int bfr  = r >> 5;
    const int lane = tid & 63;
    const int lr   = lane & 15;
    const int kg   = lane >> 4;
    const int w_   = tid >> 6;

    // ---- ROI params ----
    const float S = 1.f / 16.f;
    const float bx = bbox[r*4+0], by = bbox[r*4+1];
    const float bw_ = bbox[r*4+2], bh_ = bbox[r*4+3];
    const float x1 = bx * S, y1 = by * S;
    const float bwx = (bw_ * S) * (1.f / RESQ);
    const float bwy = (bh_ * S) * (1.f / RESQ);
    const float area = bwx * bwy;
    const float inv_area = (area > 0.f) ? 1.f / fmaxf(area, 1e-12f) : 0.f;

    // ---- Phase A: integral tables + zero-init LDS ----
    if (tid < 252) {
        int p = tid / 36, i = tid - p * 36;
        float st = y1 + bwy * p, en = st + bwy;
        wyb[tid] = Fk(en - (float)i) - Fk(st - (float)i);
    } else if (tid >= 256 && tid < 508) {
        int t = tid - 256;
        int q = t / 36, i = t - q * 36;
        float st = x1 + bwx * q, en = st + bwx;
        wxb[t] = Fk(en - (float)i) - Fk(st - (float)i);
    }
    {   // zero xs_t, t1t, t2t (75264 bytes = 4704 uint4)
        uint4* z = (uint4*)smem;
        for (int o = tid; o < 4704; o += NT) z[o] = make_uint4(0,0,0,0);
    }
    __syncthreads();

    // ---- Phase B: PrRoI pool -> xs_t[s][c] bf16 (swizzled) ----
    {
        const float* fb = feat + (size_t)bfr * CH * HF * WF;
        for (int o = tid; o < CH * 49; o += NT) {
            int c = o / 49, s = o - c * 49;
            int p = s / 7, q = s - p * 7;
            float sy = y1 + bwy * p, ey = sy + bwy;
            float sx = x1 + bwx * q, ex = sx + bwx;
            int ylo = max(0, (int)floorf(sy)), yhi = min(HF - 1, (int)ceilf(ey));
            int xlo = max(0, (int)floorf(sx)), xhi = min(WF - 1, (int)ceilf(ex));
            float wxv[5];
            #pragma unroll
            for (int ii = 0; ii < 5; ++ii) {
                int x = xlo + ii;
                wxv[ii] = (x <= xhi) ? wxb[q * 36 + x] : 0.f;
            }
            const float* fc = fb + c * (HF * WF);
            float acc = 0.f;
            for (int y = ylo; y <= yhi; ++y) {
                float wyv = wyb[p * 36 + y];
                const float* frow = fc + y * WF;
                #pragma unroll
                for (int ii = 0; ii < 5; ++ii) {
                    int x = xlo + ii;
                    if (x <= xhi) acc = fmaf(wyv * wxv[ii], frow[x], acc);
                }
            }
            *(unsigned short*)(smem + XS_OFF + s * 512 + ((2 * c) ^ SWZ(s))) =
                bf16bits(acc * inv_area);
        }
    }
    __syncthreads();

    // ---- Phase C: bottleneck blocks ----
    for (int ib = 0; ib < NB; ++ib) {
        // ===== conv1: xs_t(256) -> t1t(128 interior), K=256 =====
        // wave w_ owns m-tile w_ (16 ch), iterates all 4 n-tiles
        {
            const int m0 = w_ * 16;
            f4_ acc[4] = {};
            #pragma unroll
            for (int ks = 0; ks < 8; ++ks) {
                const int kb = ks * 32 + kg * 8;
                bh8 a;
                if (USE_WS) a = ld_bh8(ws + W1OFF + ((size_t)(ib * BC + m0 + lr) * CH + kb) * 2);
                else        a = cvt8(w1 + (size_t)(ib * BC + m0 + lr) * CH + kb);
                #pragma unroll
                for (int nt = 0; nt < 4; ++nt) {
                    const int n = nt * 16 + lr;
                    bh8 b = ld_bh8(smem + XS_OFF + n * 512 + ((2 * kb) ^ SWZ(n)));
                    acc[nt] = __builtin_amdgcn_mfma_f32_16x16x32_bf16(a, b, acc[nt], 0, 0, 0);
                }
            }
            const int c0 = m0 + kg * 4;
            const float4 sv = *(const float4*)(s1 + ib * BC + c0);
            const float4 bv = *(const float4*)(b1 + ib * BC + c0);
            #pragma unroll
            for (int nt = 0; nt < 4; ++nt) {
                const int n = nt * 16 + lr;
                if (n < 49) {
                    const int row = (n / 7 + 1) * 9 + (n % 7 + 1);
                    float v0 = fmaxf(fmaf(acc[nt][0], sv.x, bv.x), 0.f);
                    float v1 = fmaxf(fmaf(acc[nt][1], sv.y, bv.y), 0.f);
                    float v2 = fmaxf(fmaf(acc[nt][2], sv.z, bv.z), 0.f);
                    float v3 = fmaxf(fmaf(acc[nt][3], sv.w, bv.w), 0.f);
                    *(uint2*)(smem + T1_OFF + row * 256 + ((2 * c0) ^ SWZ(row))) =
                        make_uint2(pk2(v0, v1), pk2(v2, v3));
                }
            }
        }
        __syncthreads();

        // ===== conv2: 3x3 as 9 tap-GEMMs, t1t(128) -> t2t(128) =====
        {
            const int m0 = w_ * 16;
            int trow0[4];
            #pragma unroll
            for (int nt = 0; nt < 4; ++nt) {
                const int n = nt * 16 + lr;
                trow0[nt] = (n < 49) ? (n / 7) * 9 + (n % 7) : 81;
            }
            f4_ acc[4] = {};
            #pragma unroll
            for (int tap = 0; tap < 9; ++tap) {
                const int roff = (tap / 3) * 9 + (tap % 3);
                #pragma unroll
                for (int ks = 0; ks < 4; ++ks) {
                    const int kb = ks * 32 + kg * 8;
                    bh8 a;
                    if (USE_WS) a = ld_bh8(ws + W2OFF + ((size_t)((ib * 9 + tap) * BC + m0 + lr) * BC + kb) * 2);
                    else        a = gather8(w2 + ((size_t)(ib * BC + m0 + lr) * BC + kb) * 9 + tap, 9);
                    #pragma unroll
                    for (int nt = 0; nt < 4; ++nt) {
                        const int row = trow0[nt] + roff;
                        bh8 b = ld_bh8(smem + T1_OFF + row * 256 + ((2 * kb) ^ SWZ(row)));
                        acc[nt] = __builtin_amdgcn_mfma_f32_16x16x32_bf16(a, b, acc[nt], 0, 0, 0);
                    }
                }
            }
            const int c0 = m0 + kg * 4;
            const float4 sv = *(const float4*)(s2 + ib * BC + c0);
            const float4 bv = *(const float4*)(b2 + ib * BC + c0);
            #pragma unroll
            for (int nt = 0; nt < 4; ++nt) {
                const int n = nt * 16 + lr;
                if (n < 49) {
                    float v0 = fmaxf(fmaf(acc[nt][0], sv.x, bv.x), 0.f);
                    float v1 = fmaxf(fmaf(acc[nt][1], sv.y, bv.y), 0.f);
                    float v2 = fmaxf(fmaf(acc[nt][2], sv.z, bv.z), 0.f);
                    float v3 = fmaxf(fmaf(acc[nt][3], sv.w, bv.w), 0.f);
                    *(uint2*)(smem + T2_OFF + n * 256 + ((2 * c0) ^ SWZ(n))) =
                        make_uint2(pk2(v0, v1), pk2(v2, v3));
                }
            }
        }
        __syncthreads();

        // ===== conv3: t2t(128) -> xs_t(256) + residual + relu =====
        // wave w_ owns 2 m-tiles (32 ch), iterates all 4 n-tiles
        {
            const int m0 = w_ * 32;
            f4_ acc[2][4] = {};
            #pragma unroll
            for (int ks = 0; ks < 4; ++ks) {
                const int kb = ks * 32 + kg * 8;
                bh8 a[2];
                #pragma unroll
                for (int i = 0; i < 2; ++i) {
                    if (USE_WS) a[i] = ld_bh8(ws + W3OFF + ((size_t)(ib * CH + m0 + i * 16 + lr) * BC + kb) * 2);
                    else        a[i] = cvt8(w3 + (size_t)(ib * CH + m0 + i * 16 + lr) * BC + kb);
                }
                #pragma unroll
                for (int nt = 0; nt < 4; ++nt) {
                    const int n = nt * 16 + lr;
                    bh8 b = ld_bh8(smem + T2_OFF + n * 256 + ((2 * kb) ^ SWZ(n)));
                    #pragma unroll
                    for (int i = 0; i < 2; ++i)
                        acc[i][nt] = __builtin_amdgcn_mfma_f32_16x16x32_bf16(a[i], b, acc[i][nt], 0, 0, 0);
                }
            }
            #pragma unroll
            for (int nt = 0; nt < 4; ++nt) {
                const int n = nt * 16 + lr;
                if (n < 49) {
                    #pragma unroll
                    for (int i = 0; i < 2; ++i) {
                        const int c0 = m0 + i * 16 + kg * 4;
                        const float4 sv = *(const float4*)(s3 + ib * CH + c0);
                        const float4 bv = *(const float4*)(b3 + ib * CH + c0);
                        unsigned char* p = smem + XS_OFF + n * 512 + ((2 * c0) ^ SWZ(n));
                        union { uint2 u; unsigned short h[4]; } old;
                        old.u = *(uint2*)p;
                        float v0 = fmaxf(fmaf(acc[i][nt][0], sv.x, bv.x) + b2f(old.h[0]), 0.f);
                        float v1 = fmaxf(fmaf(acc[i][nt][1], sv.y, bv.y) + b2f(old.h[1]), 0.f);
                        float v2 = fmaxf(fmaf(acc[i][nt][2], sv.z, bv.z) + b2f(old.h[2]), 0.f);
                        float v3 = fmaxf(fmaf(acc[i][nt][3], sv.w, bv.w) + b2f(old.h[3]), 0.f);
                        *(uint2*)p = make_uint2(pk2(v0, v1), pk2(v2, v3));
                    }
                }
            }
        }
        __syncthreads();
    }

    // ---- Phase D: deconv quadrants + mask head ----
    for (int quad = 0; quad < 4; ++quad) {
        {
            const int m0 = w_ * 32;
            f4_ acc[2][4] = {};
            #pragma unroll
            for (int ks = 0; ks < 8; ++ks) {
                const int kb = ks * 32 + kg * 8;
                bh8 a[2];
                #pragma unroll
                for (int i = 0; i < 2; ++i) {
                    if (USE_WS) a[i] = ld_bh8(ws + WTOFF + ((size_t)(quad * CH + m0 + i * 16 + lr) * CH + kb) * 2);
                    else        a[i] = gather8(wt + (size_t)kb * 1024 + (m0 + i * 16 + lr) * 4 + quad, 1024);
                }
                #pragma unroll
                for (int nt = 0; nt < 4; ++nt) {
                    const int n = nt * 16 + lr;
                    bh8 b = ld_bh8(smem + XS_OFF + n * 512 + ((2 * kb) ^ SWZ(n)));
                    #pragma unroll
                    for (int i = 0; i < 2; ++i)
                        acc[i][nt] = __builtin_amdgcn_mfma_f32_16x16x32_bf16(a[i], b, acc[i][nt], 0, 0, 0);
                }
            }
            #pragma unroll
            for (int nt = 0; nt < 4; ++nt) {
                const int n = nt * 16 + lr;
                if (n < 49) {
                    #pragma unroll
                    for (int i = 0; i < 2; ++i) {
                        const int c0 = m0 + i * 16 + kg * 4;
                        const float4 bv = *(const float4*)(bt + c0);
                        float v0 = fmaxf(acc[i][nt][0] + bv.x, 0.f);
                        float v1 = fmaxf(acc[i][nt][1] + bv.y, 0.f);
                        float v2 = fmaxf(acc[i][nt][2] + bv.z, 0.f);
                        float v3 = fmaxf(acc[i][nt][3] + bv.w, 0.f);
                        *(uint2*)(smem + DB_OFF + n * 512 + ((2 * c0) ^ SWZ(n))) =
                            make_uint2(pk2(v0, v1), pk2(v2, v3));
                    }
                }
            }
        }
        __syncthreads();

        // mask head: logit[s] = bm + sum_c wm[c]*dbuf[s][c]
        {
            const int s = tid & 63, ch_ = tid >> 6;
            if (s < 49) {
                float part = 0.f;
                #pragma unroll
                for (int ii = 0; ii < 4; ++ii) {
                    const int c0 = ch_ * 32 + ii * 8;
                    bh8 v = ld_bh8(smem + DB_OFF + s * 512 + ((2 * c0) ^ SWZ(s)));
                    const float4 wa = *(const float4*)(wm + c0);
                    const float4 wb = *(const float4*)(wm + c0 + 4);
                    part = fmaf(wa.x, (float)v[0], part);
                    part = fmaf(wa.y, (float)v[1], part);
                    part = fmaf(wa.z, (float)v[2], part);
                    part = fmaf(wa.w, (float)v[3], part);
                    part = fmaf(wb.x, (float)v[4], part);
                    part = fmaf(wb.y, (float)v[5], part);
                    part = fmaf(wb.z, (float)v[6], part);
                    part = fmaf(wb.w, (float)v[7], part);
                }
                red[s * 8 + ch_] = part;
            }
        }
        __syncthreads();
        if (tid < 49) {
            float lg = bm[0];
            #pragma unroll
            for (int ch_ = 0; ch_ < 8; ++ch_) lg += red[tid * 8 + ch_];
            const int p = tid / 7, q = tid - p * 7;
            const int dy = quad >> 1, dx = quad & 1;
            out[(size_t)r * 196 + (2 * p + dy) * 14 + (2 * q + dx)] =
                1.f / (1.f + expf(-lg));
        }
        __syncthreads();
    }
}

extern "C" void kernel_launch(void* const* d_in, const int* in_sizes, int n_in,
                              void* d_out, int out_size, void* d_ws, size_t ws_size,
                              hipStream_t stream) {
    const float* feat = (const float*)d_in[0];
    const float* bbox = (const float*)d_in[1];
    const float* w1   = (const float*)d_in[2];
    const float* s1   = (const float*)d_in[3];
    const float* b1   = (const float*)d_in[4];
    const float* w2   = (const float*)d_in[5];
    const float* s2   = (const float*)d_in[6];
    const float* b2   = (const float*)d_in[7];
    const float* w3   = (const float*)d_in[8];
    const float* s3   = (const float*)d_in[9];
    const float* b3   = (const float*)d_in[10];
    const float* wt   = (const float*)d_in[11];
    const float* bt   = (const float*)d_in[12];
    const float* wm   = (const float*)d_in[13];
    const float* bm   = (const float*)d_in[14];
    float* out = (float*)d_out;

    if (ws_size >= (size_t)WS_BYTES) {
        unsigned char* ws = (unsigned char*)d_ws;
        hipLaunchKernelGGL(prepass, dim3(1024), dim3(256), 0, stream, w1, w2, w3, wt, ws);
        hipLaunchKernelGGL((masknet_mfma<1>), dim3(NROI), dim3(NT), 0, stream,
                           feat, bbox, w1, s1, b1, w2, s2, b2, w3, s3, b3,
                           wt, bt, wm, bm, ws, out);
    } else {
        hipLaunchKernelGGL((masknet_mfma<0>), dim3(NROI), dim3(NT), 0, stream,
                           feat, bbox, w1, s1, b1, w2, s2, b2, w3, s3, b3,
                           wt, bt, wm, bm, (const unsigned char*)nullptr, out);
    }
}

// Round 5
// 316.286 us; speedup vs baseline: 3.5344x; 1.0046x over previous
//
#include <hip/hip_runtime.h>
#include <math.h>

#define RESQ 7
#define CH   256
#define HF   36
#define WF   36
#define NROI 512
#define BC   128
#define NB   3
#define NT   512

typedef __bf16 bh8 __attribute__((ext_vector_type(8)));
typedef float  f4_ __attribute__((ext_vector_type(4)));

// ---- d_ws weight layout (bytes) ----
#define W1OFF 0            // [3][128][256] bf16  -> 196608 B
#define W2OFF 196608       // [3][9][128][128] bf16 (tap-major) -> 884736 B
#define W3OFF 1081344      // [3][256][128] bf16 -> 196608 B
#define WTOFF 1277952      // [4][256 co][256 ci] bf16 -> 524288 B
#define WS_BYTES 1802240
#define PRE_ELEMS 901120   // 98304 + 442368 + 98304 + 262144

// ---- LDS layout (bytes) ----
#define XS_OFF 0           // xs_t  [64 sp][256 ch] bf16 = 32768
#define T1_OFF 32768       // t1t   [102 rows][128 ch] bf16 = 26112 (9x9 pad + zero rows 81..101)
#define T2_OFF 58880       // t2t   [64 sp][128 ch] bf16 = 16384
#define WY_OFF 75264       // 252 f32
#define WX_OFF 76272       // 252 f32
#define RED_OFF 77280      // [64][8] f32 = 2048
#define LDS_BYTES 79328
#define DB_OFF T1_OFF      // dbuf [64 sp][256 ch] bf16 = 32768 (overlays t1t + head of t2t)

#define SWZ(row) (((row) & 7) << 4)

__device__ __forceinline__ float Fk(float t) {
    t = fminf(1.f, fmaxf(-1.f, t));
    float a = t + 1.f, b = 1.f - t;
    return (t < 0.f) ? 0.5f * a * a : 1.f - 0.5f * b * b;
}

// ---- register-only bf16 bit manipulation (NO unions -> no scratch) ----
__device__ __forceinline__ unsigned short bf16bits(float a) {
    return __builtin_bit_cast(unsigned short, (__bf16)a);
}
__device__ __forceinline__ unsigned int pk2(float a, float b) {
    return (unsigned int)bf16bits(a) | ((unsigned int)bf16bits(b) << 16);
}
__device__ __forceinline__ float b2f(unsigned int s) {
    return __builtin_bit_cast(float, s << 16);
}

__device__ __forceinline__ bh8 ld_bh8(const unsigned char* p) {
    return *(const bh8*)p;
}
__device__ __forceinline__ bh8 cvt8(const float* p) {
    float4 a = *(const float4*)p;
    float4 b = *(const float4*)(p + 4);
    bh8 r;
    r[0]=(__bf16)a.x; r[1]=(__bf16)a.y; r[2]=(__bf16)a.z; r[3]=(__bf16)a.w;
    r[4]=(__bf16)b.x; r[5]=(__bf16)b.y; r[6]=(__bf16)b.z; r[7]=(__bf16)b.w;
    return r;
}
__device__ __forceinline__ bh8 gather8(const float* p, int stride) {
    bh8 r;
    #pragma unroll
    for (int j = 0; j < 8; ++j) r[j] = (__bf16)p[j * stride];
    return r;
}

// ---------------- weight prepass: f32 -> bf16 (+ transposes) ----------------
extern "C" __global__ void prepass(const float* __restrict__ w1,
                                   const float* __restrict__ w2,
                                   const float* __restrict__ w3,
                                   const float* __restrict__ wt,
                                   unsigned char* __restrict__ ws) {
    for (int i = blockIdx.x * blockDim.x + threadIdx.x; i < PRE_ELEMS;
         i += gridDim.x * blockDim.x) {
        if (i < 98304) {
            ((__bf16*)(ws + W1OFF))[i] = (__bf16)w1[i];
        } else if (i < 98304 + 442368) {
            int d = i - 98304;
            int ib = d / 147456, r = d - ib * 147456;
            int tap = r / 16384, r2 = r - tap * 16384;
            int m = r2 >> 7, ci = r2 & 127;
            ((__bf16*)(ws + W2OFF))[d] = (__bf16)w2[((ib * BC + m) * BC + ci) * 9 + tap];
        } else if (i < 98304 + 442368 + 98304) {
            int d = i - (98304 + 442368);
            ((__bf16*)(ws + W3OFF))[d] = (__bf16)w3[d];
        } else {
            int d = i - (98304 + 442368 + 98304);
            int quad = d >> 16, r = d & 65535;
            int co = r >> 8, ci = r & 255;
            ((__bf16*)(ws + WTOFF))[d] = (__bf16)wt[ci * 1024 + co * 4 + quad];
        }
    }
}

// ---------------- fused main kernel ----------------
template<int USE_WS>
__global__ __launch_bounds__(NT, 2)
void masknet_mfma(const float* __restrict__ feat,
                  const float* __restrict__ bbox,
                  const float* __restrict__ w1, const float* __restrict__ s1, const float* __restrict__ b1,
                  const float* __restrict__ w2, const float* __restrict__ s2, const float* __restrict__ b2,
                  const float* __restrict__ w3, const float* __restrict__ s3, const float* __restrict__ b3,
                  const float* __restrict__ wt, const float* __restrict__ bt,
                  const float* __restrict__ wm, const float* __restrict__ bm,
                  const unsigned char* __restrict__ ws,
                  float* __restrict__ out)
{
    __shared__ __align__(16) unsigned char smem[LDS_BYTES];
    float* wyb = (float*)(smem + WY_OFF);
    float* wxb = (float*)(smem + WX_OFF);
    float* red = (float*)(smem + RED_OFF);

    const int tid  = threadIdx.x;
    const int r    = blockIdx.x;
    const int bfr  = r >> 5;
    const int lane = tid & 63;
    const int lr   = lane & 15;
    const int kg   = lane >> 4;
    const int w_   = tid >> 6;

    // ---- ROI params ----
    const float S = 1.f / 16.f;
    const float bx = bbox[r*4+0], by = bbox[r*4+1];
    const float bw_ = bbox[r*4+2], bh_ = bbox[r*4+3];
    const float x1 = bx * S, y1 = by * S;
    const float bwx = (bw_ * S) * (1.f / RESQ);
    const float bwy = (bh_ * S) * (1.f / RESQ);
    const float area = bwx * bwy;
    const float inv_area = (area > 0.f) ? 1.f / fmaxf(area, 1e-12f) : 0.f;

    // ---- Phase A: integral tables + zero-init LDS ----
    if (tid < 252) {
        int p = tid / 36, i = tid - p * 36;
        float st = y1 + bwy * p, en = st + bwy;
        wyb[tid] = Fk(en - (float)i) - Fk(st - (float)i);
    } else if (tid >= 256 && tid < 508) {
        int t = tid - 256;
        int q = t / 36, i = t - q * 36;
        float st = x1 + bwx * q, en = st + bwx;
        wxb[t] = Fk(en - (float)i) - Fk(st - (float)i);
    }
    {   // zero xs_t, t1t, t2t (75264 bytes = 4704 uint4)
        uint4* z = (uint4*)smem;
        for (int o = tid; o < 4704; o += NT) z[o] = make_uint4(0,0,0,0);
    }
    __syncthreads();

    // ---- Phase B: PrRoI pool -> xs_t[s][c] bf16 (swizzled) ----
    {
        const float* fb = feat + (size_t)bfr * CH * HF * WF;
        for (int o = tid; o < CH * 49; o += NT) {
            int c = o / 49, s = o - c * 49;
            int p = s / 7, q = s - p * 7;
            float sy = y1 + bwy * p, ey = sy + bwy;
            float sx = x1 + bwx * q, ex = sx + bwx;
            int ylo = max(0, (int)floorf(sy)), yhi = min(HF - 1, (int)ceilf(ey));
            int xlo = max(0, (int)floorf(sx)), xhi = min(WF - 1, (int)ceilf(ex));
            float wxv[5];
            #pragma unroll
            for (int ii = 0; ii < 5; ++ii) {
                int x = xlo + ii;
                wxv[ii] = (x <= xhi) ? wxb[q * 36 + x] : 0.f;
            }
            const float* fc = fb + c * (HF * WF);
            float acc = 0.f;
            for (int y = ylo; y <= yhi; ++y) {
                float wyv = wyb[p * 36 + y];
                const float* frow = fc + y * WF;
                #pragma unroll
                for (int ii = 0; ii < 5; ++ii) {
                    int x = xlo + ii;
                    if (x <= xhi) acc = fmaf(wyv * wxv[ii], frow[x], acc);
                }
            }
            *(unsigned short*)(smem + XS_OFF + s * 512 + ((2 * c) ^ SWZ(s))) =
                bf16bits(acc * inv_area);
        }
    }
    __syncthreads();

    // ---- Phase C: bottleneck blocks ----
    for (int ib = 0; ib < NB; ++ib) {
        // ===== conv1: xs_t(256) -> t1t(128 interior), K=256 =====
        // wave w_ owns m-tile w_ (16 ch), iterates all 4 n-tiles
        {
            const int m0 = w_ * 16;
            f4_ acc[4] = {};
            #pragma unroll
            for (int ks = 0; ks < 8; ++ks) {
                const int kb = ks * 32 + kg * 8;
                bh8 a;
                if (USE_WS) a = ld_bh8(ws + W1OFF + ((size_t)(ib * BC + m0 + lr) * CH + kb) * 2);
                else        a = cvt8(w1 + (size_t)(ib * BC + m0 + lr) * CH + kb);
                #pragma unroll
                for (int nt = 0; nt < 4; ++nt) {
                    const int n = nt * 16 + lr;
                    bh8 b = ld_bh8(smem + XS_OFF + n * 512 + ((2 * kb) ^ SWZ(n)));
                    acc[nt] = __builtin_amdgcn_mfma_f32_16x16x32_bf16(a, b, acc[nt], 0, 0, 0);
                }
            }
            const int c0 = m0 + kg * 4;
            const float4 sv = *(const float4*)(s1 + ib * BC + c0);
            const float4 bv = *(const float4*)(b1 + ib * BC + c0);
            #pragma unroll
            for (int nt = 0; nt < 4; ++nt) {
                const int n = nt * 16 + lr;
                if (n < 49) {
                    const int row = (n / 7 + 1) * 9 + (n % 7 + 1);
                    float v0 = fmaxf(fmaf(acc[nt][0], sv.x, bv.x), 0.f);
                    float v1 = fmaxf(fmaf(acc[nt][1], sv.y, bv.y), 0.f);
                    float v2 = fmaxf(fmaf(acc[nt][2], sv.z, bv.z), 0.f);
                    float v3 = fmaxf(fmaf(acc[nt][3], sv.w, bv.w), 0.f);
                    *(uint2*)(smem + T1_OFF + row * 256 + ((2 * c0) ^ SWZ(row))) =
                        make_uint2(pk2(v0, v1), pk2(v2, v3));
                }
            }
        }
        __syncthreads();

        // ===== conv2: 3x3 as 9 tap-GEMMs, t1t(128) -> t2t(128) =====
        {
            const int m0 = w_ * 16;
            int trow0[4];
            #pragma unroll
            for (int nt = 0; nt < 4; ++nt) {
                const int n = nt * 16 + lr;
                trow0[nt] = (n < 49) ? (n / 7) * 9 + (n % 7) : 81;
            }
            f4_ acc[4] = {};
            #pragma unroll
            for (int tap = 0; tap < 9; ++tap) {
                const int roff = (tap / 3) * 9 + (tap % 3);
                #pragma unroll
                for (int ks = 0; ks < 4; ++ks) {
                    const int kb = ks * 32 + kg * 8;
                    bh8 a;
                    if (USE_WS) a = ld_bh8(ws + W2OFF + ((size_t)((ib * 9 + tap) * BC + m0 + lr) * BC + kb) * 2);
                    else        a = gather8(w2 + ((size_t)(ib * BC + m0 + lr) * BC + kb) * 9 + tap, 9);
                    #pragma unroll
                    for (int nt = 0; nt < 4; ++nt) {
                        const int row = trow0[nt] + roff;
                        bh8 b = ld_bh8(smem + T1_OFF + row * 256 + ((2 * kb) ^ SWZ(row)));
                        acc[nt] = __builtin_amdgcn_mfma_f32_16x16x32_bf16(a, b, acc[nt], 0, 0, 0);
                    }
                }
            }
            const int c0 = m0 + kg * 4;
            const float4 sv = *(const float4*)(s2 + ib * BC + c0);
            const float4 bv = *(const float4*)(b2 + ib * BC + c0);
            #pragma unroll
            for (int nt = 0; nt < 4; ++nt) {
                const int n = nt * 16 + lr;
                if (n < 49) {
                    float v0 = fmaxf(fmaf(acc[nt][0], sv.x, bv.x), 0.f);
                    float v1 = fmaxf(fmaf(acc[nt][1], sv.y, bv.y), 0.f);
                    float v2 = fmaxf(fmaf(acc[nt][2], sv.z, bv.z), 0.f);
                    float v3 = fmaxf(fmaf(acc[nt][3], sv.w, bv.w), 0.f);
                    *(uint2*)(smem + T2_OFF + n * 256 + ((2 * c0) ^ SWZ(n))) =
                        make_uint2(pk2(v0, v1), pk2(v2, v3));
                }
            }
        }
        __syncthreads();

        // ===== conv3: t2t(128) -> xs_t(256) + residual + relu =====
        // wave w_ owns 2 m-tiles (32 ch), iterates all 4 n-tiles
        {
            const int m0 = w_ * 32;
            f4_ acc[2][4] = {};
            #pragma unroll
            for (int ks = 0; ks < 4; ++ks) {
                const int kb = ks * 32 + kg * 8;
                bh8 a[2];
                #pragma unroll
                for (int i = 0; i < 2; ++i) {
                    if (USE_WS) a[i] = ld_bh8(ws + W3OFF + ((size_t)(ib * CH + m0 + i * 16 + lr) * BC + kb) * 2);
                    else        a[i] = cvt8(w3 + (size_t)(ib * CH + m0 + i * 16 + lr) * BC + kb);
                }
                #pragma unroll
                for (int nt = 0; nt < 4; ++nt) {
                    const int n = nt * 16 + lr;
                    bh8 b = ld_bh8(smem + T2_OFF + n * 256 + ((2 * kb) ^ SWZ(n)));
                    #pragma unroll
                    for (int i = 0; i < 2; ++i)
                        acc[i][nt] = __builtin_amdgcn_mfma_f32_16x16x32_bf16(a[i], b, acc[i][nt], 0, 0, 0);
                }
            }
            #pragma unroll
            for (int nt = 0; nt < 4; ++nt) {
                const int n = nt * 16 + lr;
                if (n < 49) {
                    #pragma unroll
                    for (int i = 0; i < 2; ++i) {
                        const int c0 = m0 + i * 16 + kg * 4;
                        const float4 sv = *(const float4*)(s3 + ib * CH + c0);
                        const float4 bv = *(const float4*)(b3 + ib * CH + c0);
                        unsigned char* p = smem + XS_OFF + n * 512 + ((2 * c0) ^ SWZ(n));
                        const uint2 old = *(const uint2*)p;
                        float v0 = fmaxf(fmaf(acc[i][nt][0], sv.x, bv.x) + b2f(old.x & 0xFFFFu), 0.f);
                        float v1 = fmaxf(fmaf(acc[i][nt][1], sv.y, bv.y) + b2f(old.x >> 16), 0.f);
                        float v2 = fmaxf(fmaf(acc[i][nt][2], sv.z, bv.z) + b2f(old.y & 0xFFFFu), 0.f);
                        float v3 = fmaxf(fmaf(acc[i][nt][3], sv.w, bv.w) + b2f(old.y >> 16), 0.f);
                        *(uint2*)p = make_uint2(pk2(v0, v1), pk2(v2, v3));
                    }
                }
            }
        }
        __syncthreads();
    }

    // ---- Phase D: deconv quadrants + mask head ----
    for (int quad = 0; quad < 4; ++quad) {
        {
            const int m0 = w_ * 32;
            f4_ acc[2][4] = {};
            #pragma unroll
            for (int ks = 0; ks < 8; ++ks) {
                const int kb = ks * 32 + kg * 8;
                bh8 a[2];
                #pragma unroll
                for (int i = 0; i < 2; ++i) {
                    if (USE_WS) a[i] = ld_bh8(ws + WTOFF + ((size_t)(quad * CH + m0 + i * 16 + lr) * CH + kb) * 2);
                    else        a[i] = gather8(wt + (size_t)kb * 1024 + (m0 + i * 16 + lr) * 4 + quad, 1024);
                }
                #pragma unroll
                for (int nt = 0; nt < 4; ++nt) {
                    const int n = nt * 16 + lr;
                    bh8 b = ld_bh8(smem + XS_OFF + n * 512 + ((2 * kb) ^ SWZ(n)));
                    #pragma unroll
                    for (int i = 0; i < 2; ++i)
                        acc[i][nt] = __builtin_amdgcn_mfma_f32_16x16x32_bf16(a[i], b, acc[i][nt], 0, 0, 0);
                }
            }
            #pragma unroll
            for (int nt = 0; nt < 4; ++nt) {
                const int n = nt * 16 + lr;
                if (n < 49) {
                    #pragma unroll
                    for (int i = 0; i < 2; ++i) {
                        const int c0 = m0 + i * 16 + kg * 4;
                        const float4 bv = *(const float4*)(bt + c0);
                        float v0 = fmaxf(acc[i][nt][0] + bv.x, 0.f);
                        float v1 = fmaxf(acc[i][nt][1] + bv.y, 0.f);
                        float v2 = fmaxf(acc[i][nt][2] + bv.z, 0.f);
                        float v3 = fmaxf(acc[i][nt][3] + bv.w, 0.f);
                        *(uint2*)(smem + DB_OFF + n * 512 + ((2 * c0) ^ SWZ(n))) =
                            make_uint2(pk2(v0, v1), pk2(v2, v3));
                    }
                }
            }
        }
        __syncthreads();

        // mask head: logit[s] = bm + sum_c wm[c]*dbuf[s][c]
        {
            const int s = tid & 63, ch_ = tid >> 6;
            if (s < 49) {
                float part = 0.f;
                #pragma unroll
                for (int ii = 0; ii < 4; ++ii) {
                    const int c0 = ch_ * 32 + ii * 8;
                    bh8 v = ld_bh8(smem + DB_OFF + s * 512 + ((2 * c0) ^ SWZ(s)));
                    const float4 wa = *(const float4*)(wm + c0);
                    const float4 wb = *(const float4*)(wm + c0 + 4);
                    part = fmaf(wa.x, (float)v[0], part);
                    part = fmaf(wa.y, (float)v[1], part);
                    part = fmaf(wa.z, (float)v[2], part);
                    part = fmaf(wa.w, (float)v[3], part);
                    part = fmaf(wb.x, (float)v[4], part);
                    part = fmaf(wb.y, (float)v[5], part);
                    part = fmaf(wb.z, (float)v[6], part);
                    part = fmaf(wb.w, (float)v[7], part);
                }
                red[s * 8 + ch_] = part;
            }
        }
        __syncthreads();
        if (tid < 49) {
            float lg = bm[0];
            #pragma unroll
            for (int ch_ = 0; ch_ < 8; ++ch_) lg += red[tid * 8 + ch_];
            const int p = tid / 7, q = tid - p * 7;
            const int dy = quad >> 1, dx = quad & 1;
            out[(size_t)r * 196 + (2 * p + dy) * 14 + (2 * q + dx)] =
                1.f / (1.f + expf(-lg));
        }
        __syncthreads();
    }
}

extern "C" void kernel_launch(void* const* d_in, const int* in_sizes, int n_in,
                              void* d_out, int out_size, void* d_ws, size_t ws_size,
                              hipStream_t stream) {
    const float* feat = (const float*)d_in[0];
    const float* bbox = (const float*)d_in[1];
    const float* w1   = (const float*)d_in[2];
    const float* s1   = (const float*)d_in[3];
    const float* b1   = (const float*)d_in[4];
    const float* w2   = (const float*)d_in[5];
    const float* s2   = (const float*)d_in[6];
    const float* b2   = (const float*)d_in[7];
    const float* w3   = (const float*)d_in[8];
    const float* s3   = (const float*)d_in[9];
    const float* b3   = (const float*)d_in[10];
    const float* wt   = (const float*)d_in[11];
    const float* bt   = (const float*)d_in[12];
    const float* wm   = (const float*)d_in[13];
    const float* bm   = (const float*)d_in[14];
    float* out = (float*)d_out;

    if (ws_size >= (size_t)WS_BYTES) {
        unsigned char* ws = (unsigned char*)d_ws;
        hipLaunchKernelGGL(prepass, dim3(1024), dim3(256), 0, stream, w1, w2, w3, wt, ws);
        hipLaunchKernelGGL((masknet_mfma<1>), dim3(NROI), dim3(NT), 0, stream,
                           feat, bbox, w1, s1, b1, w2, s2, b2, w3, s3, b3,
                           wt, bt, wm, bm, ws, out);
    } else {
        hipLaunchKernelGGL((masknet_mfma<0>), dim3(NROI), dim3(NT), 0, stream,
                           feat, bbox, w1, s1, b1, w2, s2, b2, w3, s3, b3,
                           wt, bt, wm, bm, (const unsigned char*)nullptr, out);
    }
}

// Round 6
// 271.136 us; speedup vs baseline: 4.1229x; 1.1665x over previous
//
#include <hip/hip_runtime.h>
#include <math.h>

#define RESQ 7
#define CH   256
#define HF   36
#define WF   36
#define NROI 512
#define BC   128
#define NB   3
#define NT   512

typedef __bf16 bh8 __attribute__((ext_vector_type(8)));
typedef float  f4_ __attribute__((ext_vector_type(4)));

// ---- d_ws weight layout (bytes) ----
#define W1OFF 0            // [3][128][256] bf16  -> 196608 B
#define W2OFF 196608       // [3][9][128][128] bf16 (tap-major) -> 884736 B
#define W3OFF 1081344      // [3][256][128] bf16 -> 196608 B
#define WTOFF 1277952      // [4][256 co][256 ci] bf16 -> 524288 B
#define WS_BYTES 1802240
#define PRE_ELEMS 901120   // 98304 + 442368 + 98304 + 262144

// ---- LDS layout (bytes) ----
#define XS_OFF 0           // xs_t  [64 sp][256 ch] bf16 = 32768
#define T1_OFF 32768       // t1t   [102 rows][128 ch] bf16 = 26112 (9x9 pad + zero rows 81..101)
#define T2_OFF 58880       // t2t   [64 sp][128 ch] bf16 = 16384
#define WY_OFF 75264       // 252 f32
#define WX_OFF 76272       // 252 f32
#define RED_OFF 77280      // [64][8] f32 = 2048
#define LDS_BYTES 79328
#define DB_OFF T1_OFF      // dbuf [64 sp][256 ch] bf16 = 32768 (overlays t1t + head of t2t)

#define SWZ(row) (((row) & 7) << 4)

__device__ __forceinline__ float Fk(float t) {
    t = fminf(1.f, fmaxf(-1.f, t));
    float a = t + 1.f, b = 1.f - t;
    return (t < 0.f) ? 0.5f * a * a : 1.f - 0.5f * b * b;
}

// ---- register-only bf16 bit manipulation ----
__device__ __forceinline__ unsigned short bf16bits(float a) {
    return __builtin_bit_cast(unsigned short, (__bf16)a);
}
__device__ __forceinline__ unsigned int pk2(float a, float b) {
    return (unsigned int)bf16bits(a) | ((unsigned int)bf16bits(b) << 16);
}
__device__ __forceinline__ float b2f(unsigned int s) {
    return __builtin_bit_cast(float, s << 16);
}

__device__ __forceinline__ bh8 ld_bh8(const unsigned char* p) {
    return *(const bh8*)p;
}
__device__ __forceinline__ bh8 cvt8(const float* p) {
    float4 a = *(const float4*)p;
    float4 b = *(const float4*)(p + 4);
    bh8 r;
    r[0]=(__bf16)a.x; r[1]=(__bf16)a.y; r[2]=(__bf16)a.z; r[3]=(__bf16)a.w;
    r[4]=(__bf16)b.x; r[5]=(__bf16)b.y; r[6]=(__bf16)b.z; r[7]=(__bf16)b.w;
    return r;
}
__device__ __forceinline__ bh8 gather8(const float* p, int stride) {
    bh8 r;
    #pragma unroll
    for (int j = 0; j < 8; ++j) r[j] = (__bf16)p[j * stride];
    return r;
}

// ---------------- weight prepass: f32 -> bf16 (+ transposes) ----------------
extern "C" __global__ void prepass(const float* __restrict__ w1,
                                   const float* __restrict__ w2,
                                   const float* __restrict__ w3,
                                   const float* __restrict__ wt,
                                   unsigned char* __restrict__ ws) {
    for (int i = blockIdx.x * blockDim.x + threadIdx.x; i < PRE_ELEMS;
         i += gridDim.x * blockDim.x) {
        if (i < 98304) {
            ((__bf16*)(ws + W1OFF))[i] = (__bf16)w1[i];
        } else if (i < 98304 + 442368) {
            int d = i - 98304;
            int ib = d / 147456, r = d - ib * 147456;
            int tap = r / 16384, r2 = r - tap * 16384;
            int m = r2 >> 7, ci = r2 & 127;
            ((__bf16*)(ws + W2OFF))[d] = (__bf16)w2[((ib * BC + m) * BC + ci) * 9 + tap];
        } else if (i < 98304 + 442368 + 98304) {
            int d = i - (98304 + 442368);
            ((__bf16*)(ws + W3OFF))[d] = (__bf16)w3[d];
        } else {
            int d = i - (98304 + 442368 + 98304);
            int quad = d >> 16, r = d & 65535;
            int co = r >> 8, ci = r & 255;
            ((__bf16*)(ws + WTOFF))[d] = (__bf16)wt[ci * 1024 + co * 4 + quad];
        }
    }
}

// ---------------- fused main kernel ----------------
template<int USE_WS>
__global__ __launch_bounds__(NT, 2)
void masknet_mfma(const float* __restrict__ feat,
                  const float* __restrict__ bbox,
                  const float* __restrict__ w1, const float* __restrict__ s1, const float* __restrict__ b1,
                  const float* __restrict__ w2, const float* __restrict__ s2, const float* __restrict__ b2,
                  const float* __restrict__ w3, const float* __restrict__ s3, const float* __restrict__ b3,
                  const float* __restrict__ wt, const float* __restrict__ bt,
                  const float* __restrict__ wm, const float* __restrict__ bm,
                  const unsigned char* __restrict__ ws,
                  float* __restrict__ out)
{
    __shared__ __align__(16) unsigned char smem[LDS_BYTES];
    float* wyb = (float*)(smem + WY_OFF);
    float* wxb = (float*)(smem + WX_OFF);
    float* red = (float*)(smem + RED_OFF);

    const int tid  = threadIdx.x;
    const int r    = blockIdx.x;
    const int bfr  = r >> 5;
    const int lane = tid & 63;
    const int lr   = lane & 15;
    const int kg   = lane >> 4;
    const int w_   = tid >> 6;

    // ---- ROI params ----
    const float S = 1.f / 16.f;
    const float bx = bbox[r*4+0], by = bbox[r*4+1];
    const float bw_ = bbox[r*4+2], bh_ = bbox[r*4+3];
    const float x1 = bx * S, y1 = by * S;
    const float bwx = (bw_ * S) * (1.f / RESQ);
    const float bwy = (bh_ * S) * (1.f / RESQ);
    const float area = bwx * bwy;
    const float inv_area = (area > 0.f) ? 1.f / fmaxf(area, 1e-12f) : 0.f;

    // ---- Phase A: integral tables + zero-init LDS ----
    if (tid < 252) {
        int p = tid / 36, i = tid - p * 36;
        float st = y1 + bwy * p, en = st + bwy;
        wyb[tid] = Fk(en - (float)i) - Fk(st - (float)i);
    } else if (tid >= 256 && tid < 508) {
        int t = tid - 256;
        int q = t / 36, i = t - q * 36;
        float st = x1 + bwx * q, en = st + bwx;
        wxb[t] = Fk(en - (float)i) - Fk(st - (float)i);
    }
    {   // zero xs_t, t1t, t2t (75264 bytes = 4704 uint4)
        uint4* z = (uint4*)smem;
        for (int o = tid; o < 4704; o += NT) z[o] = make_uint4(0,0,0,0);
    }
    __syncthreads();

    // ---- Phase B: PrRoI pool -> xs_t[s][c] bf16 (swizzled) ----
    {
        const float* fb = feat + (size_t)bfr * CH * HF * WF;
        for (int o = tid; o < CH * 49; o += NT) {
            int c = o / 49, s = o - c * 49;
            int p = s / 7, q = s - p * 7;
            float sy = y1 + bwy * p, ey = sy + bwy;
            float sx = x1 + bwx * q, ex = sx + bwx;
            int ylo = max(0, (int)floorf(sy)), yhi = min(HF - 1, (int)ceilf(ey));
            int xlo = max(0, (int)floorf(sx)), xhi = min(WF - 1, (int)ceilf(ex));
            float wxv[5];
            #pragma unroll
            for (int ii = 0; ii < 5; ++ii) {
                int x = xlo + ii;
                wxv[ii] = (x <= xhi) ? wxb[q * 36 + x] : 0.f;
            }
            const float* fc = fb + c * (HF * WF);
            float acc = 0.f;
            for (int y = ylo; y <= yhi; ++y) {
                float wyv = wyb[p * 36 + y];
                const float* frow = fc + y * WF;
                #pragma unroll
                for (int ii = 0; ii < 5; ++ii) {
                    int x = xlo + ii;
                    if (x <= xhi) acc = fmaf(wyv * wxv[ii], frow[x], acc);
                }
            }
            *(unsigned short*)(smem + XS_OFF + s * 512 + ((2 * c) ^ SWZ(s))) =
                bf16bits(acc * inv_area);
        }
    }
    __syncthreads();

    // ---- Phase C: bottleneck blocks ----
    for (int ib = 0; ib < NB; ++ib) {
        // ===== conv1: xs_t(256) -> t1t(128 interior), K=256 =====
        // wave w_ owns m-tile w_ (16 ch), iterates all 4 n-tiles
        {
            const int m0 = w_ * 16;
            f4_ acc[4] = {};
            #pragma unroll
            for (int ks = 0; ks < 8; ++ks) {
                const int kb = ks * 32 + kg * 8;
                bh8 a;
                if (USE_WS) a = ld_bh8(ws + W1OFF + ((size_t)(ib * BC + m0 + lr) * CH + kb) * 2);
                else        a = cvt8(w1 + (size_t)(ib * BC + m0 + lr) * CH + kb);
                #pragma unroll
                for (int nt = 0; nt < 4; ++nt) {
                    const int n = nt * 16 + lr;
                    bh8 b = ld_bh8(smem + XS_OFF + n * 512 + ((2 * kb) ^ SWZ(n)));
                    acc[nt] = __builtin_amdgcn_mfma_f32_16x16x32_bf16(a, b, acc[nt], 0, 0, 0);
                }
            }
            const int c0 = m0 + kg * 4;
            const float4 sv = *(const float4*)(s1 + ib * BC + c0);
            const float4 bv = *(const float4*)(b1 + ib * BC + c0);
            #pragma unroll
            for (int nt = 0; nt < 4; ++nt) {
                const int n = nt * 16 + lr;
                if (n < 49) {
                    const int row = (n / 7 + 1) * 9 + (n % 7 + 1);
                    float v0 = fmaxf(fmaf(acc[nt][0], sv.x, bv.x), 0.f);
                    float v1 = fmaxf(fmaf(acc[nt][1], sv.y, bv.y), 0.f);
                    float v2 = fmaxf(fmaf(acc[nt][2], sv.z, bv.z), 0.f);
                    float v3 = fmaxf(fmaf(acc[nt][3], sv.w, bv.w), 0.f);
                    *(uint2*)(smem + T1_OFF + row * 256 + ((2 * c0) ^ SWZ(row))) =
                        make_uint2(pk2(v0, v1), pk2(v2, v3));
                }
            }
        }
        __syncthreads();

        // ===== conv2: 3x3 as 9 tap-GEMMs, t1t(128) -> t2t(128) =====
        // outer ty loop NOT unrolled: only 12 weight loads (48 VGPR) in flight
        {
            const int m0 = w_ * 16;
            int trow0[4];
            #pragma unroll
            for (int nt = 0; nt < 4; ++nt) {
                const int n = nt * 16 + lr;
                trow0[nt] = (n < 49) ? (n / 7) * 9 + (n % 7) : 81;
            }
            f4_ acc[4] = {};
            #pragma unroll 1
            for (int ty = 0; ty < 3; ++ty) {
                bh8 aw[3][4];
                #pragma unroll
                for (int tx = 0; tx < 3; ++tx) {
                    #pragma unroll
                    for (int ks = 0; ks < 4; ++ks) {
                        const int tap = ty * 3 + tx;
                        const int kb = ks * 32 + kg * 8;
                        if (USE_WS) aw[tx][ks] = ld_bh8(ws + W2OFF + ((size_t)((ib * 9 + tap) * BC + m0 + lr) * BC + kb) * 2);
                        else        aw[tx][ks] = gather8(w2 + ((size_t)(ib * BC + m0 + lr) * BC + kb) * 9 + tap, 9);
                    }
                }
                #pragma unroll
                for (int tx = 0; tx < 3; ++tx) {
                    const int roff = ty * 9 + tx;
                    #pragma unroll
                    for (int ks = 0; ks < 4; ++ks) {
                        const int kb = ks * 32 + kg * 8;
                        #pragma unroll
                        for (int nt = 0; nt < 4; ++nt) {
                            const int row = trow0[nt] + roff;
                            bh8 b = ld_bh8(smem + T1_OFF + row * 256 + ((2 * kb) ^ SWZ(row)));
                            acc[nt] = __builtin_amdgcn_mfma_f32_16x16x32_bf16(aw[tx][ks], b, acc[nt], 0, 0, 0);
                        }
                    }
                }
            }
            const int c0 = m0 + kg * 4;
            const float4 sv = *(const float4*)(s2 + ib * BC + c0);
            const float4 bv = *(const float4*)(b2 + ib * BC + c0);
            #pragma unroll
            for (int nt = 0; nt < 4; ++nt) {
                const int n = nt * 16 + lr;
                if (n < 49) {
                    float v0 = fmaxf(fmaf(acc[nt][0], sv.x, bv.x), 0.f);
                    float v1 = fmaxf(fmaf(acc[nt][1], sv.y, bv.y), 0.f);
                    float v2 = fmaxf(fmaf(acc[nt][2], sv.z, bv.z), 0.f);
                    float v3 = fmaxf(fmaf(acc[nt][3], sv.w, bv.w), 0.f);
                    *(uint2*)(smem + T2_OFF + n * 256 + ((2 * c0) ^ SWZ(n))) =
                        make_uint2(pk2(v0, v1), pk2(v2, v3));
                }
            }
        }
        __syncthreads();

        // ===== conv3: t2t(128) -> xs_t(256) + residual + relu =====
        // wave w_ owns 2 m-tiles (32 ch), iterates all 4 n-tiles
        {
            const int m0 = w_ * 32;
            f4_ acc[2][4] = {};
            #pragma unroll
            for (int ks = 0; ks < 4; ++ks) {
                const int kb = ks * 32 + kg * 8;
                bh8 a[2];
                #pragma unroll
                for (int i = 0; i < 2; ++i) {
                    if (USE_WS) a[i] = ld_bh8(ws + W3OFF + ((size_t)(ib * CH + m0 + i * 16 + lr) * BC + kb) * 2);
                    else        a[i] = cvt8(w3 + (size_t)(ib * CH + m0 + i * 16 + lr) * BC + kb);
                }
                #pragma unroll
                for (int nt = 0; nt < 4; ++nt) {
                    const int n = nt * 16 + lr;
                    bh8 b = ld_bh8(smem + T2_OFF + n * 256 + ((2 * kb) ^ SWZ(n)));
                    #pragma unroll
                    for (int i = 0; i < 2; ++i)
                        acc[i][nt] = __builtin_amdgcn_mfma_f32_16x16x32_bf16(a[i], b, acc[i][nt], 0, 0, 0);
                }
            }
            #pragma unroll
            for (int nt = 0; nt < 4; ++nt) {
                const int n = nt * 16 + lr;
                if (n < 49) {
                    #pragma unroll
                    for (int i = 0; i < 2; ++i) {
                        const int c0 = m0 + i * 16 + kg * 4;
                        const float4 sv = *(const float4*)(s3 + ib * CH + c0);
                        const float4 bv = *(const float4*)(b3 + ib * CH + c0);
                        unsigned char* p = smem + XS_OFF + n * 512 + ((2 * c0) ^ SWZ(n));
                        const uint2 old = *(const uint2*)p;
                        float v0 = fmaxf(fmaf(acc[i][nt][0], sv.x, bv.x) + b2f(old.x & 0xFFFFu), 0.f);
                        float v1 = fmaxf(fmaf(acc[i][nt][1], sv.y, bv.y) + b2f(old.x >> 16), 0.f);
                        float v2 = fmaxf(fmaf(acc[i][nt][2], sv.z, bv.z) + b2f(old.y & 0xFFFFu), 0.f);
                        float v3 = fmaxf(fmaf(acc[i][nt][3], sv.w, bv.w) + b2f(old.y >> 16), 0.f);
                        *(uint2*)p = make_uint2(pk2(v0, v1), pk2(v2, v3));
                    }
                }
            }
        }
        __syncthreads();
    }

    // ---- Phase D: deconv quadrants + mask head ----
    for (int quad = 0; quad < 4; ++quad) {
        {
            const int m0 = w_ * 32;
            f4_ acc[2][4] = {};
            // split K into 2 halves: only 8 weight loads (32 VGPR) in flight
            #pragma unroll 1
            for (int kh = 0; kh < 2; ++kh) {
                bh8 aw[4][2];
                #pragma unroll
                for (int k4 = 0; k4 < 4; ++k4) {
                    const int kb = (kh * 4 + k4) * 32 + kg * 8;
                    #pragma unroll
                    for (int i = 0; i < 2; ++i) {
                        if (USE_WS) aw[k4][i] = ld_bh8(ws + WTOFF + ((size_t)(quad * CH + m0 + i * 16 + lr) * CH + kb) * 2);
                        else        aw[k4][i] = gather8(wt + (size_t)kb * 1024 + (m0 + i * 16 + lr) * 4 + quad, 1024);
                    }
                }
                #pragma unroll
                for (int k4 = 0; k4 < 4; ++k4) {
                    const int kb = (kh * 4 + k4) * 32 + kg * 8;
                    #pragma unroll
                    for (int nt = 0; nt < 4; ++nt) {
                        const int n = nt * 16 + lr;
                        bh8 b = ld_bh8(smem + XS_OFF + n * 512 + ((2 * kb) ^ SWZ(n)));
                        #pragma unroll
                        for (int i = 0; i < 2; ++i)
                            acc[i][nt] = __builtin_amdgcn_mfma_f32_16x16x32_bf16(aw[k4][i], b, acc[i][nt], 0, 0, 0);
                    }
                }
            }
            #pragma unroll
            for (int nt = 0; nt < 4; ++nt) {
                const int n = nt * 16 + lr;
                if (n < 49) {
                    #pragma unroll
                    for (int i = 0; i < 2; ++i) {
                        const int c0 = m0 + i * 16 + kg * 4;
                        const float4 bv = *(const float4*)(bt + c0);
                        float v0 = fmaxf(acc[i][nt][0] + bv.x, 0.f);
                        float v1 = fmaxf(acc[i][nt][1] + bv.y, 0.f);
                        float v2 = fmaxf(acc[i][nt][2] + bv.z, 0.f);
                        float v3 = fmaxf(acc[i][nt][3] + bv.w, 0.f);
                        *(uint2*)(smem + DB_OFF + n * 512 + ((2 * c0) ^ SWZ(n))) =
                            make_uint2(pk2(v0, v1), pk2(v2, v3));
                    }
                }
            }
        }
        __syncthreads();

        // mask head: logit[s] = bm + sum_c wm[c]*dbuf[s][c]
        {
            const int s = tid & 63, ch_ = tid >> 6;
            if (s < 49) {
                float part = 0.f;
                #pragma unroll
                for (int ii = 0; ii < 4; ++ii) {
                    const int c0 = ch_ * 32 + ii * 8;
                    bh8 v = ld_bh8(smem + DB_OFF + s * 512 + ((2 * c0) ^ SWZ(s)));
                    const float4 wa = *(const float4*)(wm + c0);
                    const float4 wb = *(const float4*)(wm + c0 + 4);
                    part = fmaf(wa.x, (float)v[0], part);
                    part = fmaf(wa.y, (float)v[1], part);
                    part = fmaf(wa.z, (float)v[2], part);
                    part = fmaf(wa.w, (float)v[3], part);
                    part = fmaf(wb.x, (float)v[4], part);
                    part = fmaf(wb.y, (float)v[5], part);
                    part = fmaf(wb.z, (float)v[6], part);
                    part = fmaf(wb.w, (float)v[7], part);
                }
                red[s * 8 + ch_] = part;
            }
        }
        __syncthreads();
        if (tid < 49) {
            float lg = bm[0];
            #pragma unroll
            for (int ch_ = 0; ch_ < 8; ++ch_) lg += red[tid * 8 + ch_];
            const int p = tid / 7, q = tid - p * 7;
            const int dy = quad >> 1, dx = quad & 1;
            out[(size_t)r * 196 + (2 * p + dy) * 14 + (2 * q + dx)] =
                1.f / (1.f + expf(-lg));
        }
        __syncthreads();
    }
}

extern "C" void kernel_launch(void* const* d_in, const int* in_sizes, int n_in,
                              void* d_out, int out_size, void* d_ws, size_t ws_size,
                              hipStream_t stream) {
    const float* feat = (const float*)d_in[0];
    const float* bbox = (const float*)d_in[1];
    const float* w1   = (const float*)d_in[2];
    const float* s1   = (const float*)d_in[3];
    const float* b1   = (const float*)d_in[4];
    const float* w2   = (const float*)d_in[5];
    const float* s2   = (const float*)d_in[6];
    const float* b2   = (const float*)d_in[7];
    const float* w3   = (const float*)d_in[8];
    const float* s3   = (const float*)d_in[9];
    const float* b3   = (const float*)d_in[10];
    const float* wt   = (const float*)d_in[11];
    const float* bt   = (const float*)d_in[12];
    const float* wm   = (const float*)d_in[13];
    const float* bm   = (const float*)d_in[14];
    float* out = (float*)d_out;

    if (ws_size >= (size_t)WS_BYTES) {
        unsigned char* ws = (unsigned char*)d_ws;
        hipLaunchKernelGGL(prepass, dim3(1024), dim3(256), 0, stream, w1, w2, w3, wt, ws);
        hipLaunchKernelGGL((masknet_mfma<1>), dim3(NROI), dim3(NT), 0, stream,
                           feat, bbox, w1, s1, b1, w2, s2, b2, w3, s3, b3,
                           wt, bt, wm, bm, ws, out);
    } else {
        hipLaunchKernelGGL((masknet_mfma<0>), dim3(NROI), dim3(NT), 0, stream,
                           feat, bbox, w1, s1, b1, w2, s2, b2, w3, s3, b3,
                           wt, bt, wm, bm, (const unsigned char*)nullptr, out);
    }
}

// Round 7
// 182.688 us; speedup vs baseline: 6.1190x; 1.4841x over previous
//
#include <hip/hip_runtime.h>
#include <math.h>

#define RESQ 7
#define CH   256
#define HF   36
#define WF   36
#define NROI 512
#define BC   128
#define NB   3
#define NT   512

typedef __bf16 bh8 __attribute__((ext_vector_type(8)));
typedef float  f4_ __attribute__((ext_vector_type(4)));

// ---- d_ws layout (bytes) ----
#define W1OFF 0            // [3][128][256] bf16  -> 196608 B
#define W2OFF 196608       // [3][9][128][128] bf16 (tap-major) -> 884736 B
#define W3OFF 1081344      // [3][256][128] bf16 -> 196608 B
#define WTOFF 1277952      // [4][256 co][256 ci] bf16 -> 524288 B
#define WS_BYTES 1802240
#define FTOFF 1802240      // feat_t [16][36][36][256] bf16 -> 10616832 B
#define WS_FULL 12419072
#define PRE_ELEMS 901120   // 98304 + 442368 + 98304 + 262144

// ---- LDS layout (bytes) ----
#define XS_OFF 0           // xs_t [49 sp][256 ch] bf16 = 25088
#define T1_OFF 25088       // t1t  [81 rows][128 ch] bf16 = 20736
#define T2_OFF 45824       // t2t  [49 sp][128 ch] bf16 = 12544
#define WY_OFF 58368       // 252 f32
#define WX_OFF 59376       // 252 f32
#define RED_OFF 60384      // [64][8] f32 = 2048
#define LDS_BYTES 62432
#define DB_OFF T1_OFF      // dbuf [49 sp][256 ch] bf16 = 25088 (overlays t1t+t2t)

#define SWZ(row) (((row) & 7) << 4)

__device__ __forceinline__ float Fk(float t) {
    t = fminf(1.f, fmaxf(-1.f, t));
    float a = t + 1.f, b = 1.f - t;
    return (t < 0.f) ? 0.5f * a * a : 1.f - 0.5f * b * b;
}

// ---- register-only bf16 bit manipulation ----
__device__ __forceinline__ unsigned short bf16bits(float a) {
    return __builtin_bit_cast(unsigned short, (__bf16)a);
}
__device__ __forceinline__ unsigned int pk2(float a, float b) {
    return (unsigned int)bf16bits(a) | ((unsigned int)bf16bits(b) << 16);
}
__device__ __forceinline__ float b2f(unsigned int s) {
    return __builtin_bit_cast(float, s << 16);
}

__device__ __forceinline__ bh8 ld_bh8(const unsigned char* p) {
    return *(const bh8*)p;
}
__device__ __forceinline__ bh8 cvt8(const float* p) {
    float4 a = *(const float4*)p;
    float4 b = *(const float4*)(p + 4);
    bh8 r;
    r[0]=(__bf16)a.x; r[1]=(__bf16)a.y; r[2]=(__bf16)a.z; r[3]=(__bf16)a.w;
    r[4]=(__bf16)b.x; r[5]=(__bf16)b.y; r[6]=(__bf16)b.z; r[7]=(__bf16)b.w;
    return r;
}
__device__ __forceinline__ bh8 gather8(const float* p, int stride) {
    bh8 r;
    #pragma unroll
    for (int j = 0; j < 8; ++j) r[j] = (__bf16)p[j * stride];
    return r;
}

// ---------------- prepass: weights f32->bf16 (+transposes) and feat transpose ----------------
extern "C" __global__ void prep_all(const float* __restrict__ feat,
                                    const float* __restrict__ w1,
                                    const float* __restrict__ w2,
                                    const float* __restrict__ w3,
                                    const float* __restrict__ wt,
                                    unsigned char* __restrict__ ws,
                                    int do_ft) {
    __shared__ unsigned short tile[36 * 256];
    if (do_ft && blockIdx.x < 576) {
        // transpose one (frame, y) row-plane: feat[b][c][y][x] -> feat_t[b][y][x][c]
        const int b = blockIdx.x / 36, y = blockIdx.x % 36;
        const int c = threadIdx.x;  // 256 threads
        const float* src = feat + (size_t)(b * 256 + c) * 1296 + y * 36;
        float4 fv[9];
        #pragma unroll
        for (int i = 0; i < 9; ++i) fv[i] = *(const float4*)(src + i * 4);
        #pragma unroll
        for (int i = 0; i < 9; ++i) {
            tile[(i * 4 + 0) * 256 + c] = bf16bits(fv[i].x);
            tile[(i * 4 + 1) * 256 + c] = bf16bits(fv[i].y);
            tile[(i * 4 + 2) * 256 + c] = bf16bits(fv[i].z);
            tile[(i * 4 + 3) * 256 + c] = bf16bits(fv[i].w);
        }
        __syncthreads();
        unsigned short* dst = (unsigned short*)(ws + FTOFF) + (size_t)(b * 36 + y) * 36 * 256;
        for (int x = 0; x < 36; ++x) dst[x * 256 + c] = tile[x * 256 + c];
        return;
    }
    const int base = do_ft ? 576 : 0;
    const int nb = gridDim.x - base;
    for (int i = (blockIdx.x - base) * blockDim.x + threadIdx.x; i < PRE_ELEMS;
         i += nb * blockDim.x) {
        if (i < 98304) {
            ((__bf16*)(ws + W1OFF))[i] = (__bf16)w1[i];
        } else if (i < 98304 + 442368) {
            int d = i - 98304;
            int ib = d / 147456, r = d - ib * 147456;
            int tap = r / 16384, r2 = r - tap * 16384;
            int m = r2 >> 7, ci = r2 & 127;
            ((__bf16*)(ws + W2OFF))[d] = (__bf16)w2[((ib * BC + m) * BC + ci) * 9 + tap];
        } else if (i < 98304 + 442368 + 98304) {
            int d = i - (98304 + 442368);
            ((__bf16*)(ws + W3OFF))[d] = (__bf16)w3[d];
        } else {
            int d = i - (98304 + 442368 + 98304);
            int quad = d >> 16, r = d & 65535;
            int co = r >> 8, ci = r & 255;
            ((__bf16*)(ws + WTOFF))[d] = (__bf16)wt[ci * 1024 + co * 4 + quad];
        }
    }
}

// ---------------- fused main kernel ----------------
template<int USE_WS, int USE_FT>
__global__ __launch_bounds__(NT, 2)
void masknet_mfma(const float* __restrict__ feat,
                  const float* __restrict__ bbox,
                  const float* __restrict__ w1, const float* __restrict__ s1, const float* __restrict__ b1,
                  const float* __restrict__ w2, const float* __restrict__ s2, const float* __restrict__ b2,
                  const float* __restrict__ w3, const float* __restrict__ s3, const float* __restrict__ b3,
                  const float* __restrict__ wt, const float* __restrict__ bt,
                  const float* __restrict__ wm, const float* __restrict__ bm,
                  const unsigned char* __restrict__ ws,
                  float* __restrict__ out)
{
    __shared__ __align__(16) unsigned char smem[LDS_BYTES];
    float* wyb = (float*)(smem + WY_OFF);
    float* wxb = (float*)(smem + WX_OFF);
    float* red = (float*)(smem + RED_OFF);

    const int tid  = threadIdx.x;
    const int r    = blockIdx.x;
    const int bfr  = r >> 5;
    const int lane = tid & 63;
    const int lr   = lane & 15;
    const int kg   = lane >> 4;
    const int w_   = tid >> 6;

    // ---- ROI params ----
    const float S = 1.f / 16.f;
    const float bx = bbox[r*4+0], by = bbox[r*4+1];
    const float bw_ = bbox[r*4+2], bh_ = bbox[r*4+3];
    const float x1 = bx * S, y1 = by * S;
    const float bwx = (bw_ * S) * (1.f / RESQ);
    const float bwy = (bh_ * S) * (1.f / RESQ);
    const float area = bwx * bwy;
    const float inv_area = (area > 0.f) ? 1.f / fmaxf(area, 1e-12f) : 0.f;

    // ---- Phase A: integral tables + zero T1 (padding border) ----
    if (tid < 252) {
        int p = tid / 36, i = tid - p * 36;
        float st = y1 + bwy * p, en = st + bwy;
        wyb[tid] = Fk(en - (float)i) - Fk(st - (float)i);
    } else if (tid >= 256 && tid < 508) {
        int t = tid - 256;
        int q = t / 36, i = t - q * 36;
        float st = x1 + bwx * q, en = st + bwx;
        wxb[t] = Fk(en - (float)i) - Fk(st - (float)i);
    }
    {   // zero t1t (20736 B = 1296 uint4)
        uint4* z = (uint4*)(smem + T1_OFF);
        for (int o = tid; o < 1296; o += NT) z[o] = make_uint4(0,0,0,0);
    }
    __syncthreads();

    // ---- Phase B: PrRoI pool -> xs_t[s][c] bf16 (swizzled) ----
    if (USE_FT) {
        // coalesced path: wave per bin, lanes over channels (feat_t channel-last)
        const unsigned short* ft = (const unsigned short*)(ws + FTOFF) + (size_t)bfr * (1296 * 256);
        for (int s = w_; s < 49; s += 8) {
            const int p = s / 7, q = s - (s / 7) * 7;
            const float sy = y1 + bwy * p, sx = x1 + bwx * q;
            const int ylo = max(0, (int)floorf(sy)), yhi = min(35, (int)ceilf(sy + bwy));
            const int xlo = max(0, (int)floorf(sx)), xhi = min(35, (int)ceilf(sx + bwx));
            float a0 = 0.f, a1 = 0.f, a2 = 0.f, a3 = 0.f;
            for (int y = ylo; y <= yhi; ++y) {
                const float wy = wyb[p * 36 + y] * inv_area;
                const unsigned short* frow = ft + (size_t)(y * 36) * 256 + lane * 4;
                for (int x = xlo; x <= xhi; ++x) {
                    const float wgt = wy * wxb[q * 36 + x];
                    ushort4 v = *(const ushort4*)(frow + x * 256);
                    a0 = fmaf(wgt, b2f(v.x), a0);
                    a1 = fmaf(wgt, b2f(v.y), a1);
                    a2 = fmaf(wgt, b2f(v.z), a2);
                    a3 = fmaf(wgt, b2f(v.w), a3);
                }
            }
            *(uint2*)(smem + XS_OFF + s * 512 + ((8 * lane) ^ SWZ(s))) =
                make_uint2(pk2(a0, a1), pk2(a2, a3));
        }
    } else {
        const float* fb = feat + (size_t)bfr * CH * HF * WF;
        for (int o = tid; o < CH * 49; o += NT) {
            int c = o / 49, s = o - c * 49;
            int p = s / 7, q = s - p * 7;
            float sy = y1 + bwy * p, ey = sy + bwy;
            float sx = x1 + bwx * q, ex = sx + bwx;
            int ylo = max(0, (int)floorf(sy)), yhi = min(HF - 1, (int)ceilf(ey));
            int xlo = max(0, (int)floorf(sx)), xhi = min(WF - 1, (int)ceilf(ex));
            float wxv[5];
            #pragma unroll
            for (int ii = 0; ii < 5; ++ii) {
                int x = xlo + ii;
                wxv[ii] = (x <= xhi) ? wxb[q * 36 + x] : 0.f;
            }
            const float* fc = fb + c * (HF * WF);
            float acc = 0.f;
            for (int y = ylo; y <= yhi; ++y) {
                float wyv = wyb[p * 36 + y];
                const float* frow = fc + y * WF;
                #pragma unroll
                for (int ii = 0; ii < 5; ++ii) {
                    int x = xlo + ii;
                    if (x <= xhi) acc = fmaf(wyv * wxv[ii], frow[x], acc);
                }
            }
            *(unsigned short*)(smem + XS_OFF + s * 512 + ((2 * c) ^ SWZ(s))) =
                bf16bits(acc * inv_area);
        }
    }
    __syncthreads();

    // per-lane clamped B-row indices (rows >= 49 are don't-care lanes)
    int nld[4], trow0[4];
    #pragma unroll
    for (int nt = 0; nt < 4; ++nt) {
        const int n = nt * 16 + lr;
        nld[nt]   = (n < 49) ? n : 48;
        trow0[nt] = (n < 49) ? (n / 7) * 9 + (n % 7) : 0;
    }

    // ---- Phase C: bottleneck blocks ----
    for (int ib = 0; ib < NB; ++ib) {
        // ===== conv1: xs_t(256) -> t1t(128 interior), K=256 =====
        {
            const int m0 = w_ * 16;
            f4_ acc[4] = {};
            #pragma unroll
            for (int ks = 0; ks < 8; ++ks) {
                const int kb = ks * 32 + kg * 8;
                bh8 a;
                if (USE_WS) a = ld_bh8(ws + W1OFF + ((size_t)(ib * BC + m0 + lr) * CH + kb) * 2);
                else        a = cvt8(w1 + (size_t)(ib * BC + m0 + lr) * CH + kb);
                #pragma unroll
                for (int nt = 0; nt < 4; ++nt) {
                    const int n_ = nld[nt];
                    bh8 b = ld_bh8(smem + XS_OFF + n_ * 512 + ((2 * kb) ^ SWZ(n_)));
                    acc[nt] = __builtin_amdgcn_mfma_f32_16x16x32_bf16(a, b, acc[nt], 0, 0, 0);
                }
            }
            const int c0 = m0 + kg * 4;
            const float4 sv = *(const float4*)(s1 + ib * BC + c0);
            const float4 bv = *(const float4*)(b1 + ib * BC + c0);
            #pragma unroll
            for (int nt = 0; nt < 4; ++nt) {
                const int n = nt * 16 + lr;
                if (n < 49) {
                    const int row = (n / 7 + 1) * 9 + (n % 7 + 1);
                    float v0 = fmaxf(fmaf(acc[nt][0], sv.x, bv.x), 0.f);
                    float v1 = fmaxf(fmaf(acc[nt][1], sv.y, bv.y), 0.f);
                    float v2 = fmaxf(fmaf(acc[nt][2], sv.z, bv.z), 0.f);
                    float v3 = fmaxf(fmaf(acc[nt][3], sv.w, bv.w), 0.f);
                    *(uint2*)(smem + T1_OFF + row * 256 + ((2 * c0) ^ SWZ(row))) =
                        make_uint2(pk2(v0, v1), pk2(v2, v3));
                }
            }
        }
        __syncthreads();

        // ===== conv2: 3x3 as 9 tap-GEMMs, t1t(128) -> t2t(128) =====
        {
            const int m0 = w_ * 16;
            f4_ acc[4] = {};
            #pragma unroll 1
            for (int ty = 0; ty < 3; ++ty) {
                bh8 aw[3][4];
                #pragma unroll
                for (int tx = 0; tx < 3; ++tx) {
                    #pragma unroll
                    for (int ks = 0; ks < 4; ++ks) {
                        const int tap = ty * 3 + tx;
                        const int kb = ks * 32 + kg * 8;
                        if (USE_WS) aw[tx][ks] = ld_bh8(ws + W2OFF + ((size_t)((ib * 9 + tap) * BC + m0 + lr) * BC + kb) * 2);
                        else        aw[tx][ks] = gather8(w2 + ((size_t)(ib * BC + m0 + lr) * BC + kb) * 9 + tap, 9);
                    }
                }
                #pragma unroll
                for (int tx = 0; tx < 3; ++tx) {
                    const int roff = ty * 9 + tx;
                    #pragma unroll
                    for (int ks = 0; ks < 4; ++ks) {
                        const int kb = ks * 32 + kg * 8;
                        #pragma unroll
                        for (int nt = 0; nt < 4; ++nt) {
                            const int row = trow0[nt] + roff;
                            bh8 b = ld_bh8(smem + T1_OFF + row * 256 + ((2 * kb) ^ SWZ(row)));
                            acc[nt] = __builtin_amdgcn_mfma_f32_16x16x32_bf16(aw[tx][ks], b, acc[nt], 0, 0, 0);
                        }
                    }
                }
            }
            const int c0 = m0 + kg * 4;
            const float4 sv = *(const float4*)(s2 + ib * BC + c0);
            const float4 bv = *(const float4*)(b2 + ib * BC + c0);
            #pragma unroll
            for (int nt = 0; nt < 4; ++nt) {
                const int n = nt * 16 + lr;
                if (n < 49) {
                    float v0 = fmaxf(fmaf(acc[nt][0], sv.x, bv.x), 0.f);
                    float v1 = fmaxf(fmaf(acc[nt][1], sv.y, bv.y), 0.f);
                    float v2 = fmaxf(fmaf(acc[nt][2], sv.z, bv.z), 0.f);
                    float v3 = fmaxf(fmaf(acc[nt][3], sv.w, bv.w), 0.f);
                    *(uint2*)(smem + T2_OFF + n * 256 + ((2 * c0) ^ SWZ(n))) =
                        make_uint2(pk2(v0, v1), pk2(v2, v3));
                }
            }
        }
        __syncthreads();

        // ===== conv3: t2t(128) -> xs_t(256) + residual + relu =====
        {
            const int m0 = w_ * 32;
            f4_ acc[2][4] = {};
            #pragma unroll
            for (int ks = 0; ks < 4; ++ks) {
                const int kb = ks * 32 + kg * 8;
                bh8 a[2];
                #pragma unroll
                for (int i = 0; i < 2; ++i) {
                    if (USE_WS) a[i] = ld_bh8(ws + W3OFF + ((size_t)(ib * CH + m0 + i * 16 + lr) * BC + kb) * 2);
                    else        a[i] = cvt8(w3 + (size_t)(ib * CH + m0 + i * 16 + lr) * BC + kb);
                }
                #pragma unroll
                for (int nt = 0; nt < 4; ++nt) {
                    const int n_ = nld[nt];
                    bh8 b = ld_bh8(smem + T2_OFF + n_ * 256 + ((2 * kb) ^ SWZ(n_)));
                    #pragma unroll
                    for (int i = 0; i < 2; ++i)
                        acc[i][nt] = __builtin_amdgcn_mfma_f32_16x16x32_bf16(a[i], b, acc[i][nt], 0, 0, 0);
                }
            }
            #pragma unroll
            for (int nt = 0; nt < 4; ++nt) {
                const int n = nt * 16 + lr;
                if (n < 49) {
                    #pragma unroll
                    for (int i = 0; i < 2; ++i) {
                        const int c0 = m0 + i * 16 + kg * 4;
                        const float4 sv = *(const float4*)(s3 + ib * CH + c0);
                        const float4 bv = *(const float4*)(b3 + ib * CH + c0);
                        unsigned char* p = smem + XS_OFF + n * 512 + ((2 * c0) ^ SWZ(n));
                        const uint2 old = *(const uint2*)p;
                        float v0 = fmaxf(fmaf(acc[i][nt][0], sv.x, bv.x) + b2f(old.x & 0xFFFFu), 0.f);
                        float v1 = fmaxf(fmaf(acc[i][nt][1], sv.y, bv.y) + b2f(old.x >> 16), 0.f);
                        float v2 = fmaxf(fmaf(acc[i][nt][2], sv.z, bv.z) + b2f(old.y & 0xFFFFu), 0.f);
                        float v3 = fmaxf(fmaf(acc[i][nt][3], sv.w, bv.w) + b2f(old.y >> 16), 0.f);
                        *(uint2*)p = make_uint2(pk2(v0, v1), pk2(v2, v3));
                    }
                }
            }
        }
        __syncthreads();
    }

    // ---- Phase D: deconv quadrants + mask head ----
    for (int quad = 0; quad < 4; ++quad) {
        {
            const int m0 = w_ * 32;
            f4_ acc[2][4] = {};
            #pragma unroll 1
            for (int kh = 0; kh < 2; ++kh) {
                bh8 aw[4][2];
                #pragma unroll
                for (int k4 = 0; k4 < 4; ++k4) {
                    const int kb = (kh * 4 + k4) * 32 + kg * 8;
                    #pragma unroll
                    for (int i = 0; i < 2; ++i) {
                        if (USE_WS) aw[k4][i] = ld_bh8(ws + WTOFF + ((size_t)(quad * CH + m0 + i * 16 + lr) * CH + kb) * 2);
                        else        aw[k4][i] = gather8(wt + (size_t)kb * 1024 + (m0 + i * 16 + lr) * 4 + quad, 1024);
                    }
                }
                #pragma unroll
                for (int k4 = 0; k4 < 4; ++k4) {
                    const int kb = (kh * 4 + k4) * 32 + kg * 8;
                    #pragma unroll
                    for (int nt = 0; nt < 4; ++nt) {
                        const int n_ = nld[nt];
                        bh8 b = ld_bh8(smem + XS_OFF + n_ * 512 + ((2 * kb) ^ SWZ(n_)));
                        #pragma unroll
                        for (int i = 0; i < 2; ++i)
                            acc[i][nt] = __builtin_amdgcn_mfma_f32_16x16x32_bf16(aw[k4][i], b, acc[i][nt], 0, 0, 0);
                    }
                }
            }
            #pragma unroll
            for (int nt = 0; nt < 4; ++nt) {
                const int n = nt * 16 + lr;
                if (n < 49) {
                    #pragma unroll
                    for (int i = 0; i < 2; ++i) {
                        const int c0 = m0 + i * 16 + kg * 4;
                        const float4 bv = *(const float4*)(bt + c0);
                        float v0 = fmaxf(acc[i][nt][0] + bv.x, 0.f);
                        float v1 = fmaxf(acc[i][nt][1] + bv.y, 0.f);
                        float v2 = fmaxf(acc[i][nt][2] + bv.z, 0.f);
                        float v3 = fmaxf(acc[i][nt][3] + bv.w, 0.f);
                        *(uint2*)(smem + DB_OFF + n * 512 + ((2 * c0) ^ SWZ(n))) =
                            make_uint2(pk2(v0, v1), pk2(v2, v3));
                    }
                }
            }
        }
        __syncthreads();

        // mask head: logit[s] = bm + sum_c wm[c]*dbuf[s][c]
        {
            const int s = tid & 63, ch_ = tid >> 6;
            if (s < 49) {
                float part = 0.f;
                #pragma unroll
                for (int ii = 0; ii < 4; ++ii) {
                    const int c0 = ch_ * 32 + ii * 8;
                    bh8 v = ld_bh8(smem + DB_OFF + s * 512 + ((2 * c0) ^ SWZ(s)));
                    const float4 wa = *(const float4*)(wm + c0);
                    const float4 wb = *(const float4*)(wm + c0 + 4);
                    part = fmaf(wa.x, (float)v[0], part);
                    part = fmaf(wa.y, (float)v[1], part);
                    part = fmaf(wa.z, (float)v[2], part);
                    part = fmaf(wa.w, (float)v[3], part);
                    part = fmaf(wb.x, (float)v[4], part);
                    part = fmaf(wb.y, (float)v[5], part);
                    part = fmaf(wb.z, (float)v[6], part);
                    part = fmaf(wb.w, (float)v[7], part);
                }
                red[s * 8 + ch_] = part;
            }
        }
        __syncthreads();
        if (tid < 49) {
            float lg = bm[0];
            #pragma unroll
            for (int ch_ = 0; ch_ < 8; ++ch_) lg += red[tid * 8 + ch_];
            const int p = tid / 7, q = tid - p * 7;
            const int dy = quad >> 1, dx = quad & 1;
            out[(size_t)r * 196 + (2 * p + dy) * 14 + (2 * q + dx)] =
                1.f / (1.f + expf(-lg));
        }
        __syncthreads();
    }
}

extern "C" void kernel_launch(void* const* d_in, const int* in_sizes, int n_in,
                              void* d_out, int out_size, void* d_ws, size_t ws_size,
                              hipStream_t stream) {
    const float* feat = (const float*)d_in[0];
    const float* bbox = (const float*)d_in[1];
    const float* w1   = (const float*)d_in[2];
    const float* s1   = (const float*)d_in[3];
    const float* b1   = (const float*)d_in[4];
    const float* w2   = (const float*)d_in[5];
    const float* s2   = (const float*)d_in[6];
    const float* b2   = (const float*)d_in[7];
    const float* w3   = (const float*)d_in[8];
    const float* s3   = (const float*)d_in[9];
    const float* b3   = (const float*)d_in[10];
    const float* wt   = (const float*)d_in[11];
    const float* bt   = (const float*)d_in[12];
    const float* wm   = (const float*)d_in[13];
    const float* bm   = (const float*)d_in[14];
    float* out = (float*)d_out;

    if (ws_size >= (size_t)WS_FULL) {
        unsigned char* ws = (unsigned char*)d_ws;
        hipLaunchKernelGGL(prep_all, dim3(1024), dim3(256), 0, stream,
                           feat, w1, w2, w3, wt, ws, 1);
        hipLaunchKernelGGL((masknet_mfma<1,1>), dim3(NROI), dim3(NT), 0, stream,
                           feat, bbox, w1, s1, b1, w2, s2, b2, w3, s3, b3,
                           wt, bt, wm, bm, ws, out);
    } else if (ws_size >= (size_t)WS_BYTES) {
        unsigned char* ws = (unsigned char*)d_ws;
        hipLaunchKernelGGL(prep_all, dim3(448), dim3(256), 0, stream,
                           feat, w1, w2, w3, wt, ws, 0);
        hipLaunchKernelGGL((masknet_mfma<1,0>), dim3(NROI), dim3(NT), 0, stream,
                           feat, bbox, w1, s1, b1, w2, s2, b2, w3, s3, b3,
                           wt, bt, wm, bm, ws, out);
    } else {
        hipLaunchKernelGGL((masknet_mfma<0,0>), dim3(NROI), dim3(NT), 0, stream,
                           feat, bbox, w1, s1, b1, w2, s2, b2, w3, s3, b3,
                           wt, bt, wm, bm, (const unsigned char*)nullptr, out);
    }
}

// Round 8
// 154.284 us; speedup vs baseline: 7.2456x; 1.1841x over previous
//
#include <hip/hip_runtime.h>
#include <math.h>

#define RESQ 7
#define CH   256
#define NROI 512
#define BC   128
#define NB   3
#define NT   512

typedef __bf16 bh8  __attribute__((ext_vector_type(8)));
typedef float  f16v __attribute__((ext_vector_type(16)));

// ---- d_ws layout (bytes): fragment-major A panels ----
#define A1OFF 0            // [3 ib][4 mt][16 t][64 lane][8] bf16 = 196608
#define A2OFF 196608       // [3][9 tap][4 mt][8 t][64][8]       = 884736
#define A3OFF 1081344      // [3][8 mt][8 t][64][8]              = 196608
#define ATOFF 1277952      // [4 quad][8 mt][16 t][64][8]        = 524288
#define WS_BYTES 1802240
#define FTOFF 1802240      // feat_t [16][36][36][256] bf16 -> 10616832 B
#define WS_FULL 12419072
#define PRE_ELEMS 901120

// ---- LDS (bytes) ----
#define XS_OFF 0           // xs [49 sp][256 ch] bf16, stride 512
#define T1_OFF 25088       // t1 [81 rows][128 ch] bf16, stride 256
#define T2_OFF 45824       // t2 [49 sp][128 ch] bf16, stride 256
#define WY_OFF 58368       // 252 f32
#define WX_OFF 59376       // 252 f32
#define LG_OFF 60384       // logits [4 quad][64] f32 = 1024
#define LDS_BYTES 61440

#define SWZ(row) (((row) & 7) << 4)

__device__ __forceinline__ float Fk(float t) {
    t = fminf(1.f, fmaxf(-1.f, t));
    float a = t + 1.f, b = 1.f - t;
    return (t < 0.f) ? 0.5f * a * a : 1.f - 0.5f * b * b;
}
__device__ __forceinline__ unsigned short bf16bits(float a) {
    return __builtin_bit_cast(unsigned short, (__bf16)a);
}
__device__ __forceinline__ unsigned int pk2(float a, float b) {
    return (unsigned int)bf16bits(a) | ((unsigned int)bf16bits(b) << 16);
}
__device__ __forceinline__ float b2f(unsigned int s) {
    return __builtin_bit_cast(float, s << 16);
}
__device__ __forceinline__ bh8 ld_bh8(const unsigned char* p) { return *(const bh8*)p; }
__device__ __forceinline__ bh8 cvt8(const float* p) {
    float4 a = *(const float4*)p;
    float4 b = *(const float4*)(p + 4);
    bh8 r;
    r[0]=(__bf16)a.x; r[1]=(__bf16)a.y; r[2]=(__bf16)a.z; r[3]=(__bf16)a.w;
    r[4]=(__bf16)b.x; r[5]=(__bf16)b.y; r[6]=(__bf16)b.z; r[7]=(__bf16)b.w;
    return r;
}
__device__ __forceinline__ bh8 gather8(const float* p, int stride) {
    bh8 r;
    #pragma unroll
    for (int j = 0; j < 8; ++j) r[j] = (__bf16)p[j * stride];
    return r;
}

// epilogue helpers (compile-time reg indices only)
__device__ __forceinline__ void epi_store(const f16v acc, int chbase, int h,
        const float* sarr, const float* barr, unsigned char* rowbase, int rswz) {
    #pragma unroll
    for (int g = 0; g < 4; ++g) {
        const int ch = chbase + 8*g + 4*h;
        const float4 sv = *(const float4*)(sarr + ch);
        const float4 bv = *(const float4*)(barr + ch);
        float v0 = fmaxf(fmaf(acc[4*g+0], sv.x, bv.x), 0.f);
        float v1 = fmaxf(fmaf(acc[4*g+1], sv.y, bv.y), 0.f);
        float v2 = fmaxf(fmaf(acc[4*g+2], sv.z, bv.z), 0.f);
        float v3 = fmaxf(fmaf(acc[4*g+3], sv.w, bv.w), 0.f);
        *(uint2*)(rowbase + ((2*ch) ^ rswz)) = make_uint2(pk2(v0,v1), pk2(v2,v3));
    }
}
__device__ __forceinline__ void epi_res(const f16v acc, int chbase, int h,
        const float* sarr, const float* barr, unsigned char* rowbase, int rswz) {
    #pragma unroll
    for (int g = 0; g < 4; ++g) {
        const int ch = chbase + 8*g + 4*h;
        const float4 sv = *(const float4*)(sarr + ch);
        const float4 bv = *(const float4*)(barr + ch);
        unsigned char* p = rowbase + ((2*ch) ^ rswz);
        const uint2 old = *(const uint2*)p;
        float v0 = fmaxf(fmaf(acc[4*g+0], sv.x, bv.x) + b2f(old.x & 0xFFFFu), 0.f);
        float v1 = fmaxf(fmaf(acc[4*g+1], sv.y, bv.y) + b2f(old.x >> 16), 0.f);
        float v2 = fmaxf(fmaf(acc[4*g+2], sv.z, bv.z) + b2f(old.y & 0xFFFFu), 0.f);
        float v3 = fmaxf(fmaf(acc[4*g+3], sv.w, bv.w) + b2f(old.y >> 16), 0.f);
        *(uint2*)p = make_uint2(pk2(v0,v1), pk2(v2,v3));
    }
}
__device__ __forceinline__ float dq_part(const f16v acc, int chbase, int h,
        const float* bt, const float* wm) {
    float part = 0.f;
    #pragma unroll
    for (int g = 0; g < 4; ++g) {
        const int ch = chbase + 8*g + 4*h;
        const float4 btv = *(const float4*)(bt + ch);
        const float4 wmv = *(const float4*)(wm + ch);
        part = fmaf(wmv.x, fmaxf(acc[4*g+0] + btv.x, 0.f), part);
        part = fmaf(wmv.y, fmaxf(acc[4*g+1] + btv.y, 0.f), part);
        part = fmaf(wmv.z, fmaxf(acc[4*g+2] + btv.z, 0.f), part);
        part = fmaf(wmv.w, fmaxf(acc[4*g+3] + btv.w, 0.f), part);
    }
    return part;
}

// ---------------- prepass: fragment-major weights + feat transpose ----------------
extern "C" __global__ void prep_all(const float* __restrict__ feat,
                                    const float* __restrict__ w1,
                                    const float* __restrict__ w2,
                                    const float* __restrict__ w3,
                                    const float* __restrict__ wt,
                                    unsigned char* __restrict__ ws,
                                    int do_ft) {
    __shared__ unsigned short tile[36 * 256];
    if (do_ft && blockIdx.x < 576) {
        const int b = blockIdx.x / 36, y = blockIdx.x % 36;
        const int c = threadIdx.x;  // 256 threads
        const float* src = feat + (size_t)(b * 256 + c) * 1296 + y * 36;
        float4 fv[9];
        #pragma unroll
        for (int i = 0; i < 9; ++i) fv[i] = *(const float4*)(src + i * 4);
        #pragma unroll
        for (int i = 0; i < 9; ++i) {
            tile[(i*4+0)*256 + c] = bf16bits(fv[i].x);
            tile[(i*4+1)*256 + c] = bf16bits(fv[i].y);
            tile[(i*4+2)*256 + c] = bf16bits(fv[i].z);
            tile[(i*4+3)*256 + c] = bf16bits(fv[i].w);
        }
        __syncthreads();
        unsigned short* dst = (unsigned short*)(ws + FTOFF) + (size_t)(b*36 + y)*36*256;
        for (int x = 0; x < 36; ++x) dst[x*256 + c] = tile[x*256 + c];
        return;
    }
    const int base = do_ft ? 576 : 0;
    const int nb = gridDim.x - base;
    __bf16* wb = (__bf16*)ws;
    for (int i = (blockIdx.x - base) * blockDim.x + threadIdx.x; i < PRE_ELEMS;
         i += nb * blockDim.x) {
        float v; int dst;
        if (i < 98304) {                       // A1 frag
            int e = i;
            int j = e & 7, lane = (e>>3)&63, t = (e>>9)&15, mt = (e>>13)&3, ib = e>>15;
            int m = mt*32 + (lane&31), k = t*16 + 8*(lane>>5) + j;
            v = w1[(ib*BC + m)*CH + k];
            dst = (A1OFF>>1) + e;
        } else if (i < 98304 + 442368) {       // A2 frag (tap-major)
            int e = i - 98304;
            int j = e & 7, lane = (e>>3)&63, t = (e>>9)&7, mt = (e>>12)&3;
            int rem = e >> 14;                 // ib*9 + tap
            int ib = rem / 9, tap = rem - ib*9;
            int m = mt*32 + (lane&31), ci = t*16 + 8*(lane>>5) + j;
            v = w2[((ib*BC + m)*BC + ci)*9 + tap];
            dst = (A2OFF>>1) + e;
        } else if (i < 98304 + 442368 + 98304) { // A3 frag
            int e = i - (98304 + 442368);
            int j = e & 7, lane = (e>>3)&63, t = (e>>9)&7, mt = (e>>12)&7, ib = e>>15;
            int m = mt*32 + (lane&31), ci = t*16 + 8*(lane>>5) + j;
            v = w3[(ib*CH + m)*BC + ci];
            dst = (A3OFF>>1) + e;
        } else {                                // AT frag
            int e = i - (98304 + 442368 + 98304);
            int j = e & 7, lane = (e>>3)&63, t = (e>>9)&15, mt = (e>>13)&7, quad = e>>16;
            int co = mt*32 + (lane&31), ci = t*16 + 8*(lane>>5) + j;
            v = wt[ci*1024 + co*4 + quad];
            dst = (ATOFF>>1) + e;
        }
        wb[dst] = (__bf16)v;
    }
}

// ---------------- fused main kernel ----------------
template<int USE_WS, int USE_FT>
__global__ __launch_bounds__(NT, 2)
void masknet_mfma(const float* __restrict__ feat,
                  const float* __restrict__ bbox,
                  const float* __restrict__ w1, const float* __restrict__ s1, const float* __restrict__ b1,
                  const float* __restrict__ w2, const float* __restrict__ s2, const float* __restrict__ b2,
                  const float* __restrict__ w3, const float* __restrict__ s3, const float* __restrict__ b3,
                  const float* __restrict__ wt, const float* __restrict__ bt,
                  const float* __restrict__ wm, const float* __restrict__ bm,
                  const unsigned char* __restrict__ ws,
                  float* __restrict__ out)
{
    __shared__ __align__(16) unsigned char smem[LDS_BYTES];
    float* wyb = (float*)(smem + WY_OFF);
    float* wxb = (float*)(smem + WX_OFF);
    float* lgf = (float*)(smem + LG_OFF);

    const int tid  = threadIdx.x;
    const int r    = blockIdx.x;
    const int bfr  = r >> 5;
    const int lane = tid & 63;
    const int ln   = lane & 31;
    const int h    = lane >> 5;
    const int w_   = tid >> 6;
    const int cb   = 16 * h;

    // ---- ROI params ----
    const float S = 1.f / 16.f;
    const float bx = bbox[r*4+0], by = bbox[r*4+1];
    const float bw_ = bbox[r*4+2], bh_ = bbox[r*4+3];
    const float x1 = bx * S, y1 = by * S;
    const float bwx = (bw_ * S) * (1.f / RESQ);
    const float bwy = (bh_ * S) * (1.f / RESQ);
    const float area = bwx * bwy;
    const float inv_area = (area > 0.f) ? 1.f / fmaxf(area, 1e-12f) : 0.f;

    // ---- Phase A: tables + zero t1 + zero logits ----
    if (tid < 252) {
        int p = tid / 36, i = tid - p * 36;
        float st = y1 + bwy * p, en = st + bwy;
        wyb[tid] = Fk(en - (float)i) - Fk(st - (float)i);
    } else if (tid >= 256 && tid < 508) {
        int t = tid - 256;
        int q = t / 36, i = t - q * 36;
        float st = x1 + bwx * q, en = st + bwx;
        wxb[t] = Fk(en - (float)i) - Fk(st - (float)i);
    }
    {
        uint4* z = (uint4*)(smem + T1_OFF);
        for (int o = tid; o < 1296; o += NT) z[o] = make_uint4(0,0,0,0);
        if (tid < 256) lgf[tid] = 0.f;
    }
    __syncthreads();

    // ---- Phase B: PrRoI pool -> xs[s][c] bf16 (swizzled) ----
    if (USE_FT) {
        const unsigned short* ft = (const unsigned short*)(ws + FTOFF) + (size_t)bfr * (1296 * 256);
        for (int s = w_; s < 49; s += 8) {
            const int p = s / 7, q = s - (s / 7) * 7;
            const float sy = y1 + bwy * p, sx = x1 + bwx * q;
            const int ylo = max(0, (int)floorf(sy)), yhi = min(35, (int)ceilf(sy + bwy));
            const int xlo = max(0, (int)floorf(sx)), xhi = min(35, (int)ceilf(sx + bwx));
            float a0 = 0.f, a1 = 0.f, a2 = 0.f, a3 = 0.f;
            for (int y = ylo; y <= yhi; ++y) {
                const float wy = wyb[p * 36 + y] * inv_area;
                const unsigned short* frow = ft + (size_t)(y * 36) * 256 + lane * 4;
                for (int x = xlo; x <= xhi; ++x) {
                    const float wgt = wy * wxb[q * 36 + x];
                    ushort4 v = *(const ushort4*)(frow + x * 256);
                    a0 = fmaf(wgt, b2f(v.x), a0);
                    a1 = fmaf(wgt, b2f(v.y), a1);
                    a2 = fmaf(wgt, b2f(v.z), a2);
                    a3 = fmaf(wgt, b2f(v.w), a3);
                }
            }
            *(uint2*)(smem + XS_OFF + s * 512 + ((8 * lane) ^ SWZ(s))) =
                make_uint2(pk2(a0, a1), pk2(a2, a3));
        }
    } else {
        const float* fb = feat + (size_t)bfr * CH * 36 * 36;
        for (int o = tid; o < CH * 49; o += NT) {
            int c = o / 49, s = o - c * 49;
            int p = s / 7, q = s - p * 7;
            float sy = y1 + bwy * p, sx = x1 + bwx * q;
            int ylo = max(0, (int)floorf(sy)), yhi = min(35, (int)ceilf(sy + bwy));
            int xlo = max(0, (int)floorf(sx)), xhi = min(35, (int)ceilf(sx + bwx));
            const float* fc = fb + c * 1296;
            float acc = 0.f;
            for (int y = ylo; y <= yhi; ++y) {
                float wyv = wyb[p * 36 + y];
                for (int x = xlo; x <= xhi; ++x)
                    acc = fmaf(wyv * wxb[q * 36 + x], fc[y * 36 + x], acc);
            }
            *(unsigned short*)(smem + XS_OFF + s * 512 + ((2 * c) ^ SWZ(s))) =
                bf16bits(acc * inv_area);
        }
    }
    __syncthreads();

    // wave geometry
    const int mt12 = w_ & 3, nt12 = w_ >> 2;           // conv1/2: 4m x 2n
    const int col12 = nt12 * 32 + ln;
    const int ncl12 = min(col12, 48);
    const int mg = w_ >> 1, ng = w_ & 1;               // conv3/deconv: (2 mt) x 2n
    const int col3 = ng * 32 + ln;
    const int ncl3 = min(col3, 48);

    // ---- Phase C: bottleneck blocks ----
    for (int ib = 0; ib < NB; ++ib) {
        // ===== conv1: xs(256) -> t1(128 interior), K=256, 32x32 =====
        {
            const unsigned char* bb = smem + XS_OFF + ncl12 * 512;
            const int bswz = SWZ(ncl12);
            f16v acc = {};
            #pragma unroll
            for (int t = 0; t < 16; ++t) {
                bh8 a;
                if (USE_WS) a = ld_bh8(ws + A1OFF + ((((ib*4 + mt12)*16 + t)*64 + lane) << 4));
                else        a = cvt8(w1 + (size_t)(ib*BC + mt12*32 + ln)*CH + t*16 + 8*h);
                bh8 b = ld_bh8(bb + ((t*32 + cb) ^ bswz));
                acc = __builtin_amdgcn_mfma_f32_32x32x16_bf16(a, b, acc, 0, 0, 0);
            }
            if (col12 < 49) {
                const int row = (col12/7 + 1)*9 + (col12 - (col12/7)*7) + 1;
                epi_store(acc, mt12*32, h, s1 + ib*BC, b1 + ib*BC,
                          smem + T1_OFF + row*256, SWZ(row));
            }
        }
        __syncthreads();

        // ===== conv2: 3x3 as 9 tap-GEMMs, t1(128) -> t2(128) =====
        {
            const int tr0 = (ncl12/7)*9 + (ncl12 - (ncl12/7)*7);
            f16v acc = {};
            #pragma unroll 1
            for (int ty = 0; ty < 3; ++ty) {
                #pragma unroll
                for (int tx = 0; tx < 3; ++tx) {
                    const int tap = ty*3 + tx;
                    bh8 aw[8];
                    #pragma unroll
                    for (int t = 0; t < 8; ++t) {
                        if (USE_WS) aw[t] = ld_bh8(ws + A2OFF + (((((ib*9+tap)*4 + mt12)*8 + t)*64 + lane) << 4));
                        else        aw[t] = gather8(w2 + ((size_t)(ib*BC + mt12*32 + ln)*BC + t*16 + 8*h)*9 + tap, 9);
                    }
                    const int row = tr0 + ty*9 + tx;
                    const unsigned char* bb = smem + T1_OFF + row*256;
                    const int rs = SWZ(row);
                    #pragma unroll
                    for (int t = 0; t < 8; ++t) {
                        bh8 b = ld_bh8(bb + ((t*32 + cb) ^ rs));
                        acc = __builtin_amdgcn_mfma_f32_32x32x16_bf16(aw[t], b, acc, 0, 0, 0);
                    }
                }
            }
            if (col12 < 49) {
                epi_store(acc, mt12*32, h, s2 + ib*BC, b2 + ib*BC,
                          smem + T2_OFF + col12*256, SWZ(col12));
            }
        }
        __syncthreads();

        // ===== conv3: t2(128) -> xs(256) + residual + relu =====
        {
            const unsigned char* bb = smem + T2_OFF + ncl3 * 256;
            const int bswz = SWZ(ncl3);
            f16v acc0 = {}, acc1 = {};
            #pragma unroll
            for (int t = 0; t < 8; ++t) {
                bh8 a0, a1;
                if (USE_WS) {
                    a0 = ld_bh8(ws + A3OFF + ((((ib*8 + 2*mg+0)*8 + t)*64 + lane) << 4));
                    a1 = ld_bh8(ws + A3OFF + ((((ib*8 + 2*mg+1)*8 + t)*64 + lane) << 4));
                } else {
                    a0 = cvt8(w3 + (size_t)(ib*CH + (2*mg+0)*32 + ln)*BC + t*16 + 8*h);
                    a1 = cvt8(w3 + (size_t)(ib*CH + (2*mg+1)*32 + ln)*BC + t*16 + 8*h);
                }
                bh8 b = ld_bh8(bb + ((t*32 + cb) ^ bswz));
                acc0 = __builtin_amdgcn_mfma_f32_32x32x16_bf16(a0, b, acc0, 0, 0, 0);
                acc1 = __builtin_amdgcn_mfma_f32_32x32x16_bf16(a1, b, acc1, 0, 0, 0);
            }
            if (col3 < 49) {
                unsigned char* rowb = smem + XS_OFF + col3*512;
                const int rs = SWZ(col3);
                epi_res(acc0, (2*mg+0)*32, h, s3 + ib*CH, b3 + ib*CH, rowb, rs);
                epi_res(acc1, (2*mg+1)*32, h, s3 + ib*CH, b3 + ib*CH, rowb, rs);
            }
        }
        __syncthreads();
    }

    // ---- Phase D: deconv (4 quads as 2 passes) + fused mask head ----
    #pragma unroll 1
    for (int qp = 0; qp < 2; ++qp) {
        const unsigned char* bb = smem + XS_OFF + ncl3 * 512;
        const int bswz = SWZ(ncl3);
        f16v acc00 = {}, acc01 = {}, acc10 = {}, acc11 = {};   // [iq][im]
        #pragma unroll
        for (int t = 0; t < 16; ++t) {
            bh8 b = ld_bh8(bb + ((t*32 + cb) ^ bswz));
            bh8 a00, a01, a10, a11;
            if (USE_WS) {
                a00 = ld_bh8(ws + ATOFF + (((((2*qp+0)*8 + 2*mg+0)*16 + t)*64 + lane) << 4));
                a01 = ld_bh8(ws + ATOFF + (((((2*qp+0)*8 + 2*mg+1)*16 + t)*64 + lane) << 4));
                a10 = ld_bh8(ws + ATOFF + (((((2*qp+1)*8 + 2*mg+0)*16 + t)*64 + lane) << 4));
                a11 = ld_bh8(ws + ATOFF + (((((2*qp+1)*8 + 2*mg+1)*16 + t)*64 + lane) << 4));
            } else {
                a00 = gather8(wt + (size_t)(t*16 + 8*h)*1024 + ((2*mg+0)*32 + ln)*4 + (2*qp+0), 1024);
                a01 = gather8(wt + (size_t)(t*16 + 8*h)*1024 + ((2*mg+1)*32 + ln)*4 + (2*qp+0), 1024);
                a10 = gather8(wt + (size_t)(t*16 + 8*h)*1024 + ((2*mg+0)*32 + ln)*4 + (2*qp+1), 1024);
                a11 = gather8(wt + (size_t)(t*16 + 8*h)*1024 + ((2*mg+1)*32 + ln)*4 + (2*qp+1), 1024);
            }
            acc00 = __builtin_amdgcn_mfma_f32_32x32x16_bf16(a00, b, acc00, 0, 0, 0);
            acc01 = __builtin_amdgcn_mfma_f32_32x32x16_bf16(a01, b, acc01, 0, 0, 0);
            acc10 = __builtin_amdgcn_mfma_f32_32x32x16_bf16(a10, b, acc10, 0, 0, 0);
            acc11 = __builtin_amdgcn_mfma_f32_32x32x16_bf16(a11, b, acc11, 0, 0, 0);
        }
        float p0 = dq_part(acc00, (2*mg+0)*32, h, bt, wm)
                 + dq_part(acc01, (2*mg+1)*32, h, bt, wm);
        float p1 = dq_part(acc10, (2*mg+0)*32, h, bt, wm)
                 + dq_part(acc11, (2*mg+1)*32, h, bt, wm);
        p0 += __shfl_down(p0, 32);
        p1 += __shfl_down(p1, 32);
        if (h == 0 && col3 < 49) {
            atomicAdd(&lgf[(2*qp+0)*64 + col3], p0);
            atomicAdd(&lgf[(2*qp+1)*64 + col3], p1);
        }
    }
    __syncthreads();

    // ---- final: sigmoid + scatter to 14x14 ----
    if (tid < 196) {
        const int quad = tid / 49, s = tid - quad*49;
        const float val = lgf[quad*64 + s] + bm[0];
        const int p = s / 7, q = s - p*7;
        const int dy = quad >> 1, dx = quad & 1;
        out[(size_t)r * 196 + (2*p + dy)*14 + (2*q + dx)] = 1.f / (1.f + expf(-val));
    }
}

extern "C" void kernel_launch(void* const* d_in, const int* in_sizes, int n_in,
                              void* d_out, int out_size, void* d_ws, size_t ws_size,
                              hipStream_t stream) {
    const float* feat = (const float*)d_in[0];
    const float* bbox = (const float*)d_in[1];
    const float* w1   = (const float*)d_in[2];
    const float* s1   = (const float*)d_in[3];
    const float* b1   = (const float*)d_in[4];
    const float* w2   = (const float*)d_in[5];
    const float* s2   = (const float*)d_in[6];
    const float* b2   = (const float*)d_in[7];
    const float* w3   = (const float*)d_in[8];
    const float* s3   = (const float*)d_in[9];
    const float* b3   = (const float*)d_in[10];
    const float* wt   = (const float*)d_in[11];
    const float* bt   = (const float*)d_in[12];
    const float* wm   = (const float*)d_in[13];
    const float* bm   = (const float*)d_in[14];
    float* out = (float*)d_out;

    if (ws_size >= (size_t)WS_FULL) {
        unsigned char* ws = (unsigned char*)d_ws;
        hipLaunchKernelGGL(prep_all, dim3(1024), dim3(256), 0, stream,
                           feat, w1, w2, w3, wt, ws, 1);
        hipLaunchKernelGGL((masknet_mfma<1,1>), dim3(NROI), dim3(NT), 0, stream,
                           feat, bbox, w1, s1, b1, w2, s2, b2, w3, s3, b3,
                           wt, bt, wm, bm, ws, out);
    } else if (ws_size >= (size_t)WS_BYTES) {
        unsigned char* ws = (unsigned char*)d_ws;
        hipLaunchKernelGGL(prep_all, dim3(448), dim3(256), 0, stream,
                           feat, w1, w2, w3, wt, ws, 0);
        hipLaunchKernelGGL((masknet_mfma<1,0>), dim3(NROI), dim3(NT), 0, stream,
                           feat, bbox, w1, s1, b1, w2, s2, b2, w3, s3, b3,
                           wt, bt, wm, bm, ws, out);
    } else {
        hipLaunchKernelGGL((masknet_mfma<0,0>), dim3(NROI), dim3(NT), 0, stream,
                           feat, bbox, w1, s1, b1, w2, s2, b2, w3, s3, b3,
                           wt, bt, wm, bm, (const unsigned char*)nullptr, out);
    }
}

// Round 9
// 143.664 us; speedup vs baseline: 7.7812x; 1.0739x over previous
//
#include <hip/hip_runtime.h>
#include <math.h>

#define RESQ 7
#define CH   256
#define NROI 512
#define BC   128
#define NB   3
#define NT   512

typedef __bf16 bh8  __attribute__((ext_vector_type(8)));
typedef float  f16v __attribute__((ext_vector_type(16)));

// ---- d_ws layout (bytes): fragment-major A panels ----
#define A1OFF 0            // [3 ib][4 mt][16 t][64 lane][8] bf16 = 196608
#define A2OFF 196608       // [3][9 tap][4 mt][8 t][64][8]       = 884736
#define A3OFF 1081344      // [3][8 mt][8 t][64][8]              = 196608
#define ATOFF 1277952      // [4 quad][8 mt][16 t][64][8]        = 524288
#define WS_BYTES 1802240
#define FTOFF 1802240      // feat_t [16][36][36][256] bf16 -> 10616832 B
#define WS_FULL 12419072
#define PRE_ELEMS 901120

// ---- LDS (bytes) ----
#define XS_OFF 0           // xs [49 sp][256 ch] bf16, stride 512
#define T1_OFF 25088       // t1 [81 rows][128 ch] bf16, stride 256
#define T2_OFF 45824       // t2 [49 sp][128 ch] bf16, stride 256
#define WY_OFF 58368       // 252 f32
#define WX_OFF 59376       // 252 f32
#define LG_OFF 60384       // logits [4 quad][4 mg][64] f32 = 4096
#define LDS_BYTES 64480

#define SWZ(row) (((row) & 15) << 4)

__device__ __forceinline__ float Fk(float t) {
    t = fminf(1.f, fmaxf(-1.f, t));
    float a = t + 1.f, b = 1.f - t;
    return (t < 0.f) ? 0.5f * a * a : 1.f - 0.5f * b * b;
}
__device__ __forceinline__ unsigned short bf16bits(float a) {
    return __builtin_bit_cast(unsigned short, (__bf16)a);
}
__device__ __forceinline__ unsigned int pk2(float a, float b) {
    return (unsigned int)bf16bits(a) | ((unsigned int)bf16bits(b) << 16);
}
__device__ __forceinline__ float b2f(unsigned int s) {
    return __builtin_bit_cast(float, s << 16);
}
__device__ __forceinline__ bh8 ld_bh8(const unsigned char* p) { return *(const bh8*)p; }
__device__ __forceinline__ bh8 cvt8(const float* p) {
    float4 a = *(const float4*)p;
    float4 b = *(const float4*)(p + 4);
    bh8 r;
    r[0]=(__bf16)a.x; r[1]=(__bf16)a.y; r[2]=(__bf16)a.z; r[3]=(__bf16)a.w;
    r[4]=(__bf16)b.x; r[5]=(__bf16)b.y; r[6]=(__bf16)b.z; r[7]=(__bf16)b.w;
    return r;
}
__device__ __forceinline__ bh8 gather8(const float* p, int stride) {
    bh8 r;
    #pragma unroll
    for (int j = 0; j < 8; ++j) r[j] = (__bf16)p[j * stride];
    return r;
}

// epilogue helpers (compile-time reg indices only)
__device__ __forceinline__ void epi_store(const f16v acc, int chbase, int h,
        const float* sarr, const float* barr, unsigned char* rowbase, int rswz) {
    #pragma unroll
    for (int g = 0; g < 4; ++g) {
        const int ch = chbase + 8*g + 4*h;
        const float4 sv = *(const float4*)(sarr + ch);
        const float4 bv = *(const float4*)(barr + ch);
        float v0 = fmaxf(fmaf(acc[4*g+0], sv.x, bv.x), 0.f);
        float v1 = fmaxf(fmaf(acc[4*g+1], sv.y, bv.y), 0.f);
        float v2 = fmaxf(fmaf(acc[4*g+2], sv.z, bv.z), 0.f);
        float v3 = fmaxf(fmaf(acc[4*g+3], sv.w, bv.w), 0.f);
        *(uint2*)(rowbase + ((2*ch) ^ rswz)) = make_uint2(pk2(v0,v1), pk2(v2,v3));
    }
}
__device__ __forceinline__ void epi_res(const f16v acc, int chbase, int h,
        const float* sarr, const float* barr, unsigned char* rowbase, int rswz) {
    #pragma unroll
    for (int g = 0; g < 4; ++g) {
        const int ch = chbase + 8*g + 4*h;
        const float4 sv = *(const float4*)(sarr + ch);
        const float4 bv = *(const float4*)(barr + ch);
        unsigned char* p = rowbase + ((2*ch) ^ rswz);
        const uint2 old = *(const uint2*)p;
        float v0 = fmaxf(fmaf(acc[4*g+0], sv.x, bv.x) + b2f(old.x & 0xFFFFu), 0.f);
        float v1 = fmaxf(fmaf(acc[4*g+1], sv.y, bv.y) + b2f(old.x >> 16), 0.f);
        float v2 = fmaxf(fmaf(acc[4*g+2], sv.z, bv.z) + b2f(old.y & 0xFFFFu), 0.f);
        float v3 = fmaxf(fmaf(acc[4*g+3], sv.w, bv.w) + b2f(old.y >> 16), 0.f);
        *(uint2*)p = make_uint2(pk2(v0,v1), pk2(v2,v3));
    }
}
__device__ __forceinline__ float dq_part(const f16v acc, int chbase, int h,
        const float* bt, const float* wm) {
    float part = 0.f;
    #pragma unroll
    for (int g = 0; g < 4; ++g) {
        const int ch = chbase + 8*g + 4*h;
        const float4 btv = *(const float4*)(bt + ch);
        const float4 wmv = *(const float4*)(wm + ch);
        part = fmaf(wmv.x, fmaxf(acc[4*g+0] + btv.x, 0.f), part);
        part = fmaf(wmv.y, fmaxf(acc[4*g+1] + btv.y, 0.f), part);
        part = fmaf(wmv.z, fmaxf(acc[4*g+2] + btv.z, 0.f), part);
        part = fmaf(wmv.w, fmaxf(acc[4*g+3] + btv.w, 0.f), part);
    }
    return part;
}

// ---------------- prepass: fragment-major weights + feat transpose ----------------
extern "C" __global__ void prep_all(const float* __restrict__ feat,
                                    const float* __restrict__ w1,
                                    const float* __restrict__ w2,
                                    const float* __restrict__ w3,
                                    const float* __restrict__ wt,
                                    unsigned char* __restrict__ ws,
                                    int do_ft) {
    __shared__ unsigned short tile[36 * 256];
    if (do_ft && blockIdx.x < 576) {
        const int b = blockIdx.x / 36, y = blockIdx.x % 36;
        const int c = threadIdx.x;  // 256 threads
        const float* src = feat + (size_t)(b * 256 + c) * 1296 + y * 36;
        float4 fv[9];
        #pragma unroll
        for (int i = 0; i < 9; ++i) fv[i] = *(const float4*)(src + i * 4);
        #pragma unroll
        for (int i = 0; i < 9; ++i) {
            tile[(i*4+0)*256 + c] = bf16bits(fv[i].x);
            tile[(i*4+1)*256 + c] = bf16bits(fv[i].y);
            tile[(i*4+2)*256 + c] = bf16bits(fv[i].z);
            tile[(i*4+3)*256 + c] = bf16bits(fv[i].w);
        }
        __syncthreads();
        unsigned short* dst = (unsigned short*)(ws + FTOFF) + (size_t)(b*36 + y)*36*256;
        for (int x = 0; x < 36; ++x) dst[x*256 + c] = tile[x*256 + c];
        return;
    }
    const int base = do_ft ? 576 : 0;
    const int nb = gridDim.x - base;
    __bf16* wb = (__bf16*)ws;
    for (int i = (blockIdx.x - base) * blockDim.x + threadIdx.x; i < PRE_ELEMS;
         i += nb * blockDim.x) {
        float v; int dst;
        if (i < 98304) {                       // A1 frag
            int e = i;
            int j = e & 7, lane = (e>>3)&63, t = (e>>9)&15, mt = (e>>13)&3, ib = e>>15;
            int m = mt*32 + (lane&31), k = t*16 + 8*(lane>>5) + j;
            v = w1[(ib*BC + m)*CH + k];
            dst = (A1OFF>>1) + e;
        } else if (i < 98304 + 442368) {       // A2 frag (tap-major)
            int e = i - 98304;
            int j = e & 7, lane = (e>>3)&63, t = (e>>9)&7, mt = (e>>12)&3;
            int rem = e >> 14;                 // ib*9 + tap
            int ib = rem / 9, tap = rem - ib*9;
            int m = mt*32 + (lane&31), ci = t*16 + 8*(lane>>5) + j;
            v = w2[((ib*BC + m)*BC + ci)*9 + tap];
            dst = (A2OFF>>1) + e;
        } else if (i < 98304 + 442368 + 98304) { // A3 frag
            int e = i - (98304 + 442368);
            int j = e & 7, lane = (e>>3)&63, t = (e>>9)&7, mt = (e>>12)&7, ib = e>>15;
            int m = mt*32 + (lane&31), ci = t*16 + 8*(lane>>5) + j;
            v = w3[(ib*CH + m)*BC + ci];
            dst = (A3OFF>>1) + e;
        } else {                                // AT frag
            int e = i - (98304 + 442368 + 98304);
            int j = e & 7, lane = (e>>3)&63, t = (e>>9)&15, mt = (e>>13)&7, quad = e>>16;
            int co = mt*32 + (lane&31), ci = t*16 + 8*(lane>>5) + j;
            v = wt[ci*1024 + co*4 + quad];
            dst = (ATOFF>>1) + e;
        }
        wb[dst] = (__bf16)v;
    }
}

// ---------------- fused main kernel ----------------
template<int USE_WS, int USE_FT>
__global__ __launch_bounds__(NT, 2)
void masknet_mfma(const float* __restrict__ feat,
                  const float* __restrict__ bbox,
                  const float* __restrict__ w1, const float* __restrict__ s1, const float* __restrict__ b1,
                  const float* __restrict__ w2, const float* __restrict__ s2, const float* __restrict__ b2,
                  const float* __restrict__ w3, const float* __restrict__ s3, const float* __restrict__ b3,
                  const float* __restrict__ wt, const float* __restrict__ bt,
                  const float* __restrict__ wm, const float* __restrict__ bm,
                  const unsigned char* __restrict__ ws,
                  float* __restrict__ out)
{
    __shared__ __align__(16) unsigned char smem[LDS_BYTES];
    float* wyb = (float*)(smem + WY_OFF);
    float* wxb = (float*)(smem + WX_OFF);
    float* lgf = (float*)(smem + LG_OFF);

    const int tid  = threadIdx.x;
    const int r    = blockIdx.x;
    const int bfr  = r >> 5;
    const int lane = tid & 63;
    const int ln   = lane & 31;
    const int h    = lane >> 5;
    const int w_   = tid >> 6;
    const int cb   = 16 * h;

    // ---- ROI params ----
    const float S = 1.f / 16.f;
    const float bx = bbox[r*4+0], by = bbox[r*4+1];
    const float bw_ = bbox[r*4+2], bh_ = bbox[r*4+3];
    const float x1 = bx * S, y1 = by * S;
    const float bwx = (bw_ * S) * (1.f / RESQ);
    const float bwy = (bh_ * S) * (1.f / RESQ);
    const float area = bwx * bwy;
    const float inv_area = (area > 0.f) ? 1.f / fmaxf(area, 1e-12f) : 0.f;

    // ---- Phase A: tables + zero t1 + zero logits ----
    if (tid < 252) {
        int p = tid / 36, i = tid - p * 36;
        float st = y1 + bwy * p, en = st + bwy;
        wyb[tid] = Fk(en - (float)i) - Fk(st - (float)i);
    } else if (tid >= 256 && tid < 508) {
        int t = tid - 256;
        int q = t / 36, i = t - q * 36;
        float st = x1 + bwx * q, en = st + bwx;
        wxb[t] = Fk(en - (float)i) - Fk(st - (float)i);
    }
    {
        uint4* z = (uint4*)(smem + T1_OFF);
        for (int o = tid; o < 1296; o += NT) z[o] = make_uint4(0,0,0,0);
        for (int o = tid; o < 1024; o += NT) lgf[o] = 0.f;
    }
    __syncthreads();

    // ---- Phase B: PrRoI pool -> xs[s][c] bf16 (swizzled) ----
    if (USE_FT) {
        // 16 groups (wave-half per bin), lane = 8 channels, static 4x4 taps
        const unsigned short* ft = (const unsigned short*)(ws + FTOFF) + (size_t)bfr * (1296 * 256);
        const int g = w_ * 2 + h;   // 0..15
        #pragma unroll 1
        for (int k = 0; k < 4; ++k) {
            const int s = g + 16 * k;
            if (s >= 49) break;
            const int p = s / 7, q = s - p * 7;
            const float sy = y1 + bwy * p, sx = x1 + bwx * q;
            const int ylo = max(0, (int)floorf(sy)), yhi = min(35, (int)ceilf(sy + bwy));
            const int xlo = max(0, (int)floorf(sx)), xhi = min(35, (int)ceilf(sx + bwx));
            float wyv[4], wxv[4];
            #pragma unroll
            for (int j = 0; j < 4; ++j) {
                const int y = ylo + j, x = xlo + j;
                wyv[j] = (y <= yhi) ? wyb[p*36 + y] * inv_area : 0.f;
                wxv[j] = (x <= xhi) ? wxb[q*36 + x] : 0.f;
            }
            float ac0=0.f,ac1=0.f,ac2=0.f,ac3=0.f,ac4=0.f,ac5=0.f,ac6=0.f,ac7=0.f;
            #pragma unroll
            for (int yy = 0; yy < 4; ++yy) {
                const int y = min(ylo + yy, 35);
                const unsigned short* rowp = ft + (size_t)(y * 36) * 256 + ln * 8;
                #pragma unroll
                for (int xx = 0; xx < 4; ++xx) {
                    const int x = min(xlo + xx, 35);
                    const float wgt = wyv[yy] * wxv[xx];
                    const uint4 v = *(const uint4*)(rowp + x * 256);
                    ac0 = fmaf(wgt, b2f(v.x & 0xFFFFu), ac0);
                    ac1 = fmaf(wgt, b2f(v.x >> 16),     ac1);
                    ac2 = fmaf(wgt, b2f(v.y & 0xFFFFu), ac2);
                    ac3 = fmaf(wgt, b2f(v.y >> 16),     ac3);
                    ac4 = fmaf(wgt, b2f(v.z & 0xFFFFu), ac4);
                    ac5 = fmaf(wgt, b2f(v.z >> 16),     ac5);
                    ac6 = fmaf(wgt, b2f(v.w & 0xFFFFu), ac6);
                    ac7 = fmaf(wgt, b2f(v.w >> 16),     ac7);
                }
            }
            *(uint4*)(smem + XS_OFF + s * 512 + ((16 * ln) ^ SWZ(s))) =
                make_uint4(pk2(ac0,ac1), pk2(ac2,ac3), pk2(ac4,ac5), pk2(ac6,ac7));
        }
    } else {
        const float* fb = feat + (size_t)bfr * CH * 36 * 36;
        for (int o = tid; o < CH * 49; o += NT) {
            int c = o / 49, s = o - c * 49;
            int p = s / 7, q = s - p * 7;
            float sy = y1 + bwy * p, sx = x1 + bwx * q;
            int ylo = max(0, (int)floorf(sy)), yhi = min(35, (int)ceilf(sy + bwy));
            int xlo = max(0, (int)floorf(sx)), xhi = min(35, (int)ceilf(sx + bwx));
            const float* fc = fb + c * 1296;
            float acc = 0.f;
            for (int y = ylo; y <= yhi; ++y) {
                float wyv = wyb[p * 36 + y];
                for (int x = xlo; x <= xhi; ++x)
                    acc = fmaf(wyv * wxb[q * 36 + x], fc[y * 36 + x], acc);
            }
            *(unsigned short*)(smem + XS_OFF + s * 512 + ((2 * c) ^ SWZ(s))) =
                bf16bits(acc * inv_area);
        }
    }
    __syncthreads();

    // wave geometry
    const int mt12 = w_ & 3, nt12 = w_ >> 2;           // conv1/2: 4m x 2n
    const int col12 = nt12 * 32 + ln;
    const int ncl12 = min(col12, 48);
    const int mg = w_ >> 1, ng = w_ & 1;               // conv3/deconv: (2 mt) x 2n
    const int col3 = ng * 32 + ln;
    const int ncl3 = min(col3, 48);

    // ---- Phase C: bottleneck blocks ----
    for (int ib = 0; ib < NB; ++ib) {
        // ===== conv1: xs(256) -> t1(128 interior), K=256, 32x32 =====
        {
            const unsigned char* bb = smem + XS_OFF + ncl12 * 512;
            const int bswz = SWZ(ncl12);
            f16v acc = {};
            #pragma unroll
            for (int t = 0; t < 16; ++t) {
                bh8 a;
                if (USE_WS) a = ld_bh8(ws + A1OFF + ((((ib*4 + mt12)*16 + t)*64 + lane) << 4));
                else        a = cvt8(w1 + (size_t)(ib*BC + mt12*32 + ln)*CH + t*16 + 8*h);
                bh8 b = ld_bh8(bb + ((t*32 + cb) ^ bswz));
                acc = __builtin_amdgcn_mfma_f32_32x32x16_bf16(a, b, acc, 0, 0, 0);
            }
            if (col12 < 49) {
                const int row = (col12/7 + 1)*9 + (col12 - (col12/7)*7) + 1;
                epi_store(acc, mt12*32, h, s1 + ib*BC, b1 + ib*BC,
                          smem + T1_OFF + row*256, SWZ(row));
            }
        }
        __syncthreads();

        // ===== conv2: 3x3 as 9 tap-GEMMs, t1(128) -> t2(128) =====
        {
            const int tr0 = (ncl12/7)*9 + (ncl12 - (ncl12/7)*7);
            f16v acc = {};
            #pragma unroll 1
            for (int ty = 0; ty < 3; ++ty) {
                #pragma unroll
                for (int tx = 0; tx < 3; ++tx) {
                    const int tap = ty*3 + tx;
                    bh8 aw[8];
                    #pragma unroll
                    for (int t = 0; t < 8; ++t) {
                        if (USE_WS) aw[t] = ld_bh8(ws + A2OFF + (((((ib*9+tap)*4 + mt12)*8 + t)*64 + lane) << 4));
                        else        aw[t] = gather8(w2 + ((size_t)(ib*BC + mt12*32 + ln)*BC + t*16 + 8*h)*9 + tap, 9);
                    }
                    const int row = tr0 + ty*9 + tx;
                    const unsigned char* bb = smem + T1_OFF + row*256;
                    const int rs = SWZ(row);
                    #pragma unroll
                    for (int t = 0; t < 8; ++t) {
                        bh8 b = ld_bh8(bb + ((t*32 + cb) ^ rs));
                        acc = __builtin_amdgcn_mfma_f32_32x32x16_bf16(aw[t], b, acc, 0, 0, 0);
                    }
                }
            }
            if (col12 < 49) {
                epi_store(acc, mt12*32, h, s2 + ib*BC, b2 + ib*BC,
                          smem + T2_OFF + col12*256, SWZ(col12));
            }
        }
        __syncthreads();

        // ===== conv3: t2(128) -> xs(256) + residual + relu =====
        {
            const unsigned char* bb = smem + T2_OFF + ncl3 * 256;
            const int bswz = SWZ(ncl3);
            f16v acc0 = {}, acc1 = {};
            #pragma unroll
            for (int t = 0; t < 8; ++t) {
                bh8 a0, a1;
                if (USE_WS) {
                    a0 = ld_bh8(ws + A3OFF + ((((ib*8 + 2*mg+0)*8 + t)*64 + lane) << 4));
                    a1 = ld_bh8(ws + A3OFF + ((((ib*8 + 2*mg+1)*8 + t)*64 + lane) << 4));
                } else {
                    a0 = cvt8(w3 + (size_t)(ib*CH + (2*mg+0)*32 + ln)*BC + t*16 + 8*h);
                    a1 = cvt8(w3 + (size_t)(ib*CH + (2*mg+1)*32 + ln)*BC + t*16 + 8*h);
                }
                bh8 b = ld_bh8(bb + ((t*32 + cb) ^ bswz));
                acc0 = __builtin_amdgcn_mfma_f32_32x32x16_bf16(a0, b, acc0, 0, 0, 0);
                acc1 = __builtin_amdgcn_mfma_f32_32x32x16_bf16(a1, b, acc1, 0, 0, 0);
            }
            if (col3 < 49) {
                unsigned char* rowb = smem + XS_OFF + col3*512;
                const int rs = SWZ(col3);
                epi_res(acc0, (2*mg+0)*32, h, s3 + ib*CH, b3 + ib*CH, rowb, rs);
                epi_res(acc1, (2*mg+1)*32, h, s3 + ib*CH, b3 + ib*CH, rowb, rs);
            }
        }
        __syncthreads();
    }

    // ---- Phase D: deconv (4 quads as 2 passes) + fused mask head ----
    #pragma unroll 1
    for (int qp = 0; qp < 2; ++qp) {
        const unsigned char* bb = smem + XS_OFF + ncl3 * 512;
        const int bswz = SWZ(ncl3);
        f16v acc00 = {}, acc01 = {}, acc10 = {}, acc11 = {};   // [iq][im]
        #pragma unroll
        for (int t = 0; t < 16; ++t) {
            bh8 b = ld_bh8(bb + ((t*32 + cb) ^ bswz));
            bh8 a00, a01, a10, a11;
            if (USE_WS) {
                a00 = ld_bh8(ws + ATOFF + (((((2*qp+0)*8 + 2*mg+0)*16 + t)*64 + lane) << 4));
                a01 = ld_bh8(ws + ATOFF + (((((2*qp+0)*8 + 2*mg+1)*16 + t)*64 + lane) << 4));
                a10 = ld_bh8(ws + ATOFF + (((((2*qp+1)*8 + 2*mg+0)*16 + t)*64 + lane) << 4));
                a11 = ld_bh8(ws + ATOFF + (((((2*qp+1)*8 + 2*mg+1)*16 + t)*64 + lane) << 4));
            } else {
                a00 = gather8(wt + (size_t)(t*16 + 8*h)*1024 + ((2*mg+0)*32 + ln)*4 + (2*qp+0), 1024);
                a01 = gather8(wt + (size_t)(t*16 + 8*h)*1024 + ((2*mg+1)*32 + ln)*4 + (2*qp+0), 1024);
                a10 = gather8(wt + (size_t)(t*16 + 8*h)*1024 + ((2*mg+0)*32 + ln)*4 + (2*qp+1), 1024);
                a11 = gather8(wt + (size_t)(t*16 + 8*h)*1024 + ((2*mg+1)*32 + ln)*4 + (2*qp+1), 1024);
            }
            acc00 = __builtin_amdgcn_mfma_f32_32x32x16_bf16(a00, b, acc00, 0, 0, 0);
            acc01 = __builtin_amdgcn_mfma_f32_32x32x16_bf16(a01, b, acc01, 0, 0, 0);
            acc10 = __builtin_amdgcn_mfma_f32_32x32x16_bf16(a10, b, acc10, 0, 0, 0);
            acc11 = __builtin_amdgcn_mfma_f32_32x32x16_bf16(a11, b, acc11, 0, 0, 0);
        }
        float p0 = dq_part(acc00, (2*mg+0)*32, h, bt, wm)
                 + dq_part(acc01, (2*mg+1)*32, h, bt, wm);
        float p1 = dq_part(acc10, (2*mg+0)*32, h, bt, wm)
                 + dq_part(acc11, (2*mg+1)*32, h, bt, wm);
        p0 += __shfl_down(p0, 32);
        p1 += __shfl_down(p1, 32);
        if (h == 0 && col3 < 49) {
            lgf[((2*qp+0)*4 + mg)*64 + col3] = p0;
            lgf[((2*qp+1)*4 + mg)*64 + col3] = p1;
        }
    }
    __syncthreads();

    // ---- final: sigmoid + scatter to 14x14 ----
    if (tid < 196) {
        const int quad = tid / 49, s = tid - quad*49;
        const float val = lgf[(quad*4+0)*64 + s] + lgf[(quad*4+1)*64 + s]
                        + lgf[(quad*4+2)*64 + s] + lgf[(quad*4+3)*64 + s] + bm[0];
        const int p = s / 7, q = s - p*7;
        const int dy = quad >> 1, dx = quad & 1;
        out[(size_t)r * 196 + (2*p + dy)*14 + (2*q + dx)] = 1.f / (1.f + expf(-val));
    }
}

extern "C" void kernel_launch(void* const* d_in, const int* in_sizes, int n_in,
                              void* d_out, int out_size, void* d_ws, size_t ws_size,
                              hipStream_t stream) {
    const float* feat = (const float*)d_in[0];
    const float* bbox = (const float*)d_in[1];
    const float* w1   = (const float*)d_in[2];
    const float* s1   = (const float*)d_in[3];
    const float* b1   = (const float*)d_in[4];
    const float* w2   = (const float*)d_in[5];
    const float* s2   = (const float*)d_in[6];
    const float* b2   = (const float*)d_in[7];
    const float* w3   = (const float*)d_in[8];
    const float* s3   = (const float*)d_in[9];
    const float* b3   = (const float*)d_in[10];
    const float* wt   = (const float*)d_in[11];
    const float* bt   = (const float*)d_in[12];
    const float* wm   = (const float*)d_in[13];
    const float* bm   = (const float*)d_in[14];
    float* out = (float*)d_out;

    if (ws_size >= (size_t)WS_FULL) {
        unsigned char* ws = (unsigned char*)d_ws;
        hipLaunchKernelGGL(prep_all, dim3(1024), dim3(256), 0, stream,
                           feat, w1, w2, w3, wt, ws, 1);
        hipLaunchKernelGGL((masknet_mfma<1,1>), dim3(NROI), dim3(NT), 0, stream,
                           feat, bbox, w1, s1, b1, w2, s2, b2, w3, s3, b3,
                           wt, bt, wm, bm, ws, out);
    } else if (ws_size >= (size_t)WS_BYTES) {
        unsigned char* ws = (unsigned char*)d_ws;
        hipLaunchKernelGGL(prep_all, dim3(448), dim3(256), 0, stream,
                           feat, w1, w2, w3, wt, ws, 0);
        hipLaunchKernelGGL((masknet_mfma<1,0>), dim3(NROI), dim3(NT), 0, stream,
                           feat, bbox, w1, s1, b1, w2, s2, b2, w3, s3, b3,
                           wt, bt, wm, bm, ws, out);
    } else {
        hipLaunchKernelGGL((masknet_mfma<0,0>), dim3(NROI), dim3(NT), 0, stream,
                           feat, bbox, w1, s1, b1, w2, s2, b2, w3, s3, b3,
                           wt, bt, wm, bm, (const unsigned char*)nullptr, out);
    }
}

// Round 10
// 115.313 us; speedup vs baseline: 9.6943x; 1.2459x over previous
//
#include <hip/hip_runtime.h>
#include <math.h>

#define RESQ 7
#define CH   256
#define NROI 512
#define BC   128
#define NB   3
#define NT   512

typedef __bf16 bh8  __attribute__((ext_vector_type(8)));
typedef float  f16v __attribute__((ext_vector_type(16)));

// LDS-only barrier: drain LDS counter, NOT vmcnt -> global prefetch stays in flight
#define BAR() do { \
    asm volatile("s_waitcnt lgkmcnt(0)" ::: "memory"); \
    __builtin_amdgcn_s_barrier(); \
    asm volatile("" ::: "memory"); \
} while (0)

// ---- d_ws layout (bytes): fragment-major A panels ----
#define A1OFF 0            // [3 ib][4 mt][16 t][64 lane][8] bf16 = 196608
#define A2OFF 196608       // [3][9 tap][4 mt][8 t][64][8]       = 884736
#define A3OFF 1081344      // [3][8 mt][8 t][64][8]              = 196608
#define ATOFF 1277952      // [4 quad][8 mt][16 t][64][8]        = 524288
#define WS_BYTES 1802240
#define FTOFF 1802240      // feat_t [16][36][36][256] bf16 -> 10616832 B
#define WS_FULL 12419072
#define PRE_ELEMS 901120

// ---- LDS (bytes) ----
#define XS_OFF 0           // xs [49 sp][256 ch] bf16, stride 512
#define T1_OFF 25088       // t1 [81 rows][128 ch] bf16, stride 256
#define T2_OFF 45824       // t2 [49 sp][128 ch] bf16, stride 256
#define WY_OFF 58368       // 252 f32
#define WX_OFF 59376       // 252 f32
#define LG_OFF 60384       // logits [4 quad][4 mg][64] f32 = 4096
#define LDS_BYTES 64480

#define SWZ(row) (((row) & 15) << 4)

__device__ __forceinline__ float Fk(float t) {
    t = fminf(1.f, fmaxf(-1.f, t));
    float a = t + 1.f, b = 1.f - t;
    return (t < 0.f) ? 0.5f * a * a : 1.f - 0.5f * b * b;
}
__device__ __forceinline__ unsigned short bf16bits(float a) {
    return __builtin_bit_cast(unsigned short, (__bf16)a);
}
__device__ __forceinline__ unsigned int pk2(float a, float b) {
    return (unsigned int)bf16bits(a) | ((unsigned int)bf16bits(b) << 16);
}
__device__ __forceinline__ float b2f(unsigned int s) {
    return __builtin_bit_cast(float, s << 16);
}
__device__ __forceinline__ bh8 ld_bh8(const unsigned char* p) { return *(const bh8*)p; }
__device__ __forceinline__ bh8 cvt8(const float* p) {
    float4 a = *(const float4*)p;
    float4 b = *(const float4*)(p + 4);
    bh8 r;
    r[0]=(__bf16)a.x; r[1]=(__bf16)a.y; r[2]=(__bf16)a.z; r[3]=(__bf16)a.w;
    r[4]=(__bf16)b.x; r[5]=(__bf16)b.y; r[6]=(__bf16)b.z; r[7]=(__bf16)b.w;
    return r;
}
__device__ __forceinline__ bh8 gather8(const float* p, int stride) {
    bh8 r;
    #pragma unroll
    for (int j = 0; j < 8; ++j) r[j] = (__bf16)p[j * stride];
    return r;
}

// epilogue helpers (compile-time reg indices only)
__device__ __forceinline__ void epi_store(const f16v acc, int chbase, int h,
        const float* sarr, const float* barr, unsigned char* rowbase, int rswz) {
    #pragma unroll
    for (int g = 0; g < 4; ++g) {
        const int ch = chbase + 8*g + 4*h;
        const float4 sv = *(const float4*)(sarr + ch);
        const float4 bv = *(const float4*)(barr + ch);
        float v0 = fmaxf(fmaf(acc[4*g+0], sv.x, bv.x), 0.f);
        float v1 = fmaxf(fmaf(acc[4*g+1], sv.y, bv.y), 0.f);
        float v2 = fmaxf(fmaf(acc[4*g+2], sv.z, bv.z), 0.f);
        float v3 = fmaxf(fmaf(acc[4*g+3], sv.w, bv.w), 0.f);
        *(uint2*)(rowbase + ((2*ch) ^ rswz)) = make_uint2(pk2(v0,v1), pk2(v2,v3));
    }
}
__device__ __forceinline__ void epi_res(const f16v acc, int chbase, int h,
        const float* sarr, const float* barr, unsigned char* rowbase, int rswz) {
    #pragma unroll
    for (int g = 0; g < 4; ++g) {
        const int ch = chbase + 8*g + 4*h;
        const float4 sv = *(const float4*)(sarr + ch);
        const float4 bv = *(const float4*)(barr + ch);
        unsigned char* p = rowbase + ((2*ch) ^ rswz);
        const uint2 old = *(const uint2*)p;
        float v0 = fmaxf(fmaf(acc[4*g+0], sv.x, bv.x) + b2f(old.x & 0xFFFFu), 0.f);
        float v1 = fmaxf(fmaf(acc[4*g+1], sv.y, bv.y) + b2f(old.x >> 16), 0.f);
        float v2 = fmaxf(fmaf(acc[4*g+2], sv.z, bv.z) + b2f(old.y & 0xFFFFu), 0.f);
        float v3 = fmaxf(fmaf(acc[4*g+3], sv.w, bv.w) + b2f(old.y >> 16), 0.f);
        *(uint2*)p = make_uint2(pk2(v0,v1), pk2(v2,v3));
    }
}
__device__ __forceinline__ float dq_part(const f16v acc, int chbase, int h,
        const float* bt, const float* wm) {
    float part = 0.f;
    #pragma unroll
    for (int g = 0; g < 4; ++g) {
        const int ch = chbase + 8*g + 4*h;
        const float4 btv = *(const float4*)(bt + ch);
        const float4 wmv = *(const float4*)(wm + ch);
        part = fmaf(wmv.x, fmaxf(acc[4*g+0] + btv.x, 0.f), part);
        part = fmaf(wmv.y, fmaxf(acc[4*g+1] + btv.y, 0.f), part);
        part = fmaf(wmv.z, fmaxf(acc[4*g+2] + btv.z, 0.f), part);
        part = fmaf(wmv.w, fmaxf(acc[4*g+3] + btv.w, 0.f), part);
    }
    return part;
}

// ---------------- prepass: fragment-major weights + feat transpose ----------------
extern "C" __global__ void prep_all(const float* __restrict__ feat,
                                    const float* __restrict__ w1,
                                    const float* __restrict__ w2,
                                    const float* __restrict__ w3,
                                    const float* __restrict__ wt,
                                    unsigned char* __restrict__ ws,
                                    int do_ft) {
    __shared__ unsigned short tile[36 * 256];
    if (do_ft && blockIdx.x < 576) {
        const int b = blockIdx.x / 36, y = blockIdx.x % 36;
        const int c = threadIdx.x;  // 256 threads
        const float* src = feat + (size_t)(b * 256 + c) * 1296 + y * 36;
        float4 fv[9];
        #pragma unroll
        for (int i = 0; i < 9; ++i) fv[i] = *(const float4*)(src + i * 4);
        #pragma unroll
        for (int i = 0; i < 9; ++i) {
            tile[(i*4+0)*256 + c] = bf16bits(fv[i].x);
            tile[(i*4+1)*256 + c] = bf16bits(fv[i].y);
            tile[(i*4+2)*256 + c] = bf16bits(fv[i].z);
            tile[(i*4+3)*256 + c] = bf16bits(fv[i].w);
        }
        __syncthreads();
        unsigned short* dst = (unsigned short*)(ws + FTOFF) + (size_t)(b*36 + y)*36*256;
        for (int x = 0; x < 36; ++x) dst[x*256 + c] = tile[x*256 + c];
        return;
    }
    const int base = do_ft ? 576 : 0;
    const int nb = gridDim.x - base;
    __bf16* wb = (__bf16*)ws;
    for (int i = (blockIdx.x - base) * blockDim.x + threadIdx.x; i < PRE_ELEMS;
         i += nb * blockDim.x) {
        float v; int dst;
        if (i < 98304) {                       // A1 frag
            int e = i;
            int j = e & 7, lane = (e>>3)&63, t = (e>>9)&15, mt = (e>>13)&3, ib = e>>15;
            int m = mt*32 + (lane&31), k = t*16 + 8*(lane>>5) + j;
            v = w1[(ib*BC + m)*CH + k];
            dst = (A1OFF>>1) + e;
        } else if (i < 98304 + 442368) {       // A2 frag (tap-major)
            int e = i - 98304;
            int j = e & 7, lane = (e>>3)&63, t = (e>>9)&7, mt = (e>>12)&3;
            int rem = e >> 14;                 // ib*9 + tap
            int ib = rem / 9, tap = rem - ib*9;
            int m = mt*32 + (lane&31), ci = t*16 + 8*(lane>>5) + j;
            v = w2[((ib*BC + m)*BC + ci)*9 + tap];
            dst = (A2OFF>>1) + e;
        } else if (i < 98304 + 442368 + 98304) { // A3 frag
            int e = i - (98304 + 442368);
            int j = e & 7, lane = (e>>3)&63, t = (e>>9)&7, mt = (e>>12)&7, ib = e>>15;
            int m = mt*32 + (lane&31), ci = t*16 + 8*(lane>>5) + j;
            v = w3[(ib*CH + m)*BC + ci];
            dst = (A3OFF>>1) + e;
        } else {                                // AT frag
            int e = i - (98304 + 442368 + 98304);
            int j = e & 7, lane = (e>>3)&63, t = (e>>9)&15, mt = (e>>13)&7, quad = e>>16;
            int co = mt*32 + (lane&31), ci = t*16 + 8*(lane>>5) + j;
            v = wt[ci*1024 + co*4 + quad];
            dst = (ATOFF>>1) + e;
        }
        wb[dst] = (__bf16)v;
    }
}

// ---------------- fused main kernel ----------------
template<int USE_WS, int USE_FT>
__global__ __launch_bounds__(NT, 2)
void masknet_mfma(const float* __restrict__ feat,
                  const float* __restrict__ bbox,
                  const float* __restrict__ w1, const float* __restrict__ s1, const float* __restrict__ b1,
                  const float* __restrict__ w2, const float* __restrict__ s2, const float* __restrict__ b2,
                  const float* __restrict__ w3, const float* __restrict__ s3, const float* __restrict__ b3,
                  const float* __restrict__ wt, const float* __restrict__ bt,
                  const float* __restrict__ wm, const float* __restrict__ bm,
                  const unsigned char* __restrict__ ws,
                  float* __restrict__ out)
{
    __shared__ __align__(16) unsigned char smem[LDS_BYTES];
    float* wyb = (float*)(smem + WY_OFF);
    float* wxb = (float*)(smem + WX_OFF);
    float* lgf = (float*)(smem + LG_OFF);

    const int tid  = threadIdx.x;
    const int r    = blockIdx.x;
    const int bfr  = r >> 5;
    const int lane = tid & 63;
    const int ln   = lane & 31;
    const int h    = lane >> 5;
    const int w_   = tid >> 6;
    const int cb   = 16 * h;

    // ---- ROI params ----
    const float S = 1.f / 16.f;
    const float bx = bbox[r*4+0], by = bbox[r*4+1];
    const float bw_ = bbox[r*4+2], bh_ = bbox[r*4+3];
    const float x1 = bx * S, y1 = by * S;
    const float bwx = (bw_ * S) * (1.f / RESQ);
    const float bwy = (bh_ * S) * (1.f / RESQ);
    const float area = bwx * bwy;
    const float inv_area = (area > 0.f) ? 1.f / fmaxf(area, 1e-12f) : 0.f;

    // ---- Phase A: tables + zero t1 + zero logits ----
    if (tid < 252) {
        int p = tid / 36, i = tid - p * 36;
        float st = y1 + bwy * p, en = st + bwy;
        wyb[tid] = Fk(en - (float)i) - Fk(st - (float)i);
    } else if (tid >= 256 && tid < 508) {
        int t = tid - 256;
        int q = t / 36, i = t - q * 36;
        float st = x1 + bwx * q, en = st + bwx;
        wxb[t] = Fk(en - (float)i) - Fk(st - (float)i);
    }
    {
        uint4* z = (uint4*)(smem + T1_OFF);
        for (int o = tid; o < 1296; o += NT) z[o] = make_uint4(0,0,0,0);
        for (int o = tid; o < 1024; o += NT) lgf[o] = 0.f;
    }
    BAR();

    // ---- Phase B: PrRoI pool -> xs[s][c] bf16 (swizzled) ----
    if (USE_FT) {
        // 16 groups (wave-half per bin), lane = 8 channels, static 4x4 taps
        const unsigned short* ft = (const unsigned short*)(ws + FTOFF) + (size_t)bfr * (1296 * 256);
        const int g = w_ * 2 + h;   // 0..15
        #pragma unroll 1
        for (int k = 0; k < 4; ++k) {
            const int s = g + 16 * k;
            if (s >= 49) break;
            const int p = s / 7, q = s - p * 7;
            const float sy = y1 + bwy * p, sx = x1 + bwx * q;
            const int ylo = max(0, (int)floorf(sy)), yhi = min(35, (int)ceilf(sy + bwy));
            const int xlo = max(0, (int)floorf(sx)), xhi = min(35, (int)ceilf(sx + bwx));
            float wyv[4], wxv[4];
            #pragma unroll
            for (int j = 0; j < 4; ++j) {
                const int y = ylo + j, x = xlo + j;
                wyv[j] = (y <= yhi) ? wyb[p*36 + y] * inv_area : 0.f;
                wxv[j] = (x <= xhi) ? wxb[q*36 + x] : 0.f;
            }
            float ac0=0.f,ac1=0.f,ac2=0.f,ac3=0.f,ac4=0.f,ac5=0.f,ac6=0.f,ac7=0.f;
            #pragma unroll
            for (int yy = 0; yy < 4; ++yy) {
                const int y = min(ylo + yy, 35);
                const unsigned short* rowp = ft + (size_t)(y * 36) * 256 + ln * 8;
                #pragma unroll
                for (int xx = 0; xx < 4; ++xx) {
                    const int x = min(xlo + xx, 35);
                    const float wgt = wyv[yy] * wxv[xx];
                    const uint4 v = *(const uint4*)(rowp + x * 256);
                    ac0 = fmaf(wgt, b2f(v.x & 0xFFFFu), ac0);
                    ac1 = fmaf(wgt, b2f(v.x >> 16),     ac1);
                    ac2 = fmaf(wgt, b2f(v.y & 0xFFFFu), ac2);
                    ac3 = fmaf(wgt, b2f(v.y >> 16),     ac3);
                    ac4 = fmaf(wgt, b2f(v.z & 0xFFFFu), ac4);
                    ac5 = fmaf(wgt, b2f(v.z >> 16),     ac5);
                    ac6 = fmaf(wgt, b2f(v.w & 0xFFFFu), ac6);
                    ac7 = fmaf(wgt, b2f(v.w >> 16),     ac7);
                }
            }
            *(uint4*)(smem + XS_OFF + s * 512 + ((16 * ln) ^ SWZ(s))) =
                make_uint4(pk2(ac0,ac1), pk2(ac2,ac3), pk2(ac4,ac5), pk2(ac6,ac7));
        }
    } else {
        const float* fb = feat + (size_t)bfr * CH * 36 * 36;
        for (int o = tid; o < CH * 49; o += NT) {
            int c = o / 49, s = o - c * 49;
            int p = s / 7, q = s - p * 7;
            float sy = y1 + bwy * p, sx = x1 + bwx * q;
            int ylo = max(0, (int)floorf(sy)), yhi = min(35, (int)ceilf(sy + bwy));
            int xlo = max(0, (int)floorf(sx)), xhi = min(35, (int)ceilf(sx + bwx));
            const float* fc = fb + c * 1296;
            float acc = 0.f;
            for (int y = ylo; y <= yhi; ++y) {
                float wyv = wyb[p * 36 + y];
                for (int x = xlo; x <= xhi; ++x)
                    acc = fmaf(wyv * wxb[q * 36 + x], fc[y * 36 + x], acc);
            }
            *(unsigned short*)(smem + XS_OFF + s * 512 + ((2 * c) ^ SWZ(s))) =
                bf16bits(acc * inv_area);
        }
    }

    // wave geometry
    const int mt12 = w_ & 3, nt12 = w_ >> 2;           // conv1/2: 4m x 2n
    const int col12 = nt12 * 32 + ln;
    const int ncl12 = min(col12, 48);
    const int mg = w_ >> 1, ng = w_ & 1;               // conv3/deconv: (2 mt) x 2n
    const int col3 = ng * 32 + ln;
    const int ncl3 = min(col3, 48);

    // prefetch registers: first 4 A-frags of the upcoming phase, issued pre-barrier
    bh8 pf[4] = {};
    if (USE_WS) {
        #pragma unroll
        for (int t = 0; t < 4; ++t)
            pf[t] = ld_bh8(ws + A1OFF + ((((0*4 + mt12)*16 + t)*64 + lane) << 4));
    }
    BAR();

    // ---- Phase C: bottleneck blocks ----
    #pragma unroll 1
    for (int ib = 0; ib < NB; ++ib) {
        // ===== conv1: xs(256) -> t1(128 interior), K=256, 32x32 =====
        {
            const unsigned char* bb = smem + XS_OFF + ncl12 * 512;
            const int bswz = SWZ(ncl12);
            f16v acc = {};
            #pragma unroll
            for (int t = 0; t < 16; ++t) {
                bh8 a;
                if (USE_WS) a = (t < 4) ? pf[t]
                                        : ld_bh8(ws + A1OFF + ((((ib*4 + mt12)*16 + t)*64 + lane) << 4));
                else        a = cvt8(w1 + (size_t)(ib*BC + mt12*32 + ln)*CH + t*16 + 8*h);
                bh8 b = ld_bh8(bb + ((t*32 + cb) ^ bswz));
                acc = __builtin_amdgcn_mfma_f32_32x32x16_bf16(a, b, acc, 0, 0, 0);
            }
            if (col12 < 49) {
                const int row = (col12/7 + 1)*9 + (col12 - (col12/7)*7) + 1;
                epi_store(acc, mt12*32, h, s1 + ib*BC, b1 + ib*BC,
                          smem + T1_OFF + row*256, SWZ(row));
            }
        }
        if (USE_WS) {   // prefetch conv2 tap0 t=0..3
            #pragma unroll
            for (int t = 0; t < 4; ++t)
                pf[t] = ld_bh8(ws + A2OFF + (((((ib*9+0)*4 + mt12)*8 + t)*64 + lane) << 4));
        }
        BAR();

        // ===== conv2: 3x3 as 9 tap-GEMMs, t1(128) -> t2(128) =====
        {
            const int tr0 = (ncl12/7)*9 + (ncl12 - (ncl12/7)*7);
            f16v acc = {};
            #pragma unroll 1
            for (int ty = 0; ty < 3; ++ty) {
                #pragma unroll
                for (int tx = 0; tx < 3; ++tx) {
                    const int tap = ty*3 + tx;
                    bh8 aw[8];
                    #pragma unroll
                    for (int t = 0; t < 8; ++t) {
                        if (USE_WS) aw[t] = (ty == 0 && tx == 0 && t < 4) ? pf[t]
                                          : ld_bh8(ws + A2OFF + (((((ib*9+tap)*4 + mt12)*8 + t)*64 + lane) << 4));
                        else        aw[t] = gather8(w2 + ((size_t)(ib*BC + mt12*32 + ln)*BC + t*16 + 8*h)*9 + tap, 9);
                    }
                    const int row = tr0 + ty*9 + tx;
                    const unsigned char* bb = smem + T1_OFF + row*256;
                    const int rs = SWZ(row);
                    #pragma unroll
                    for (int t = 0; t < 8; ++t) {
                        bh8 b = ld_bh8(bb + ((t*32 + cb) ^ rs));
                        acc = __builtin_amdgcn_mfma_f32_32x32x16_bf16(aw[t], b, acc, 0, 0, 0);
                    }
                }
            }
            if (col12 < 49) {
                epi_store(acc, mt12*32, h, s2 + ib*BC, b2 + ib*BC,
                          smem + T2_OFF + col12*256, SWZ(col12));
            }
        }
        if (USE_WS) {   // prefetch conv3 a0 t=0..3
            #pragma unroll
            for (int t = 0; t < 4; ++t)
                pf[t] = ld_bh8(ws + A3OFF + ((((ib*8 + 2*mg+0)*8 + t)*64 + lane) << 4));
        }
        BAR();

        // ===== conv3: t2(128) -> xs(256) + residual + relu =====
        {
            const unsigned char* bb = smem + T2_OFF + ncl3 * 256;
            const int bswz = SWZ(ncl3);
            f16v acc0 = {}, acc1 = {};
            #pragma unroll
            for (int t = 0; t < 8; ++t) {
                bh8 a0, a1;
                if (USE_WS) {
                    a0 = (t < 4) ? pf[t]
                                 : ld_bh8(ws + A3OFF + ((((ib*8 + 2*mg+0)*8 + t)*64 + lane) << 4));
                    a1 = ld_bh8(ws + A3OFF + ((((ib*8 + 2*mg+1)*8 + t)*64 + lane) << 4));
                } else {
                    a0 = cvt8(w3 + (size_t)(ib*CH + (2*mg+0)*32 + ln)*BC + t*16 + 8*h);
                    a1 = cvt8(w3 + (size_t)(ib*CH + (2*mg+1)*32 + ln)*BC + t*16 + 8*h);
                }
                bh8 b = ld_bh8(bb + ((t*32 + cb) ^ bswz));
                acc0 = __builtin_amdgcn_mfma_f32_32x32x16_bf16(a0, b, acc0, 0, 0, 0);
                acc1 = __builtin_amdgcn_mfma_f32_32x32x16_bf16(a1, b, acc1, 0, 0, 0);
            }
            if (col3 < 49) {
                unsigned char* rowb = smem + XS_OFF + col3*512;
                const int rs = SWZ(col3);
                epi_res(acc0, (2*mg+0)*32, h, s3 + ib*CH, b3 + ib*CH, rowb, rs);
                epi_res(acc1, (2*mg+1)*32, h, s3 + ib*CH, b3 + ib*CH, rowb, rs);
            }
        }
        if (USE_WS) {   // prefetch next conv1 (ib+1) or deconv quad0
            #pragma unroll
            for (int t = 0; t < 4; ++t) {
                if (ib < NB - 1)
                    pf[t] = ld_bh8(ws + A1OFF + (((((ib+1)*4 + mt12)*16 + t)*64 + lane) << 4));
                else
                    pf[t] = ld_bh8(ws + ATOFF + ((((0*8 + 2*mg+0)*16 + t)*64 + lane) << 4));
            }
        }
        BAR();
    }

    // ---- Phase D: deconv as 4 quad passes (2 acc each) + fused mask head ----
    {
        const unsigned char* bb = smem + XS_OFF + ncl3 * 512;
        const int bswz = SWZ(ncl3);
        // pass 0 (uses pf)
        {
            f16v acc0 = {}, acc1 = {};
            #pragma unroll
            for (int t = 0; t < 16; ++t) {
                bh8 b = ld_bh8(bb + ((t*32 + cb) ^ bswz));
                bh8 a0, a1;
                if (USE_WS) {
                    a0 = (t < 4) ? pf[t]
                                 : ld_bh8(ws + ATOFF + ((((0*8 + 2*mg+0)*16 + t)*64 + lane) << 4));
                    a1 = ld_bh8(ws + ATOFF + ((((0*8 + 2*mg+1)*16 + t)*64 + lane) << 4));
                } else {
                    a0 = gather8(wt + (size_t)(t*16 + 8*h)*1024 + ((2*mg+0)*32 + ln)*4 + 0, 1024);
                    a1 = gather8(wt + (size_t)(t*16 + 8*h)*1024 + ((2*mg+1)*32 + ln)*4 + 0, 1024);
                }
                acc0 = __builtin_amdgcn_mfma_f32_32x32x16_bf16(a0, b, acc0, 0, 0, 0);
                acc1 = __builtin_amdgcn_mfma_f32_32x32x16_bf16(a1, b, acc1, 0, 0, 0);
            }
            float p0 = dq_part(acc0, (2*mg+0)*32, h, bt, wm)
                     + dq_part(acc1, (2*mg+1)*32, h, bt, wm);
            p0 += __shfl_down(p0, 32);
            if (h == 0 && col3 < 49) lgf[(0*4 + mg)*64 + col3] = p0;
        }
        // passes 1..3
        #pragma unroll 1
        for (int quad = 1; quad < 4; ++quad) {
            f16v acc0 = {}, acc1 = {};
            #pragma unroll
            for (int t = 0; t < 16; ++t) {
                bh8 b = ld_bh8(bb + ((t*32 + cb) ^ bswz));
                bh8 a0, a1;
                if (USE_WS) {
                    a0 = ld_bh8(ws + ATOFF + ((((quad*8 + 2*mg+0)*16 + t)*64 + lane) << 4));
                    a1 = ld_bh8(ws + ATOFF + ((((quad*8 + 2*mg+1)*16 + t)*64 + lane) << 4));
                } else {
                    a0 = gather8(wt + (size_t)(t*16 + 8*h)*1024 + ((2*mg+0)*32 + ln)*4 + quad, 1024);
                    a1 = gather8(wt + (size_t)(t*16 + 8*h)*1024 + ((2*mg+1)*32 + ln)*4 + quad, 1024);
                }
                acc0 = __builtin_amdgcn_mfma_f32_32x32x16_bf16(a0, b, acc0, 0, 0, 0);
                acc1 = __builtin_amdgcn_mfma_f32_32x32x16_bf16(a1, b, acc1, 0, 0, 0);
            }
            float p0 = dq_part(acc0, (2*mg+0)*32, h, bt, wm)
                     + dq_part(acc1, (2*mg+1)*32, h, bt, wm);
            p0 += __shfl_down(p0, 32);
            if (h == 0 && col3 < 49) lgf[(quad*4 + mg)*64 + col3] = p0;
        }
    }
    BAR();

    // ---- final: sigmoid + scatter to 14x14 ----
    if (tid < 196) {
        const int quad = tid / 49, s = tid - quad*49;
        const float val = lgf[(quad*4+0)*64 + s] + lgf[(quad*4+1)*64 + s]
                        + lgf[(quad*4+2)*64 + s] + lgf[(quad*4+3)*64 + s] + bm[0];
        const int p = s / 7, q = s - p*7;
        const int dy = quad >> 1, dx = quad & 1;
        out[(size_t)r * 196 + (2*p + dy)*14 + (2*q + dx)] = 1.f / (1.f + expf(-val));
    }
}

extern "C" void kernel_launch(void* const* d_in, const int* in_sizes, int n_in,
                              void* d_out, int out_size, void* d_ws, size_t ws_size,
                              hipStream_t stream) {
    const float* feat = (const float*)d_in[0];
    const float* bbox = (const float*)d_in[1];
    const float* w1   = (const float*)d_in[2];
    const float* s1   = (const float*)d_in[3];
    const float* b1   = (const float*)d_in[4];
    const float* w2   = (const float*)d_in[5];
    const float* s2   = (const float*)d_in[6];
    const float* b2   = (const float*)d_in[7];
    const float* w3   = (const float*)d_in[8];
    const float* s3   = (const float*)d_in[9];
    const float* b3   = (const float*)d_in[10];
    const float* wt   = (const float*)d_in[11];
    const float* bt   = (const float*)d_in[12];
    const float* wm   = (const float*)d_in[13];
    const float* bm   = (const float*)d_in[14];
    float* out = (float*)d_out;

    if (ws_size >= (size_t)WS_FULL) {
        unsigned char* ws = (unsigned char*)d_ws;
        hipLaunchKernelGGL(prep_all, dim3(1024), dim3(256), 0, stream,
                           feat, w1, w2, w3, wt, ws, 1);
        hipLaunchKernelGGL((masknet_mfma<1,1>), dim3(NROI), dim3(NT), 0, stream,
                           feat, bbox, w1, s1, b1, w2, s2, b2, w3, s3, b3,
                           wt, bt, wm, bm, ws, out);
    } else if (ws_size >= (size_t)WS_BYTES) {
        unsigned char* ws = (unsigned char*)d_ws;
        hipLaunchKernelGGL(prep_all, dim3(448), dim3(256), 0, stream,
                           feat, w1, w2, w3, wt, ws, 0);
        hipLaunchKernelGGL((masknet_mfma<1,0>), dim3(NROI), dim3(NT), 0, stream,
                           feat, bbox, w1, s1, b1, w2, s2, b2, w3, s3, b3,
                           wt, bt, wm, bm, ws, out);
    } else {
        hipLaunchKernelGGL((masknet_mfma<0,0>), dim3(NROI), dim3(NT), 0, stream,
                           feat, bbox, w1, s1, b1, w2, s2, b2, w3, s3, b3,
                           wt, bt, wm, bm, (const unsigned char*)nullptr, out);
    }
}